// Round 1
// baseline (973.833 us; speedup 1.0000x reference)
//
#include <hip/hip_runtime.h>
#include <math.h>

#define NN 4096
#define NE 131072
#define EE (NE + NN)

// ===================== CSR build =====================
__global__ void k_count(const int* __restrict__ ei, int* __restrict__ deg) {
  int e = blockIdx.x * 256 + threadIdx.x;
  if (e >= EE) return;
  int dst = (e < NE) ? ei[NE + e] : (e - NE);
  atomicAdd(&deg[dst], 1);
}

__global__ __launch_bounds__(1024) void k_scan(const int* __restrict__ deg, int* __restrict__ rowptr) {
  __shared__ int lds[1024];
  int t = threadIdx.x;
  int v0 = deg[t*4+0], v1 = deg[t*4+1], v2 = deg[t*4+2], v3 = deg[t*4+3];
  int s1 = v0+v1, s2 = s1+v2, s3 = s2+v3;
  lds[t] = s3;
  __syncthreads();
  for (int off = 1; off < 1024; off <<= 1) {
    int add = (t >= off) ? lds[t-off] : 0;
    __syncthreads();
    lds[t] += add;
    __syncthreads();
  }
  int base = lds[t] - s3;
  rowptr[t*4+1] = base + v0;
  rowptr[t*4+2] = base + s1;
  rowptr[t*4+3] = base + s2;
  rowptr[t*4+4] = base + s3;
  if (t == 0) rowptr[0] = 0;
}

__global__ void k_scatter(const int* __restrict__ ei, const int* __restrict__ rowptr,
                          int* __restrict__ cursor, int* __restrict__ csr_src) {
  int e = blockIdx.x * 256 + threadIdx.x;
  if (e >= EE) return;
  int src, dst;
  if (e < NE) { src = ei[e]; dst = ei[NE + e]; }
  else { src = e - NE; dst = src; }
  int pos = rowptr[dst] + atomicAdd(&cursor[dst], 1);
  csr_src[pos] = src;
}

// ===================== GAT projection (h = x @ W^T, + attention logits) =====================
template<int K, int F, int HEADS, int C>
__global__ __launch_bounds__(256) void k_gat_proj(
    const float* __restrict__ x, const float* __restrict__ W,
    const float* __restrict__ asrc, const float* __restrict__ adst,
    float* __restrict__ feat, float* __restrict__ als, float* __restrict__ ald)
{
  int n = blockIdx.x, t = threadIdx.x;
  __shared__ float xrow[K];
  __shared__ float red[F];
  for (int i = t; i < K; i += F) xrow[i] = x[(size_t)n*K + i];
  __syncthreads();
  const float4* wr = (const float4*)(W + (size_t)t*K);
  const float4* xr = (const float4*)xrow;
  float acc = 0.f;
  #pragma unroll 8
  for (int k4 = 0; k4 < K/4; ++k4) {
    float4 w = wr[k4], xx = xr[k4];
    acc += w.x*xx.x + w.y*xx.y + w.z*xx.z + w.w*xx.w;
  }
  feat[(size_t)n*F + t] = acc;
  int hh = t / C, cc = t % C;
  // reduce acc * asrc over each C-segment  (asrc flat layout [HEADS*C] == index t)
  red[t] = acc * asrc[t];
  __syncthreads();
  for (int off = C/2; off > 0; off >>= 1) {
    float add = (cc < off) ? red[t + off] : 0.f;
    __syncthreads();
    if (cc < off) red[t] += add;
    __syncthreads();
  }
  if (cc == 0) als[(size_t)n*HEADS + hh] = red[t];
  __syncthreads();
  red[t] = acc * adst[t];
  __syncthreads();
  for (int off = C/2; off > 0; off >>= 1) {
    float add = (cc < off) ? red[t + off] : 0.f;
    __syncthreads();
    if (cc < off) red[t] += add;
    __syncthreads();
  }
  if (cc == 0) ald[(size_t)n*HEADS + hh] = red[t];
}

// ===================== GAT aggregation (segment softmax + weighted sum) =====================
template<int HEADS, int C, bool DO_ELU>
__global__ __launch_bounds__(256) void k_gat_agg(
    const float* __restrict__ feat, const float* __restrict__ als,
    const float* __restrict__ ald, const float* __restrict__ bias,
    const int* __restrict__ rowptr, const int* __restrict__ csr_src,
    float* __restrict__ out)
{
  constexpr int F = HEADS * C;
  int n = blockIdx.x, t = threadIdx.x;
  __shared__ float m_sh[HEADS], s_sh[HEADS];
  int start = rowptr[n];
  int deg = rowptr[n+1] - start;
  int lane = t & 63, wv = t >> 6;
  for (int hh = wv; hh < HEADS; hh += F/64) {
    float adl = ald[(size_t)n*HEADS + hh];
    float mx = -INFINITY;
    for (int i = lane; i < deg; i += 64) {
      int s = csr_src[start + i];
      float lg = als[(size_t)s*HEADS + hh] + adl;
      lg = (lg > 0.f) ? lg : 0.2f * lg;
      mx = fmaxf(mx, lg);
    }
    #pragma unroll
    for (int off = 32; off; off >>= 1) mx = fmaxf(mx, __shfl_xor(mx, off));
    float sm = 0.f;
    for (int i = lane; i < deg; i += 64) {
      int s = csr_src[start + i];
      float lg = als[(size_t)s*HEADS + hh] + adl;
      lg = (lg > 0.f) ? lg : 0.2f * lg;
      sm += expf(lg - mx);
    }
    #pragma unroll
    for (int off = 32; off; off >>= 1) sm += __shfl_xor(sm, off);
    if (lane == 0) { m_sh[hh] = mx; s_sh[hh] = sm; }
  }
  __syncthreads();
  int hh = t / C;
  float adl = ald[(size_t)n*HEADS + hh];
  float mh = m_sh[hh];
  float acc = 0.f;
  for (int i = 0; i < deg; ++i) {
    int s = csr_src[start + i];
    float lg = als[(size_t)s*HEADS + hh] + adl;
    lg = (lg > 0.f) ? lg : 0.2f * lg;
    float p = expf(lg - mh);
    acc += p * feat[(size_t)s*F + t];
  }
  float o = acc / (s_sh[hh] + 1e-16f) + bias[t];
  if (DO_ELU) o = (o > 0.f) ? o : (expf(o) - 1.f);
  out[(size_t)n*F + t] = o;
}

// ===================== Tiled GEMM: C[M,N] = A[M,K] @ B[N,K]^T + bias (act: 0 none, 1 relu) =====================
template<int BM, int BN, int TM, int TN>
__global__ __launch_bounds__(256) void k_gemm_bt(
    const float* __restrict__ A, const float* __restrict__ B,
    const float* __restrict__ bias, float* __restrict__ C_,
    int M, int N, int K, int act)
{
  constexpr int BK = 16;
  __shared__ float As[BK][BM + 4];
  __shared__ float Bs[BK][BN + 4];
  const int t = threadIdx.x;
  constexpr int TX = BN / TN;
  const int tx = t % TX, ty = t / TX;
  const int m0 = blockIdx.y * BM, n0 = blockIdx.x * BN;
  float acc[TM][TN] = {};
  for (int k0 = 0; k0 < K; k0 += BK) {
    #pragma unroll
    for (int idx = t; idx < BM*(BK/4); idx += 256) {
      int r = idx / (BK/4), c4 = (idx % (BK/4)) * 4;
      float4 v = *(const float4*)&A[(size_t)(m0 + r)*K + k0 + c4];
      As[c4+0][r] = v.x; As[c4+1][r] = v.y; As[c4+2][r] = v.z; As[c4+3][r] = v.w;
    }
    #pragma unroll
    for (int idx = t; idx < BN*(BK/4); idx += 256) {
      int r = idx / (BK/4), c4 = (idx % (BK/4)) * 4;
      float4 v = *(const float4*)&B[(size_t)(n0 + r)*K + k0 + c4];
      Bs[c4+0][r] = v.x; Bs[c4+1][r] = v.y; Bs[c4+2][r] = v.z; Bs[c4+3][r] = v.w;
    }
    __syncthreads();
    #pragma unroll
    for (int kk = 0; kk < BK; ++kk) {
      float a[TM], b[TN];
      #pragma unroll
      for (int i4 = 0; i4 < TM/4; ++i4) *(float4*)&a[i4*4] = *(const float4*)&As[kk][ty*TM + i4*4];
      #pragma unroll
      for (int j4 = 0; j4 < TN/4; ++j4) *(float4*)&b[j4*4] = *(const float4*)&Bs[kk][tx*TN + j4*4];
      #pragma unroll
      for (int i = 0; i < TM; ++i)
        #pragma unroll
        for (int j = 0; j < TN; ++j)
          acc[i][j] += a[i] * b[j];
    }
    __syncthreads();
  }
  #pragma unroll
  for (int i = 0; i < TM; ++i) {
    int row = m0 + ty*TM + i;
    #pragma unroll
    for (int j4 = 0; j4 < TN; j4 += 4) {
      int col = n0 + tx*TN + j4;
      float4 bv = *(const float4*)&bias[col];
      float4 o;
      o.x = acc[i][j4+0] + bv.x;
      o.y = acc[i][j4+1] + bv.y;
      o.z = acc[i][j4+2] + bv.z;
      o.w = acc[i][j4+3] + bv.w;
      if (act == 1) {
        o.x = fmaxf(o.x, 0.f); o.y = fmaxf(o.y, 0.f);
        o.z = fmaxf(o.z, 0.f); o.w = fmaxf(o.w, 0.f);
      }
      *(float4*)&C_[(size_t)row*N + col] = o;
    }
  }
}

// ===================== LayerNorm(a + res) =====================
__global__ __launch_bounds__(256) void k_ln(
    const float* __restrict__ a, const float* __restrict__ res,
    const float* __restrict__ g, const float* __restrict__ bb,
    float* __restrict__ out)
{
  int n = blockIdx.x, t = threadIdx.x;
  __shared__ float part[4];
  float v = a[(size_t)n*256 + t] + res[(size_t)n*256 + t];
  float s = v;
  #pragma unroll
  for (int off = 32; off; off >>= 1) s += __shfl_xor(s, off);
  if ((t & 63) == 0) part[t >> 6] = s;
  __syncthreads();
  float mean = (part[0] + part[1] + part[2] + part[3]) * (1.f/256.f);
  __syncthreads();
  float d = v - mean;
  float s2 = d * d;
  #pragma unroll
  for (int off = 32; off; off >>= 1) s2 += __shfl_xor(s2, off);
  if ((t & 63) == 0) part[t >> 6] = s2;
  __syncthreads();
  float var = (part[0] + part[1] + part[2] + part[3]) * (1.f/256.f);
  float rstd = rsqrtf(var + 1e-5f);
  out[(size_t)n*256 + t] = d * rstd * g[t] + bb[t];
}

// ===================== Flash attention (fp32), 4 heads, hd=64 =====================
__global__ __launch_bounds__(256) void k_attn(const float* __restrict__ qkv, float* __restrict__ o_out)
{
  const int head = blockIdx.y;
  const int q0 = blockIdx.x * 64;
  __shared__ float Qs[64][68];
  __shared__ float KPs[64][68];   // holds K^T as [d][k], then P as [q][k]
  __shared__ float Vs[64][68];
  __shared__ float red[64][17];
  __shared__ float mrun[64], lrun[64], mnew[64], scsh[64];
  const int t = threadIdx.x;
  const int tx = t & 15, ty = t >> 4;

  #pragma unroll
  for (int it = 0; it < 4; ++it) {
    int row = it*16 + (t >> 4);
    int c4 = (t & 15) * 4;
    *(float4*)&Qs[row][c4] = *(const float4*)&qkv[(size_t)(q0 + row)*768 + head*64 + c4];
  }
  if (t < 64) { mrun[t] = -INFINITY; lrun[t] = 0.f; }
  float o_acc[4][4] = {};
  __syncthreads();

  for (int kt = 0; kt < NN; kt += 64) {
    // stage K (transposed) and V
    #pragma unroll
    for (int it = 0; it < 4; ++it) {
      int row = it*16 + (t >> 4);
      int c4 = (t & 15) * 4;
      float4 kv = *(const float4*)&qkv[(size_t)(kt + row)*768 + 256 + head*64 + c4];
      KPs[c4+0][row] = kv.x; KPs[c4+1][row] = kv.y; KPs[c4+2][row] = kv.z; KPs[c4+3][row] = kv.w;
      *(float4*)&Vs[row][c4] = *(const float4*)&qkv[(size_t)(kt + row)*768 + 512 + head*64 + c4];
    }
    __syncthreads();                       // B1: tiles staged
    float s[4][4] = {};
    #pragma unroll
    for (int d0 = 0; d0 < 64; d0 += 4) {
      float qa[4][4], kb[4][4];
      #pragma unroll
      for (int i = 0; i < 4; ++i) *(float4*)qa[i] = *(const float4*)&Qs[ty*4+i][d0];
      #pragma unroll
      for (int dd = 0; dd < 4; ++dd) *(float4*)kb[dd] = *(const float4*)&KPs[d0+dd][tx*4];
      #pragma unroll
      for (int i = 0; i < 4; ++i)
        #pragma unroll
        for (int j = 0; j < 4; ++j)
          s[i][j] += qa[i][0]*kb[0][j] + qa[i][1]*kb[1][j] + qa[i][2]*kb[2][j] + qa[i][3]*kb[3][j];
    }
    float pmax[4];
    #pragma unroll
    for (int i = 0; i < 4; ++i) {
      pmax[i] = -INFINITY;
      #pragma unroll
      for (int j = 0; j < 4; ++j) { s[i][j] *= 0.125f; pmax[i] = fmaxf(pmax[i], s[i][j]); }
      red[ty*4+i][tx] = pmax[i];
    }
    __syncthreads();                       // B2: partial maxes ready; K reads done
    if (t < 64) {
      float rm = red[t][0];
      #pragma unroll
      for (int j = 1; j < 16; ++j) rm = fmaxf(rm, red[t][j]);
      float mo = mrun[t];
      float mn = fmaxf(mo, rm);
      mnew[t] = mn;
      scsh[t] = expf(mo - mn);
      mrun[t] = mn;
    }
    __syncthreads();                       // B3: mnew/scale ready
    #pragma unroll
    for (int i = 0; i < 4; ++i) {
      float mn = mnew[ty*4+i];
      float p0 = expf(s[i][0]-mn), p1 = expf(s[i][1]-mn);
      float p2 = expf(s[i][2]-mn), p3 = expf(s[i][3]-mn);
      float4 pv; pv.x = p0; pv.y = p1; pv.z = p2; pv.w = p3;
      *(float4*)&KPs[ty*4+i][tx*4] = pv;
      red[ty*4+i][tx] = p0+p1+p2+p3;
    }
    __syncthreads();                       // B4: P + partial sums ready
    if (t < 64) {
      float ps = 0.f;
      #pragma unroll
      for (int j = 0; j < 16; ++j) ps += red[t][j];
      lrun[t] = lrun[t]*scsh[t] + ps;
    }
    #pragma unroll
    for (int i = 0; i < 4; ++i) {
      float sc = scsh[ty*4+i];
      #pragma unroll
      for (int j = 0; j < 4; ++j) o_acc[i][j] *= sc;
    }
    #pragma unroll
    for (int k0 = 0; k0 < 64; k0 += 4) {
      float pa[4][4], vb[4][4];
      #pragma unroll
      for (int i = 0; i < 4; ++i) *(float4*)pa[i] = *(const float4*)&KPs[ty*4+i][k0];
      #pragma unroll
      for (int l = 0; l < 4; ++l) *(float4*)vb[l] = *(const float4*)&Vs[k0+l][tx*4];
      #pragma unroll
      for (int i = 0; i < 4; ++i)
        #pragma unroll
        for (int j = 0; j < 4; ++j)
          o_acc[i][j] += pa[i][0]*vb[0][j] + pa[i][1]*vb[1][j] + pa[i][2]*vb[2][j] + pa[i][3]*vb[3][j];
    }
    __syncthreads();                       // B5: done with KPs/Vs/lrun for this tile
  }
  #pragma unroll
  for (int i = 0; i < 4; ++i) {
    int q = ty*4 + i;
    float inv = 1.f / lrun[q];
    float4 o;
    o.x = o_acc[i][0]*inv; o.y = o_acc[i][1]*inv;
    o.z = o_acc[i][2]*inv; o.w = o_acc[i][3]*inv;
    *(float4*)&o_out[(size_t)(q0 + q)*256 + head*64 + tx*4] = o;
  }
}

// ===================== host launcher =====================
extern "C" void kernel_launch(void* const* d_in, const int* in_sizes, int n_in,
                              void* d_out, int out_size, void* d_ws, size_t ws_size,
                              hipStream_t stream)
{
  const float* x       = (const float*)d_in[0];
  const int*   ei      = (const int*)d_in[1];
  const float* gat1_w  = (const float*)d_in[2];
  const float* gat1_as = (const float*)d_in[3];
  const float* gat1_ad = (const float*)d_in[4];
  const float* gat1_b  = (const float*)d_in[5];
  const float* inp_w   = (const float*)d_in[6];
  const float* inp_b   = (const float*)d_in[7];
  const float* outp_w  = (const float*)d_in[8];
  const float* outp_b  = (const float*)d_in[9];
  const float* lin1_w  = (const float*)d_in[10];
  const float* lin1_b  = (const float*)d_in[11];
  const float* lin2_w  = (const float*)d_in[12];
  const float* lin2_b  = (const float*)d_in[13];
  const float* ln1_g   = (const float*)d_in[14];
  const float* ln1_bb  = (const float*)d_in[15];
  const float* ln2_g   = (const float*)d_in[16];
  const float* ln2_bb  = (const float*)d_in[17];
  const float* gat2_w  = (const float*)d_in[18];
  const float* gat2_as = (const float*)d_in[19];
  const float* gat2_ad = (const float*)d_in[20];
  const float* gat2_b  = (const float*)d_in[21];
  float* out = (float*)d_out;
  (void)in_sizes; (void)n_in; (void)out_size; (void)ws_size;

  char* ws = (char*)d_ws;
  size_t off = 0;
  auto nxt = [&](size_t bytes) { size_t r = off; off += (bytes + 255) & ~(size_t)255; return r; };
  int* deg      = (int*)(ws + nxt((size_t)NN*4));
  int* cursor   = (int*)(ws + nxt((size_t)NN*4));
  int* rowptr   = (int*)(ws + nxt((size_t)(NN+1)*4));
  int* csr_src  = (int*)(ws + nxt((size_t)EE*4));
  float* feat1  = (float*)(ws + nxt((size_t)NN*256*4));
  float* al1s   = (float*)(ws + nxt((size_t)NN*4*4));
  float* al1d   = (float*)(ws + nxt((size_t)NN*4*4));
  float* hgat1  = (float*)(ws + nxt((size_t)NN*256*4));
  float* qkvb   = (float*)(ws + nxt((size_t)NN*768*4));
  float* attno  = (float*)(ws + nxt((size_t)NN*256*4));
  float* tmp256 = (float*)(ws + nxt((size_t)NN*256*4));
  float* hln1   = (float*)(ws + nxt((size_t)NN*256*4));
  float* ff1    = (float*)(ws + nxt((size_t)NN*2048*4));
  float* hln2   = (float*)(ws + nxt((size_t)NN*256*4));
  float* feat2  = (float*)(ws + nxt((size_t)NN*128*4));
  float* al2s   = (float*)(ws + nxt((size_t)NN*4));
  float* al2d   = (float*)(ws + nxt((size_t)NN*4));

  hipMemsetAsync(deg, 0, (size_t)NN*4, stream);
  hipMemsetAsync(cursor, 0, (size_t)NN*4, stream);
  k_count<<<(EE+255)/256, 256, 0, stream>>>(ei, deg);
  k_scan<<<1, 1024, 0, stream>>>(deg, rowptr);
  k_scatter<<<(EE+255)/256, 256, 0, stream>>>(ei, rowptr, cursor, csr_src);

  // GAT layer 1 + ELU
  k_gat_proj<128,256,4,64><<<NN, 256, 0, stream>>>(x, gat1_w, gat1_as, gat1_ad, feat1, al1s, al1d);
  k_gat_agg<4,64,true><<<NN, 256, 0, stream>>>(feat1, al1s, al1d, gat1_b, rowptr, csr_src, hgat1);

  // Transformer encoder layer
  k_gemm_bt<64,64,4,4><<<dim3(768/64, NN/64), 256, 0, stream>>>(hgat1, inp_w, inp_b, qkvb, NN, 768, 256, 0);
  k_attn<<<dim3(NN/64, 4), 256, 0, stream>>>(qkvb, attno);
  k_gemm_bt<64,64,4,4><<<dim3(256/64, NN/64), 256, 0, stream>>>(attno, outp_w, outp_b, tmp256, NN, 256, 256, 0);
  k_ln<<<NN, 256, 0, stream>>>(tmp256, hgat1, ln1_g, ln1_bb, hln1);
  k_gemm_bt<128,128,8,8><<<dim3(2048/128, NN/128), 256, 0, stream>>>(hln1, lin1_w, lin1_b, ff1, NN, 2048, 256, 1);
  k_gemm_bt<64,64,4,4><<<dim3(256/64, NN/64), 256, 0, stream>>>(ff1, lin2_w, lin2_b, tmp256, NN, 256, 2048, 0);
  k_ln<<<NN, 256, 0, stream>>>(tmp256, hln1, ln2_g, ln2_bb, hln2);

  // GAT layer 2 -> final output
  k_gat_proj<256,128,1,128><<<NN, 128, 0, stream>>>(hln2, gat2_w, gat2_as, gat2_ad, feat2, al2s, al2d);
  k_gat_agg<1,128,false><<<NN, 128, 0, stream>>>(feat2, al2s, al2d, gat2_b, rowptr, csr_src, out);
}

// Round 3
// 641.487 us; speedup vs baseline: 1.5181x; 1.5181x over previous
//
#include <hip/hip_runtime.h>
#include <hip/hip_bf16.h>
#include <math.h>

#define NN 4096
#define NE 131072
#define EE (NE + NN)

typedef unsigned short u16;
typedef short s8v __attribute__((ext_vector_type(8)));
typedef float f4v __attribute__((ext_vector_type(4)));

__device__ inline u16 f2b(float f) {
  __hip_bfloat16 h = __float2bfloat16(f);
  return __builtin_bit_cast(u16, h);
}

// ===================== CSR build =====================
__global__ void k_count(const int* __restrict__ ei, int* __restrict__ deg) {
  int e = blockIdx.x * 256 + threadIdx.x;
  if (e >= EE) return;
  int dst = (e < NE) ? ei[NE + e] : (e - NE);
  atomicAdd(&deg[dst], 1);
}

__global__ __launch_bounds__(1024) void k_scan(const int* __restrict__ deg, int* __restrict__ rowptr) {
  __shared__ int lds[1024];
  int t = threadIdx.x;
  int v0 = deg[t*4+0], v1 = deg[t*4+1], v2 = deg[t*4+2], v3 = deg[t*4+3];
  int s1 = v0+v1, s2 = s1+v2, s3 = s2+v3;
  lds[t] = s3;
  __syncthreads();
  for (int off = 1; off < 1024; off <<= 1) {
    int add = (t >= off) ? lds[t-off] : 0;
    __syncthreads();
    lds[t] += add;
    __syncthreads();
  }
  int base = lds[t] - s3;
  rowptr[t*4+1] = base + v0;
  rowptr[t*4+2] = base + s1;
  rowptr[t*4+3] = base + s2;
  rowptr[t*4+4] = base + s3;
  if (t == 0) rowptr[0] = 0;
}

__global__ void k_scatter(const int* __restrict__ ei, const int* __restrict__ rowptr,
                          int* __restrict__ cursor, int* __restrict__ csr_src) {
  int e = blockIdx.x * 256 + threadIdx.x;
  if (e >= EE) return;
  int src, dst;
  if (e < NE) { src = ei[e]; dst = ei[NE + e]; }
  else { src = e - NE; dst = src; }
  int pos = rowptr[dst] + atomicAdd(&cursor[dst], 1);
  csr_src[pos] = src;
}

// ===================== GAT projection =====================
template<int K, int F, int HEADS, int C>
__global__ __launch_bounds__(256) void k_gat_proj(
    const float* __restrict__ x, const float* __restrict__ W,
    const float* __restrict__ asrc, const float* __restrict__ adst,
    float* __restrict__ feat, float* __restrict__ als, float* __restrict__ ald)
{
  int n = blockIdx.x, t = threadIdx.x;
  __shared__ float xrow[K];
  __shared__ float red[F];
  for (int i = t; i < K; i += F) xrow[i] = x[(size_t)n*K + i];
  __syncthreads();
  const float4* wr = (const float4*)(W + (size_t)t*K);
  const float4* xr = (const float4*)xrow;
  float acc = 0.f;
  #pragma unroll 8
  for (int k4 = 0; k4 < K/4; ++k4) {
    float4 w = wr[k4], xx = xr[k4];
    acc += w.x*xx.x + w.y*xx.y + w.z*xx.z + w.w*xx.w;
  }
  feat[(size_t)n*F + t] = acc;
  int hh = t / C, cc = t % C;
  red[t] = acc * asrc[t];
  __syncthreads();
  for (int off = C/2; off > 0; off >>= 1) {
    float add = (cc < off) ? red[t + off] : 0.f;
    __syncthreads();
    if (cc < off) red[t] += add;
    __syncthreads();
  }
  if (cc == 0) als[(size_t)n*HEADS + hh] = red[t];
  __syncthreads();
  red[t] = acc * adst[t];
  __syncthreads();
  for (int off = C/2; off > 0; off >>= 1) {
    float add = (cc < off) ? red[t + off] : 0.f;
    __syncthreads();
    if (cc < off) red[t] += add;
    __syncthreads();
  }
  if (cc == 0) ald[(size_t)n*HEADS + hh] = red[t];
}

// ===================== GAT aggregation =====================
template<int HEADS, int C, bool DO_ELU>
__global__ __launch_bounds__(256) void k_gat_agg(
    const float* __restrict__ feat, const float* __restrict__ als,
    const float* __restrict__ ald, const float* __restrict__ bias,
    const int* __restrict__ rowptr, const int* __restrict__ csr_src,
    float* __restrict__ out)
{
  constexpr int F = HEADS * C;
  int n = blockIdx.x, t = threadIdx.x;
  __shared__ float m_sh[HEADS], s_sh[HEADS];
  int start = rowptr[n];
  int deg = rowptr[n+1] - start;
  int lane = t & 63, wv = t >> 6;
  for (int hh = wv; hh < HEADS; hh += F/64) {
    float adl = ald[(size_t)n*HEADS + hh];
    float mx = -INFINITY;
    for (int i = lane; i < deg; i += 64) {
      int s = csr_src[start + i];
      float lg = als[(size_t)s*HEADS + hh] + adl;
      lg = (lg > 0.f) ? lg : 0.2f * lg;
      mx = fmaxf(mx, lg);
    }
    #pragma unroll
    for (int off = 32; off; off >>= 1) mx = fmaxf(mx, __shfl_xor(mx, off));
    float sm = 0.f;
    for (int i = lane; i < deg; i += 64) {
      int s = csr_src[start + i];
      float lg = als[(size_t)s*HEADS + hh] + adl;
      lg = (lg > 0.f) ? lg : 0.2f * lg;
      sm += expf(lg - mx);
    }
    #pragma unroll
    for (int off = 32; off; off >>= 1) sm += __shfl_xor(sm, off);
    if (lane == 0) { m_sh[hh] = mx; s_sh[hh] = sm; }
  }
  __syncthreads();
  int hh = t / C;
  float adl = ald[(size_t)n*HEADS + hh];
  float mh = m_sh[hh];
  float acc = 0.f;
  for (int i = 0; i < deg; ++i) {
    int s = csr_src[start + i];
    float lg = als[(size_t)s*HEADS + hh] + adl;
    lg = (lg > 0.f) ? lg : 0.2f * lg;
    float p = expf(lg - mh);
    acc += p * feat[(size_t)s*F + t];
  }
  float o = acc / (s_sh[hh] + 1e-16f) + bias[t];
  if (DO_ELU) o = (o > 0.f) ? o : (expf(o) - 1.f);
  out[(size_t)n*F + t] = o;
}

// ===================== Tiled GEMM: C = A @ B^T + bias =====================
template<int BM, int BN, int TM, int TN>
__global__ __launch_bounds__(256) void k_gemm_bt(
    const float* __restrict__ A, const float* __restrict__ B,
    const float* __restrict__ bias, float* __restrict__ C_,
    int M, int N, int K, int act)
{
  constexpr int BK = 16;
  __shared__ float As[BK][BM + 4];
  __shared__ float Bs[BK][BN + 4];
  const int t = threadIdx.x;
  constexpr int TX = BN / TN;
  const int tx = t % TX, ty = t / TX;
  const int m0 = blockIdx.y * BM, n0 = blockIdx.x * BN;
  float acc[TM][TN] = {};
  for (int k0 = 0; k0 < K; k0 += BK) {
    #pragma unroll
    for (int idx = t; idx < BM*(BK/4); idx += 256) {
      int r = idx / (BK/4), c4 = (idx % (BK/4)) * 4;
      float4 v = *(const float4*)&A[(size_t)(m0 + r)*K + k0 + c4];
      As[c4+0][r] = v.x; As[c4+1][r] = v.y; As[c4+2][r] = v.z; As[c4+3][r] = v.w;
    }
    #pragma unroll
    for (int idx = t; idx < BN*(BK/4); idx += 256) {
      int r = idx / (BK/4), c4 = (idx % (BK/4)) * 4;
      float4 v = *(const float4*)&B[(size_t)(n0 + r)*K + k0 + c4];
      Bs[c4+0][r] = v.x; Bs[c4+1][r] = v.y; Bs[c4+2][r] = v.z; Bs[c4+3][r] = v.w;
    }
    __syncthreads();
    #pragma unroll
    for (int kk = 0; kk < BK; ++kk) {
      float a[TM], b[TN];
      #pragma unroll
      for (int i4 = 0; i4 < TM/4; ++i4) *(float4*)&a[i4*4] = *(const float4*)&As[kk][ty*TM + i4*4];
      #pragma unroll
      for (int j4 = 0; j4 < TN/4; ++j4) *(float4*)&b[j4*4] = *(const float4*)&Bs[kk][tx*TN + j4*4];
      #pragma unroll
      for (int i = 0; i < TM; ++i)
        #pragma unroll
        for (int j = 0; j < TN; ++j)
          acc[i][j] += a[i] * b[j];
    }
    __syncthreads();
  }
  #pragma unroll
  for (int i = 0; i < TM; ++i) {
    int row = m0 + ty*TM + i;
    #pragma unroll
    for (int j4 = 0; j4 < TN; j4 += 4) {
      int col = n0 + tx*TN + j4;
      float4 bv = *(const float4*)&bias[col];
      float4 o;
      o.x = acc[i][j4+0] + bv.x;
      o.y = acc[i][j4+1] + bv.y;
      o.z = acc[i][j4+2] + bv.z;
      o.w = acc[i][j4+3] + bv.w;
      if (act == 1) {
        o.x = fmaxf(o.x, 0.f); o.y = fmaxf(o.y, 0.f);
        o.z = fmaxf(o.z, 0.f); o.w = fmaxf(o.w, 0.f);
      }
      *(float4*)&C_[(size_t)row*N + col] = o;
    }
  }
}

// ===================== LayerNorm(a + res) =====================
__global__ __launch_bounds__(256) void k_ln(
    const float* __restrict__ a, const float* __restrict__ res,
    const float* __restrict__ g, const float* __restrict__ bb,
    float* __restrict__ out)
{
  int n = blockIdx.x, t = threadIdx.x;
  __shared__ float part[4];
  float v = a[(size_t)n*256 + t] + res[(size_t)n*256 + t];
  float s = v;
  #pragma unroll
  for (int off = 32; off; off >>= 1) s += __shfl_xor(s, off);
  if ((t & 63) == 0) part[t >> 6] = s;
  __syncthreads();
  float mean = (part[0] + part[1] + part[2] + part[3]) * (1.f/256.f);
  __syncthreads();
  float d = v - mean;
  float s2 = d * d;
  #pragma unroll
  for (int off = 32; off; off >>= 1) s2 += __shfl_xor(s2, off);
  if ((t & 63) == 0) part[t >> 6] = s2;
  __syncthreads();
  float var = (part[0] + part[1] + part[2] + part[3]) * (1.f/256.f);
  float rstd = rsqrtf(var + 1e-5f);
  out[(size_t)n*256 + t] = d * rstd * g[t] + bb[t];
}

// ===================== qkv fp32 -> bf16 (Q,K row-major; V transposed) =====================
__global__ __launch_bounds__(256) void k_cvtqk(const float* __restrict__ qkv,
                                               u16* __restrict__ Qb, u16* __restrict__ Kb)
{
  int idx = blockIdx.x * 256 + threadIdx.x;   // 4096 blocks -> n = idx>>8
  int n = idx >> 8;
  int c2 = (idx & 255) * 2;                   // 0..510 over q+k region
  float2 v = *(const float2*)(qkv + (size_t)n*768 + c2);
  unsigned int pack = (unsigned int)f2b(v.x) | ((unsigned int)f2b(v.y) << 16);
  int head = (c2 >> 6) & 3;
  int d = c2 & 63;
  u16* dst = (c2 < 256) ? Qb : Kb;
  *(unsigned int*)(dst + ((size_t)head*4096 + n)*64 + d) = pack;
}

__global__ __launch_bounds__(256) void k_cvtv(const float* __restrict__ qkv, u16* __restrict__ Vt)
{
  __shared__ float tile[64][68];
  int n0 = blockIdx.x * 64, head = blockIdx.y;
  int t = threadIdx.x;
  int r = t >> 4, c4 = (t & 15) * 4;
  #pragma unroll
  for (int it = 0; it < 4; ++it) {
    float4 v = *(const float4*)(qkv + (size_t)(n0 + it*16 + r)*768 + 512 + head*64 + c4);
    *(float4*)&tile[it*16 + r][c4] = v;
  }
  __syncthreads();
  int d = t >> 2, g = (t & 3) * 16;
  u16 buf[16];
  #pragma unroll
  for (int i = 0; i < 16; ++i) buf[i] = f2b(tile[g + i][d]);
  u16* dst = Vt + (size_t)head*64*4096 + (size_t)d*4096 + n0 + g;
  *(s8v*)dst = *(s8v*)&buf[0];
  *(s8v*)(dst + 8) = *(s8v*)&buf[8];
}

// ===================== bf16 MFMA flash attention =====================
// one wave per 16-query strip; K/V fragments loaded directly from global
// (L1/L2-resident); P staged via 2KB XOR-swizzled LDS.
__global__ __launch_bounds__(64) void k_attn_mfma(
    const u16* __restrict__ Qb, const u16* __restrict__ Kb,
    const u16* __restrict__ Vt, float* __restrict__ o_out)
{
  const int head = blockIdx.y;
  const int q0 = blockIdx.x * 16;
  const int l = threadIdx.x;
  const int lr = l & 15;
  const int lk = l >> 4;
  __shared__ u16 P_lds[16 * 64];
  char* Pb = (char*)P_lds;

  const u16* Qh = Qb + (size_t)head * (4096*64);
  const u16* Kh = Kb + (size_t)head * (4096*64);
  const u16* Vh = Vt + (size_t)head * (64*4096);

  const s8v qa0 = *(const s8v*)(Qh + (q0 + lr)*64 + lk*8);
  const s8v qa1 = *(const s8v*)(Qh + (q0 + lr)*64 + 32 + lk*8);

  f4v oacc[4];
  float mrow[4], lrow[4];
  #pragma unroll
  for (int r = 0; r < 4; ++r) { mrow[r] = -INFINITY; lrow[r] = 0.f; }
  #pragma unroll
  for (int d = 0; d < 4; ++d) oacc[d] = f4v{0.f, 0.f, 0.f, 0.f};

  const float CE = 0.18033688011112042f;  // log2(e)/8

  const int ra0 = lr*128 + ((lk*16) ^ ((lr & 7) << 4));
  const int ra1 = lr*128 + ((64 + lk*16) ^ ((lr & 7) << 4));

  const u16* kptr = Kh + lr*64 + lk*8;
  const u16* vptr = Vh + (size_t)lr*4096 + lk*8;

  s8v kb[8];
  #pragma unroll
  for (int nt = 0; nt < 4; ++nt) {
    kb[nt*2+0] = *(const s8v*)(kptr + nt*16*64);
    kb[nt*2+1] = *(const s8v*)(kptr + nt*16*64 + 32);
  }

  for (int kt = 0; kt < NN; kt += 64) {
    s8v vb[8];
    #pragma unroll
    for (int dt = 0; dt < 4; ++dt) {
      vb[dt*2+0] = *(const s8v*)(vptr + (size_t)dt*16*4096 + kt);
      vb[dt*2+1] = *(const s8v*)(vptr + (size_t)dt*16*4096 + kt + 32);
    }
    f4v s[4];
    #pragma unroll
    for (int nt = 0; nt < 4; ++nt) {
      s[nt] = f4v{0.f, 0.f, 0.f, 0.f};
      s[nt] = __builtin_amdgcn_mfma_f32_16x16x32_bf16(qa0, kb[nt*2+0], s[nt], 0, 0, 0);
      s[nt] = __builtin_amdgcn_mfma_f32_16x16x32_bf16(qa1, kb[nt*2+1], s[nt], 0, 0, 0);
    }
    // prefetch next K tile (wraps to 0 on last iter; harmless)
    {
      int ktn = (kt + 64) & (NN - 1);
      const u16* kp2 = kptr + (size_t)ktn*64;
      #pragma unroll
      for (int nt = 0; nt < 4; ++nt) {
        kb[nt*2+0] = *(const s8v*)(kp2 + nt*16*64);
        kb[nt*2+1] = *(const s8v*)(kp2 + nt*16*64 + 32);
      }
    }
    #pragma unroll
    for (int r = 0; r < 4; ++r) {
      float mx = fmaxf(fmaxf(s[0][r], s[1][r]), fmaxf(s[2][r], s[3][r]));
      mx = fmaxf(mx, __shfl_xor(mx, 1));
      mx = fmaxf(mx, __shfl_xor(mx, 2));
      mx = fmaxf(mx, __shfl_xor(mx, 4));
      mx = fmaxf(mx, __shfl_xor(mx, 8));
      float mo = mrow[r];
      float mn = fmaxf(mo, mx);
      mrow[r] = mn;
      float sc = exp2f((mo - mn) * CE);
      float p0 = exp2f((s[0][r] - mn) * CE);
      float p1 = exp2f((s[1][r] - mn) * CE);
      float p2 = exp2f((s[2][r] - mn) * CE);
      float p3 = exp2f((s[3][r] - mn) * CE);
      float ps = p0 + p1 + p2 + p3;
      ps += __shfl_xor(ps, 1);
      ps += __shfl_xor(ps, 2);
      ps += __shfl_xor(ps, 4);
      ps += __shfl_xor(ps, 8);
      lrow[r] = lrow[r] * sc + ps;
      oacc[0][r] *= sc; oacc[1][r] *= sc; oacc[2][r] *= sc; oacc[3][r] *= sc;
      int q = lk*4 + r;
      int base = q*128;
      int swz = (q & 7) << 4;
      *(u16*)(Pb + base + ((0*32 + lr*2) ^ swz)) = f2b(p0);
      *(u16*)(Pb + base + ((1*32 + lr*2) ^ swz)) = f2b(p1);
      *(u16*)(Pb + base + ((2*32 + lr*2) ^ swz)) = f2b(p2);
      *(u16*)(Pb + base + ((3*32 + lr*2) ^ swz)) = f2b(p3);
    }
    s8v pa0 = *(const s8v*)(Pb + ra0);
    s8v pa1 = *(const s8v*)(Pb + ra1);
    #pragma unroll
    for (int dt = 0; dt < 4; ++dt) {
      oacc[dt] = __builtin_amdgcn_mfma_f32_16x16x32_bf16(pa0, vb[dt*2+0], oacc[dt], 0, 0, 0);
      oacc[dt] = __builtin_amdgcn_mfma_f32_16x16x32_bf16(pa1, vb[dt*2+1], oacc[dt], 0, 0, 0);
    }
  }
  #pragma unroll
  for (int r = 0; r < 4; ++r) {
    float inv = 1.f / lrow[r];
    int q = q0 + lk*4 + r;
    #pragma unroll
    for (int dt = 0; dt < 4; ++dt)
      o_out[(size_t)q*256 + head*64 + dt*16 + lr] = oacc[dt][r] * inv;
  }
}

// ===================== host launcher =====================
extern "C" void kernel_launch(void* const* d_in, const int* in_sizes, int n_in,
                              void* d_out, int out_size, void* d_ws, size_t ws_size,
                              hipStream_t stream)
{
  const float* x       = (const float*)d_in[0];
  const int*   ei      = (const int*)d_in[1];
  const float* gat1_w  = (const float*)d_in[2];
  const float* gat1_as = (const float*)d_in[3];
  const float* gat1_ad = (const float*)d_in[4];
  const float* gat1_b  = (const float*)d_in[5];
  const float* inp_w   = (const float*)d_in[6];
  const float* inp_b   = (const float*)d_in[7];
  const float* outp_w  = (const float*)d_in[8];
  const float* outp_b  = (const float*)d_in[9];
  const float* lin1_w  = (const float*)d_in[10];
  const float* lin1_b  = (const float*)d_in[11];
  const float* lin2_w  = (const float*)d_in[12];
  const float* lin2_b  = (const float*)d_in[13];
  const float* ln1_g   = (const float*)d_in[14];
  const float* ln1_bb  = (const float*)d_in[15];
  const float* ln2_g   = (const float*)d_in[16];
  const float* ln2_bb  = (const float*)d_in[17];
  const float* gat2_w  = (const float*)d_in[18];
  const float* gat2_as = (const float*)d_in[19];
  const float* gat2_ad = (const float*)d_in[20];
  const float* gat2_b  = (const float*)d_in[21];
  float* out = (float*)d_out;
  (void)in_sizes; (void)n_in; (void)out_size; (void)ws_size;

  char* ws = (char*)d_ws;
  size_t off = 0;
  auto nxt = [&](size_t bytes) { size_t r = off; off += (bytes + 255) & ~(size_t)255; return r; };
  int* deg      = (int*)(ws + nxt((size_t)NN*4));
  int* cursor   = (int*)(ws + nxt((size_t)NN*4));
  int* rowptr   = (int*)(ws + nxt((size_t)(NN+1)*4));
  int* csr_src  = (int*)(ws + nxt((size_t)EE*4));
  float* feat1  = (float*)(ws + nxt((size_t)NN*256*4));
  float* al1s   = (float*)(ws + nxt((size_t)NN*4*4));
  float* al1d   = (float*)(ws + nxt((size_t)NN*4*4));
  float* hgat1  = (float*)(ws + nxt((size_t)NN*256*4));
  float* qkvb   = (float*)(ws + nxt((size_t)NN*768*4));
  float* attno  = (float*)(ws + nxt((size_t)NN*256*4));
  float* tmp256 = (float*)(ws + nxt((size_t)NN*256*4));
  float* hln1   = (float*)(ws + nxt((size_t)NN*256*4));
  float* ff1    = (float*)(ws + nxt((size_t)NN*2048*4));
  float* hln2   = (float*)(ws + nxt((size_t)NN*256*4));
  float* feat2  = (float*)(ws + nxt((size_t)NN*128*4));
  float* al2s   = (float*)(ws + nxt((size_t)NN*4));
  float* al2d   = (float*)(ws + nxt((size_t)NN*4));

  // bf16 Q/K/V buffers alias ff1 (ff1 is written only after attention is done)
  u16* Qb = (u16*)ff1;
  u16* Kb = Qb + (size_t)4*4096*64;
  u16* Vt = Kb + (size_t)4*4096*64;

  hipMemsetAsync(deg, 0, (size_t)NN*4, stream);
  hipMemsetAsync(cursor, 0, (size_t)NN*4, stream);
  k_count<<<(EE+255)/256, 256, 0, stream>>>(ei, deg);
  k_scan<<<1, 1024, 0, stream>>>(deg, rowptr);
  k_scatter<<<(EE+255)/256, 256, 0, stream>>>(ei, rowptr, cursor, csr_src);

  // GAT layer 1 + ELU
  k_gat_proj<128,256,4,64><<<NN, 256, 0, stream>>>(x, gat1_w, gat1_as, gat1_ad, feat1, al1s, al1d);
  k_gat_agg<4,64,true><<<NN, 256, 0, stream>>>(feat1, al1s, al1d, gat1_b, rowptr, csr_src, hgat1);

  // Transformer encoder layer
  k_gemm_bt<64,64,4,4><<<dim3(768/64, NN/64), 256, 0, stream>>>(hgat1, inp_w, inp_b, qkvb, NN, 768, 256, 0);
  k_cvtqk<<<4096, 256, 0, stream>>>(qkvb, Qb, Kb);
  k_cvtv<<<dim3(64, 4), 256, 0, stream>>>(qkvb, Vt);
  k_attn_mfma<<<dim3(NN/16, 4), 64, 0, stream>>>(Qb, Kb, Vt, attno);
  k_gemm_bt<64,64,4,4><<<dim3(256/64, NN/64), 256, 0, stream>>>(attno, outp_w, outp_b, tmp256, NN, 256, 256, 0);
  k_ln<<<NN, 256, 0, stream>>>(tmp256, hgat1, ln1_g, ln1_bb, hln1);
  k_gemm_bt<128,128,8,8><<<dim3(2048/128, NN/128), 256, 0, stream>>>(hln1, lin1_w, lin1_b, ff1, NN, 2048, 256, 1);
  k_gemm_bt<64,64,4,4><<<dim3(256/64, NN/64), 256, 0, stream>>>(ff1, lin2_w, lin2_b, tmp256, NN, 256, 2048, 0);
  k_ln<<<NN, 256, 0, stream>>>(tmp256, hln1, ln2_g, ln2_bb, hln2);

  // GAT layer 2 -> final output
  k_gat_proj<256,128,1,128><<<NN, 128, 0, stream>>>(hln2, gat2_w, gat2_as, gat2_ad, feat2, al2s, al2d);
  k_gat_agg<1,128,false><<<NN, 128, 0, stream>>>(feat2, al2s, al2d, gat2_b, rowptr, csr_src, out);
}

// Round 4
// 508.767 us; speedup vs baseline: 1.9141x; 1.2609x over previous
//
#include <hip/hip_runtime.h>
#include <hip/hip_bf16.h>
#include <math.h>

#define NN 4096
#define NE 131072
#define EE (NE + NN)

typedef unsigned short u16;
typedef short s8v __attribute__((ext_vector_type(8)));
typedef float f4v __attribute__((ext_vector_type(4)));

__device__ inline u16 f2b(float f) {
  __hip_bfloat16 h = __float2bfloat16(f);
  return __builtin_bit_cast(u16, h);
}

// ===================== CSR build =====================
__global__ void k_count(const int* __restrict__ ei, int* __restrict__ deg) {
  int e = blockIdx.x * 256 + threadIdx.x;
  if (e >= EE) return;
  int dst = (e < NE) ? ei[NE + e] : (e - NE);
  atomicAdd(&deg[dst], 1);
}

__global__ __launch_bounds__(1024) void k_scan(const int* __restrict__ deg, int* __restrict__ rowptr) {
  __shared__ int lds[1024];
  int t = threadIdx.x;
  int v0 = deg[t*4+0], v1 = deg[t*4+1], v2 = deg[t*4+2], v3 = deg[t*4+3];
  int s1 = v0+v1, s2 = s1+v2, s3 = s2+v3;
  lds[t] = s3;
  __syncthreads();
  for (int off = 1; off < 1024; off <<= 1) {
    int add = (t >= off) ? lds[t-off] : 0;
    __syncthreads();
    lds[t] += add;
    __syncthreads();
  }
  int base = lds[t] - s3;
  rowptr[t*4+1] = base + v0;
  rowptr[t*4+2] = base + s1;
  rowptr[t*4+3] = base + s2;
  rowptr[t*4+4] = base + s3;
  if (t == 0) rowptr[0] = 0;
}

__global__ void k_scatter(const int* __restrict__ ei, const int* __restrict__ rowptr,
                          int* __restrict__ cursor, int* __restrict__ csr_src) {
  int e = blockIdx.x * 256 + threadIdx.x;
  if (e >= EE) return;
  int src, dst;
  if (e < NE) { src = ei[e]; dst = ei[NE + e]; }
  else { src = e - NE; dst = src; }
  int pos = rowptr[dst] + atomicAdd(&cursor[dst], 1);
  csr_src[pos] = src;
}

// ===================== GAT projection =====================
template<int K, int F, int HEADS, int C>
__global__ __launch_bounds__(256) void k_gat_proj(
    const float* __restrict__ x, const float* __restrict__ W,
    const float* __restrict__ asrc, const float* __restrict__ adst,
    float* __restrict__ feat, float* __restrict__ als, float* __restrict__ ald)
{
  int n = blockIdx.x, t = threadIdx.x;
  __shared__ float xrow[K];
  __shared__ float red[F];
  for (int i = t; i < K; i += F) xrow[i] = x[(size_t)n*K + i];
  __syncthreads();
  const float4* wr = (const float4*)(W + (size_t)t*K);
  const float4* xr = (const float4*)xrow;
  float acc = 0.f;
  #pragma unroll 8
  for (int k4 = 0; k4 < K/4; ++k4) {
    float4 w = wr[k4], xx = xr[k4];
    acc += w.x*xx.x + w.y*xx.y + w.z*xx.z + w.w*xx.w;
  }
  feat[(size_t)n*F + t] = acc;
  int hh = t / C, cc = t % C;
  red[t] = acc * asrc[t];
  __syncthreads();
  for (int off = C/2; off > 0; off >>= 1) {
    float add = (cc < off) ? red[t + off] : 0.f;
    __syncthreads();
    if (cc < off) red[t] += add;
    __syncthreads();
  }
  if (cc == 0) als[(size_t)n*HEADS + hh] = red[t];
  __syncthreads();
  red[t] = acc * adst[t];
  __syncthreads();
  for (int off = C/2; off > 0; off >>= 1) {
    float add = (cc < off) ? red[t + off] : 0.f;
    __syncthreads();
    if (cc < off) red[t] += add;
    __syncthreads();
  }
  if (cc == 0) ald[(size_t)n*HEADS + hh] = red[t];
}

// ===================== GAT aggregation =====================
template<int HEADS, int C, bool DO_ELU>
__global__ __launch_bounds__(256) void k_gat_agg(
    const float* __restrict__ feat, const float* __restrict__ als,
    const float* __restrict__ ald, const float* __restrict__ bias,
    const int* __restrict__ rowptr, const int* __restrict__ csr_src,
    float* __restrict__ out)
{
  constexpr int F = HEADS * C;
  int n = blockIdx.x, t = threadIdx.x;
  __shared__ float m_sh[HEADS], s_sh[HEADS];
  int start = rowptr[n];
  int deg = rowptr[n+1] - start;
  int lane = t & 63, wv = t >> 6;
  for (int hh = wv; hh < HEADS; hh += F/64) {
    float adl = ald[(size_t)n*HEADS + hh];
    float mx = -INFINITY;
    for (int i = lane; i < deg; i += 64) {
      int s = csr_src[start + i];
      float lg = als[(size_t)s*HEADS + hh] + adl;
      lg = (lg > 0.f) ? lg : 0.2f * lg;
      mx = fmaxf(mx, lg);
    }
    #pragma unroll
    for (int off = 32; off; off >>= 1) mx = fmaxf(mx, __shfl_xor(mx, off));
    float sm = 0.f;
    for (int i = lane; i < deg; i += 64) {
      int s = csr_src[start + i];
      float lg = als[(size_t)s*HEADS + hh] + adl;
      lg = (lg > 0.f) ? lg : 0.2f * lg;
      sm += expf(lg - mx);
    }
    #pragma unroll
    for (int off = 32; off; off >>= 1) sm += __shfl_xor(sm, off);
    if (lane == 0) { m_sh[hh] = mx; s_sh[hh] = sm; }
  }
  __syncthreads();
  int hh = t / C;
  float adl = ald[(size_t)n*HEADS + hh];
  float mh = m_sh[hh];
  float acc = 0.f;
  for (int i = 0; i < deg; ++i) {
    int s = csr_src[start + i];
    float lg = als[(size_t)s*HEADS + hh] + adl;
    lg = (lg > 0.f) ? lg : 0.2f * lg;
    float p = expf(lg - mh);
    acc += p * feat[(size_t)s*F + t];
  }
  float o = acc / (s_sh[hh] + 1e-16f) + bias[t];
  if (DO_ELU) o = (o > 0.f) ? o : (expf(o) - 1.f);
  out[(size_t)n*F + t] = o;
}

// ===================== fp32 -> bf16 conversion =====================
__global__ __launch_bounds__(256) void k_f2b(const float* __restrict__ in,
                                             u16* __restrict__ out, int n4)
{
  int i = blockIdx.x * 256 + threadIdx.x;
  if (i >= n4) return;
  float4 v = ((const float4*)in)[i];
  u16 r[4] = {f2b(v.x), f2b(v.y), f2b(v.z), f2b(v.w)};
  *(uint2*)(out + (size_t)i*4) = *(uint2*)r;
}

// ===================== bf16 MFMA GEMM: C[M,N] = A[M,K] @ B[N,K]^T + bias =====================
// 64x64 block tile, 4 waves (2x2), wave tile 32x32, BK=64, XOR-swizzled LDS.
template<int RELU, int OBF16>
__global__ __launch_bounds__(256) void k_gemm_mfma(
    const u16* __restrict__ A, const u16* __restrict__ B,
    const float* __restrict__ bias, float* __restrict__ Cf, u16* __restrict__ Cb,
    int M, int N, int K)
{
  __shared__ u16 Al[64*64];
  __shared__ u16 Bl[64*64];
  char* Ab = (char*)Al;
  char* Bb = (char*)Bl;
  const int t = threadIdx.x;
  const int lane = t & 63;
  const int lr = lane & 15, lk = lane >> 4;
  const int wid = t >> 6;
  const int wm = wid & 1, wn = wid >> 1;
  const int m0 = blockIdx.y * 64, n0 = blockIdx.x * 64;

  f4v acc[2][2];
  #pragma unroll
  for (int mi = 0; mi < 2; ++mi)
    #pragma unroll
    for (int ni = 0; ni < 2; ++ni)
      acc[mi][ni] = f4v{0.f, 0.f, 0.f, 0.f};

  for (int k0 = 0; k0 < K; k0 += 64) {
    #pragma unroll
    for (int i = 0; i < 2; ++i) {
      int idx = t + i*256;
      int row = idx >> 3, ch = idx & 7;
      s8v av = *(const s8v*)(A + (size_t)(m0 + row)*K + k0 + ch*8);
      *(s8v*)(Ab + row*128 + ((ch*16) ^ ((row & 7) << 4))) = av;
      s8v bv = *(const s8v*)(B + (size_t)(n0 + row)*K + k0 + ch*8);
      *(s8v*)(Bb + row*128 + ((ch*16) ^ ((row & 7) << 4))) = bv;
    }
    __syncthreads();
    #pragma unroll
    for (int ks = 0; ks < 2; ++ks) {
      s8v af[2], bfr[2];
      #pragma unroll
      for (int mi = 0; mi < 2; ++mi) {
        int row = wm*32 + mi*16 + lr;
        int ch = ks*4 + lk;
        af[mi] = *(const s8v*)(Ab + row*128 + ((ch*16) ^ ((row & 7) << 4)));
      }
      #pragma unroll
      for (int ni = 0; ni < 2; ++ni) {
        int row = wn*32 + ni*16 + lr;
        int ch = ks*4 + lk;
        bfr[ni] = *(const s8v*)(Bb + row*128 + ((ch*16) ^ ((row & 7) << 4)));
      }
      #pragma unroll
      for (int mi = 0; mi < 2; ++mi)
        #pragma unroll
        for (int ni = 0; ni < 2; ++ni)
          acc[mi][ni] = __builtin_amdgcn_mfma_f32_16x16x32_bf16(af[mi], bfr[ni], acc[mi][ni], 0, 0, 0);
    }
    __syncthreads();
  }
  #pragma unroll
  for (int ni = 0; ni < 2; ++ni) {
    int col = n0 + wn*32 + ni*16 + lr;
    float bc = bias[col];
    #pragma unroll
    for (int mi = 0; mi < 2; ++mi) {
      #pragma unroll
      for (int r = 0; r < 4; ++r) {
        int row = m0 + wm*32 + mi*16 + lk*4 + r;
        float v = acc[mi][ni][r] + bc;
        if (RELU) v = fmaxf(v, 0.f);
        if (OBF16) Cb[(size_t)row*N + col] = f2b(v);
        else       Cf[(size_t)row*N + col] = v;
      }
    }
  }
}

// ===================== LayerNorm(a + res) =====================
__global__ __launch_bounds__(256) void k_ln(
    const float* __restrict__ a, const float* __restrict__ res,
    const float* __restrict__ g, const float* __restrict__ bb,
    float* __restrict__ out)
{
  int n = blockIdx.x, t = threadIdx.x;
  __shared__ float part[4];
  float v = a[(size_t)n*256 + t] + res[(size_t)n*256 + t];
  float s = v;
  #pragma unroll
  for (int off = 32; off; off >>= 1) s += __shfl_xor(s, off);
  if ((t & 63) == 0) part[t >> 6] = s;
  __syncthreads();
  float mean = (part[0] + part[1] + part[2] + part[3]) * (1.f/256.f);
  __syncthreads();
  float d = v - mean;
  float s2 = d * d;
  #pragma unroll
  for (int off = 32; off; off >>= 1) s2 += __shfl_xor(s2, off);
  if ((t & 63) == 0) part[t >> 6] = s2;
  __syncthreads();
  float var = (part[0] + part[1] + part[2] + part[3]) * (1.f/256.f);
  float rstd = rsqrtf(var + 1e-5f);
  out[(size_t)n*256 + t] = d * rstd * g[t] + bb[t];
}

// ===================== qkv fp32 -> bf16 (Q,K row-major; V transposed) =====================
__global__ __launch_bounds__(256) void k_cvtqk(const float* __restrict__ qkv,
                                               u16* __restrict__ Qb, u16* __restrict__ Kb)
{
  int idx = blockIdx.x * 256 + threadIdx.x;
  int n = idx >> 8;
  int c2 = (idx & 255) * 2;
  float2 v = *(const float2*)(qkv + (size_t)n*768 + c2);
  unsigned int pack = (unsigned int)f2b(v.x) | ((unsigned int)f2b(v.y) << 16);
  int head = (c2 >> 6) & 3;
  int d = c2 & 63;
  u16* dst = (c2 < 256) ? Qb : Kb;
  *(unsigned int*)(dst + ((size_t)head*4096 + n)*64 + d) = pack;
}

__global__ __launch_bounds__(256) void k_cvtv(const float* __restrict__ qkv, u16* __restrict__ Vt)
{
  __shared__ float tile[64][68];
  int n0 = blockIdx.x * 64, head = blockIdx.y;
  int t = threadIdx.x;
  int r = t >> 4, c4 = (t & 15) * 4;
  #pragma unroll
  for (int it = 0; it < 4; ++it) {
    float4 v = *(const float4*)(qkv + (size_t)(n0 + it*16 + r)*768 + 512 + head*64 + c4);
    *(float4*)&tile[it*16 + r][c4] = v;
  }
  __syncthreads();
  int d = t >> 2, g = (t & 3) * 16;
  u16 buf[16];
  #pragma unroll
  for (int i = 0; i < 16; ++i) buf[i] = f2b(tile[g + i][d]);
  u16* dst = Vt + (size_t)head*64*4096 + (size_t)d*4096 + n0 + g;
  *(s8v*)dst = *(s8v*)&buf[0];
  *(s8v*)(dst + 8) = *(s8v*)&buf[8];
}

// ===================== bf16 MFMA flash attention, split-K over keys =====================
// grid (256 strips, 4 heads, 4 splits); one wave per block; each split covers 1024 keys.
// Emits partial (m, l, unnormalized O) merged by k_attn_comb.
__global__ __launch_bounds__(64) void k_attn_split(
    const u16* __restrict__ Qb, const u16* __restrict__ Kb,
    const u16* __restrict__ Vt, float* __restrict__ op,
    float* __restrict__ mbuf, float* __restrict__ lbuf)
{
  const int strip = blockIdx.x;
  const int head = blockIdx.y;
  const int split = blockIdx.z;
  const int q0 = strip * 16;
  const int kt0 = split << 10;
  const int kt1 = kt0 + 1024;
  const int base = ((head << 8) + strip) * 4 + split;
  const int l = threadIdx.x;
  const int lr = l & 15;
  const int lk = l >> 4;
  __shared__ u16 P_lds[16 * 64];
  char* Pb = (char*)P_lds;

  const u16* Qh = Qb + (size_t)head * (4096*64);
  const u16* Kh = Kb + (size_t)head * (4096*64);
  const u16* Vh = Vt + (size_t)head * (64*4096);

  const s8v qa0 = *(const s8v*)(Qh + (q0 + lr)*64 + lk*8);
  const s8v qa1 = *(const s8v*)(Qh + (q0 + lr)*64 + 32 + lk*8);

  f4v oacc[4];
  float mrow[4], lrow[4];
  #pragma unroll
  for (int r = 0; r < 4; ++r) { mrow[r] = -INFINITY; lrow[r] = 0.f; }
  #pragma unroll
  for (int d = 0; d < 4; ++d) oacc[d] = f4v{0.f, 0.f, 0.f, 0.f};

  const float CE = 0.18033688011112042f;  // log2(e)/8

  const int ra0 = lr*128 + ((lk*16) ^ ((lr & 7) << 4));
  const int ra1 = lr*128 + ((64 + lk*16) ^ ((lr & 7) << 4));

  const u16* kptr = Kh + lr*64 + lk*8;
  const u16* vptr = Vh + (size_t)lr*4096 + lk*8;

  s8v kb[8];
  {
    const u16* kp0 = kptr + (size_t)kt0*64;
    #pragma unroll
    for (int nt = 0; nt < 4; ++nt) {
      kb[nt*2+0] = *(const s8v*)(kp0 + nt*16*64);
      kb[nt*2+1] = *(const s8v*)(kp0 + nt*16*64 + 32);
    }
  }

  for (int kt = kt0; kt < kt1; kt += 64) {
    s8v vb[8];
    #pragma unroll
    for (int dt = 0; dt < 4; ++dt) {
      vb[dt*2+0] = *(const s8v*)(vptr + (size_t)dt*16*4096 + kt);
      vb[dt*2+1] = *(const s8v*)(vptr + (size_t)dt*16*4096 + kt + 32);
    }
    f4v s[4];
    #pragma unroll
    for (int nt = 0; nt < 4; ++nt) {
      s[nt] = f4v{0.f, 0.f, 0.f, 0.f};
      s[nt] = __builtin_amdgcn_mfma_f32_16x16x32_bf16(qa0, kb[nt*2+0], s[nt], 0, 0, 0);
      s[nt] = __builtin_amdgcn_mfma_f32_16x16x32_bf16(qa1, kb[nt*2+1], s[nt], 0, 0, 0);
    }
    // prefetch next K tile (wraps to kt0 on last iter; harmless)
    {
      int ktn = kt + 64;
      if (ktn >= kt1) ktn = kt0;
      const u16* kp2 = kptr + (size_t)ktn*64;
      #pragma unroll
      for (int nt = 0; nt < 4; ++nt) {
        kb[nt*2+0] = *(const s8v*)(kp2 + nt*16*64);
        kb[nt*2+1] = *(const s8v*)(kp2 + nt*16*64 + 32);
      }
    }
    #pragma unroll
    for (int r = 0; r < 4; ++r) {
      float mx = fmaxf(fmaxf(s[0][r], s[1][r]), fmaxf(s[2][r], s[3][r]));
      mx = fmaxf(mx, __shfl_xor(mx, 1));
      mx = fmaxf(mx, __shfl_xor(mx, 2));
      mx = fmaxf(mx, __shfl_xor(mx, 4));
      mx = fmaxf(mx, __shfl_xor(mx, 8));
      float mo = mrow[r];
      float mn = fmaxf(mo, mx);
      mrow[r] = mn;
      float sc = exp2f((mo - mn) * CE);
      float p0 = exp2f((s[0][r] - mn) * CE);
      float p1 = exp2f((s[1][r] - mn) * CE);
      float p2 = exp2f((s[2][r] - mn) * CE);
      float p3 = exp2f((s[3][r] - mn) * CE);
      float ps = p0 + p1 + p2 + p3;
      ps += __shfl_xor(ps, 1);
      ps += __shfl_xor(ps, 2);
      ps += __shfl_xor(ps, 4);
      ps += __shfl_xor(ps, 8);
      lrow[r] = lrow[r] * sc + ps;
      oacc[0][r] *= sc; oacc[1][r] *= sc; oacc[2][r] *= sc; oacc[3][r] *= sc;
      int q = lk*4 + r;
      int pbase = q*128;
      int swz = (q & 7) << 4;
      *(u16*)(Pb + pbase + ((0*32 + lr*2) ^ swz)) = f2b(p0);
      *(u16*)(Pb + pbase + ((1*32 + lr*2) ^ swz)) = f2b(p1);
      *(u16*)(Pb + pbase + ((2*32 + lr*2) ^ swz)) = f2b(p2);
      *(u16*)(Pb + pbase + ((3*32 + lr*2) ^ swz)) = f2b(p3);
    }
    s8v pa0 = *(const s8v*)(Pb + ra0);
    s8v pa1 = *(const s8v*)(Pb + ra1);
    #pragma unroll
    for (int dt = 0; dt < 4; ++dt) {
      oacc[dt] = __builtin_amdgcn_mfma_f32_16x16x32_bf16(pa0, vb[dt*2+0], oacc[dt], 0, 0, 0);
      oacc[dt] = __builtin_amdgcn_mfma_f32_16x16x32_bf16(pa1, vb[dt*2+1], oacc[dt], 0, 0, 0);
    }
  }
  #pragma unroll
  for (int r = 0; r < 4; ++r) {
    int q = lk*4 + r;
    if (lr == 0) {
      mbuf[base*16 + q] = mrow[r];
      lbuf[base*16 + q] = lrow[r];
    }
    #pragma unroll
    for (int dt = 0; dt < 4; ++dt)
      op[(size_t)base*1024 + q*64 + dt*16 + lr] = oacc[dt][r];
  }
}

__global__ __launch_bounds__(64) void k_attn_comb(
    const float* __restrict__ op, const float* __restrict__ mbuf,
    const float* __restrict__ lbuf, float* __restrict__ attno)
{
  const int strip = blockIdx.x;
  const int head = blockIdx.y;
  const int d = threadIdx.x;
  const int b0 = ((head << 8) + strip) * 4;
  const float CE = 0.18033688011112042f;
  #pragma unroll 4
  for (int q = 0; q < 16; ++q) {
    float m[4];
    float M = -INFINITY;
    #pragma unroll
    for (int s = 0; s < 4; ++s) { m[s] = mbuf[(b0+s)*16 + q]; M = fmaxf(M, m[s]); }
    float L = 0.f, o = 0.f;
    #pragma unroll
    for (int s = 0; s < 4; ++s) {
      float w = exp2f((m[s] - M) * CE);
      L += w * lbuf[(b0+s)*16 + q];
      o += w * op[(size_t)(b0+s)*1024 + q*64 + d];
    }
    attno[(size_t)(strip*16 + q)*256 + (head << 6) + d] = o / L;
  }
}

// ===================== host launcher =====================
extern "C" void kernel_launch(void* const* d_in, const int* in_sizes, int n_in,
                              void* d_out, int out_size, void* d_ws, size_t ws_size,
                              hipStream_t stream)
{
  const float* x       = (const float*)d_in[0];
  const int*   ei      = (const int*)d_in[1];
  const float* gat1_w  = (const float*)d_in[2];
  const float* gat1_as = (const float*)d_in[3];
  const float* gat1_ad = (const float*)d_in[4];
  const float* gat1_b  = (const float*)d_in[5];
  const float* inp_w   = (const float*)d_in[6];
  const float* inp_b   = (const float*)d_in[7];
  const float* outp_w  = (const float*)d_in[8];
  const float* outp_b  = (const float*)d_in[9];
  const float* lin1_w  = (const float*)d_in[10];
  const float* lin1_b  = (const float*)d_in[11];
  const float* lin2_w  = (const float*)d_in[12];
  const float* lin2_b  = (const float*)d_in[13];
  const float* ln1_g   = (const float*)d_in[14];
  const float* ln1_bb  = (const float*)d_in[15];
  const float* ln2_g   = (const float*)d_in[16];
  const float* ln2_bb  = (const float*)d_in[17];
  const float* gat2_w  = (const float*)d_in[18];
  const float* gat2_as = (const float*)d_in[19];
  const float* gat2_ad = (const float*)d_in[20];
  const float* gat2_b  = (const float*)d_in[21];
  float* out = (float*)d_out;
  (void)in_sizes; (void)n_in; (void)out_size; (void)ws_size;

  char* ws = (char*)d_ws;
  size_t off = 0;
  auto nxt = [&](size_t bytes) { size_t r = off; off += (bytes + 255) & ~(size_t)255; return r; };
  int* deg      = (int*)(ws + nxt((size_t)NN*4));
  int* cursor   = (int*)(ws + nxt((size_t)NN*4));
  int* rowptr   = (int*)(ws + nxt((size_t)(NN+1)*4));
  int* csr_src  = (int*)(ws + nxt((size_t)EE*4));
  float* feat1  = (float*)(ws + nxt((size_t)NN*256*4));
  float* al1s   = (float*)(ws + nxt((size_t)NN*4*4));
  float* al1d   = (float*)(ws + nxt((size_t)NN*4*4));
  float* hgat1  = (float*)(ws + nxt((size_t)NN*256*4));
  float* qkvb   = (float*)(ws + nxt((size_t)NN*768*4));   // fp32 qkv; later overlaid by ff1_b
  float* attno  = (float*)(ws + nxt((size_t)NN*256*4));   // fp32 attn out; later overlaid by ff1_b
  float* tmp256 = (float*)(ws + nxt((size_t)NN*256*4));
  float* hln1   = (float*)(ws + nxt((size_t)NN*256*4));
  char*  arena  = (char*)(ws + nxt((size_t)NN*2048*4));   // 32MB attention arena
  float* hln2   = (float*)(ws + nxt((size_t)NN*256*4));
  float* feat2  = (float*)(ws + nxt((size_t)NN*128*4));
  float* al2s   = (float*)(ws + nxt((size_t)NN*4));
  float* al2d   = (float*)(ws + nxt((size_t)NN*4));
  u16* hgat1_b  = (u16*)(ws + nxt((size_t)NN*256*2));
  u16* attno_b  = (u16*)(ws + nxt((size_t)NN*256*2));
  u16* hln1_b   = (u16*)(ws + nxt((size_t)NN*256*2));
  u16* inp_w_b  = (u16*)(ws + nxt((size_t)768*256*2));
  u16* outp_w_b = (u16*)(ws + nxt((size_t)256*256*2));
  u16* lin1_w_b = (u16*)(ws + nxt((size_t)2048*256*2));
  u16* lin2_w_b = (u16*)(ws + nxt((size_t)256*2048*2));

  // attention arena layout (within old ff1 32MB slot)
  u16* Qb = (u16*)arena;                       // 4*4096*64 u16 = 2MB
  u16* Kb = Qb + (size_t)4*4096*64;            // 2MB
  u16* Vt = Kb + (size_t)4*4096*64;            // 2MB
  float* op   = (float*)(Vt + (size_t)4*4096*64); // 4*256*4*1024 f32 = 16.78MB
  float* mbuf = op + (size_t)4096*1024;        // 4096*16 f32
  float* lbuf = mbuf + (size_t)4096*16;        // 4096*16 f32

  // ff1 bf16 output overlays qkvb+attno (exactly 16MB, both dead by lin1 time)
  u16* ff1_b = (u16*)qkvb;

  hipMemsetAsync(deg, 0, (size_t)NN*4, stream);
  hipMemsetAsync(cursor, 0, (size_t)NN*4, stream);
  k_count<<<(EE+255)/256, 256, 0, stream>>>(ei, deg);
  k_scan<<<1, 1024, 0, stream>>>(deg, rowptr);
  k_scatter<<<(EE+255)/256, 256, 0, stream>>>(ei, rowptr, cursor, csr_src);

  // convert weights to bf16
  k_f2b<<<192, 256, 0, stream>>>(inp_w, inp_w_b, 768*256/4);
  k_f2b<<<64, 256, 0, stream>>>(outp_w, outp_w_b, 256*256/4);
  k_f2b<<<512, 256, 0, stream>>>(lin1_w, lin1_w_b, 2048*256/4);
  k_f2b<<<512, 256, 0, stream>>>(lin2_w, lin2_w_b, 256*2048/4);

  // GAT layer 1 + ELU
  k_gat_proj<128,256,4,64><<<NN, 256, 0, stream>>>(x, gat1_w, gat1_as, gat1_ad, feat1, al1s, al1d);
  k_gat_agg<4,64,true><<<NN, 256, 0, stream>>>(feat1, al1s, al1d, gat1_b, rowptr, csr_src, hgat1);

  // Transformer encoder layer
  k_f2b<<<1024, 256, 0, stream>>>(hgat1, hgat1_b, NN*256/4);
  k_gemm_mfma<0,0><<<dim3(768/64, NN/64), 256, 0, stream>>>(hgat1_b, inp_w_b, inp_b, qkvb, nullptr, NN, 768, 256);
  k_cvtqk<<<4096, 256, 0, stream>>>(qkvb, Qb, Kb);
  k_cvtv<<<dim3(64, 4), 256, 0, stream>>>(qkvb, Vt);
  k_attn_split<<<dim3(256, 4, 4), 64, 0, stream>>>(Qb, Kb, Vt, op, mbuf, lbuf);
  k_attn_comb<<<dim3(256, 4), 64, 0, stream>>>(op, mbuf, lbuf, attno);
  k_f2b<<<1024, 256, 0, stream>>>(attno, attno_b, NN*256/4);
  k_gemm_mfma<0,0><<<dim3(256/64, NN/64), 256, 0, stream>>>(attno_b, outp_w_b, outp_b, tmp256, nullptr, NN, 256, 256);
  k_ln<<<NN, 256, 0, stream>>>(tmp256, hgat1, ln1_g, ln1_bb, hln1);
  k_f2b<<<1024, 256, 0, stream>>>(hln1, hln1_b, NN*256/4);
  k_gemm_mfma<1,1><<<dim3(2048/64, NN/64), 256, 0, stream>>>(hln1_b, lin1_w_b, lin1_b, nullptr, ff1_b, NN, 2048, 256);
  k_gemm_mfma<0,0><<<dim3(256/64, NN/64), 256, 0, stream>>>(ff1_b, lin2_w_b, lin2_b, tmp256, nullptr, NN, 256, 2048);
  k_ln<<<NN, 256, 0, stream>>>(tmp256, hln1, ln2_g, ln2_bb, hln2);

  // GAT layer 2 -> final output
  k_gat_proj<256,128,1,128><<<NN, 128, 0, stream>>>(hln2, gat2_w, gat2_as, gat2_ad, feat2, al2s, al2d);
  k_gat_agg<1,128,false><<<NN, 128, 0, stream>>>(feat2, al2s, al2d, gat2_b, rowptr, csr_src, out);
}

// Round 5
// 428.467 us; speedup vs baseline: 2.2728x; 1.1874x over previous
//
#include <hip/hip_runtime.h>
#include <hip/hip_bf16.h>
#include <math.h>

#define NN 4096
#define NE 131072
#define EE (NE + NN)

typedef unsigned short u16;
typedef short s8v __attribute__((ext_vector_type(8)));
typedef float f4v __attribute__((ext_vector_type(4)));
typedef float f16v __attribute__((ext_vector_type(16)));

__device__ inline u16 f2b(float f) {
  __hip_bfloat16 h = __float2bfloat16(f);
  return __builtin_bit_cast(u16, h);
}

// ===================== CSR build =====================
__global__ void k_count(const int* __restrict__ ei, int* __restrict__ deg) {
  int e = blockIdx.x * 256 + threadIdx.x;
  if (e >= EE) return;
  int dst = (e < NE) ? ei[NE + e] : (e - NE);
  atomicAdd(&deg[dst], 1);
}

__global__ __launch_bounds__(1024) void k_scan(const int* __restrict__ deg, int* __restrict__ rowptr) {
  __shared__ int lds[1024];
  int t = threadIdx.x;
  int v0 = deg[t*4+0], v1 = deg[t*4+1], v2 = deg[t*4+2], v3 = deg[t*4+3];
  int s1 = v0+v1, s2 = s1+v2, s3 = s2+v3;
  lds[t] = s3;
  __syncthreads();
  for (int off = 1; off < 1024; off <<= 1) {
    int add = (t >= off) ? lds[t-off] : 0;
    __syncthreads();
    lds[t] += add;
    __syncthreads();
  }
  int base = lds[t] - s3;
  rowptr[t*4+1] = base + v0;
  rowptr[t*4+2] = base + s1;
  rowptr[t*4+3] = base + s2;
  rowptr[t*4+4] = base + s3;
  if (t == 0) rowptr[0] = 0;
}

__global__ void k_scatter(const int* __restrict__ ei, const int* __restrict__ rowptr,
                          int* __restrict__ cursor, int* __restrict__ csr_src) {
  int e = blockIdx.x * 256 + threadIdx.x;
  if (e >= EE) return;
  int src, dst;
  if (e < NE) { src = ei[e]; dst = ei[NE + e]; }
  else { src = e - NE; dst = src; }
  int pos = rowptr[dst] + atomicAdd(&cursor[dst], 1);
  csr_src[pos] = src;
}

// ===================== GAT projection =====================
template<int K, int F, int HEADS, int C>
__global__ __launch_bounds__(256) void k_gat_proj(
    const float* __restrict__ x, const float* __restrict__ W,
    const float* __restrict__ asrc, const float* __restrict__ adst,
    float* __restrict__ feat, float* __restrict__ als, float* __restrict__ ald)
{
  int n = blockIdx.x, t = threadIdx.x;
  __shared__ float xrow[K];
  __shared__ float red[F];
  for (int i = t; i < K; i += F) xrow[i] = x[(size_t)n*K + i];
  __syncthreads();
  const float4* wr = (const float4*)(W + (size_t)t*K);
  const float4* xr = (const float4*)xrow;
  float acc = 0.f;
  #pragma unroll 8
  for (int k4 = 0; k4 < K/4; ++k4) {
    float4 w = wr[k4], xx = xr[k4];
    acc += w.x*xx.x + w.y*xx.y + w.z*xx.z + w.w*xx.w;
  }
  feat[(size_t)n*F + t] = acc;
  int hh = t / C, cc = t % C;
  red[t] = acc * asrc[t];
  __syncthreads();
  for (int off = C/2; off > 0; off >>= 1) {
    float add = (cc < off) ? red[t + off] : 0.f;
    __syncthreads();
    if (cc < off) red[t] += add;
    __syncthreads();
  }
  if (cc == 0) als[(size_t)n*HEADS + hh] = red[t];
  __syncthreads();
  red[t] = acc * adst[t];
  __syncthreads();
  for (int off = C/2; off > 0; off >>= 1) {
    float add = (cc < off) ? red[t + off] : 0.f;
    __syncthreads();
    if (cc < off) red[t] += add;
    __syncthreads();
  }
  if (cc == 0) ald[(size_t)n*HEADS + hh] = red[t];
}

// ===================== GAT aggregation =====================
template<int HEADS, int C, bool DO_ELU, bool WB>
__global__ __launch_bounds__(256) void k_gat_agg(
    const float* __restrict__ feat, const float* __restrict__ als,
    const float* __restrict__ ald, const float* __restrict__ bias,
    const int* __restrict__ rowptr, const int* __restrict__ csr_src,
    float* __restrict__ out, u16* __restrict__ outb)
{
  constexpr int F = HEADS * C;
  int n = blockIdx.x, t = threadIdx.x;
  __shared__ float m_sh[HEADS], s_sh[HEADS];
  int start = rowptr[n];
  int deg = rowptr[n+1] - start;
  int lane = t & 63, wv = t >> 6;
  for (int hh = wv; hh < HEADS; hh += F/64) {
    float adl = ald[(size_t)n*HEADS + hh];
    float mx = -INFINITY;
    for (int i = lane; i < deg; i += 64) {
      int s = csr_src[start + i];
      float lg = als[(size_t)s*HEADS + hh] + adl;
      lg = (lg > 0.f) ? lg : 0.2f * lg;
      mx = fmaxf(mx, lg);
    }
    #pragma unroll
    for (int off = 32; off; off >>= 1) mx = fmaxf(mx, __shfl_xor(mx, off));
    float sm = 0.f;
    for (int i = lane; i < deg; i += 64) {
      int s = csr_src[start + i];
      float lg = als[(size_t)s*HEADS + hh] + adl;
      lg = (lg > 0.f) ? lg : 0.2f * lg;
      sm += expf(lg - mx);
    }
    #pragma unroll
    for (int off = 32; off; off >>= 1) sm += __shfl_xor(sm, off);
    if (lane == 0) { m_sh[hh] = mx; s_sh[hh] = sm; }
  }
  __syncthreads();
  int hh = t / C;
  float adl = ald[(size_t)n*HEADS + hh];
  float mh = m_sh[hh];
  float acc = 0.f;
  for (int i = 0; i < deg; ++i) {
    int s = csr_src[start + i];
    float lg = als[(size_t)s*HEADS + hh] + adl;
    lg = (lg > 0.f) ? lg : 0.2f * lg;
    float p = expf(lg - mh);
    acc += p * feat[(size_t)s*F + t];
  }
  float o = acc / (s_sh[hh] + 1e-16f) + bias[t];
  if (DO_ELU) o = (o > 0.f) ? o : (expf(o) - 1.f);
  out[(size_t)n*F + t] = o;
  if (WB) outb[(size_t)n*F + t] = f2b(o);
}

// ===================== fp32 -> bf16 conversion (weights) =====================
__global__ __launch_bounds__(256) void k_f2b(const float* __restrict__ in,
                                             u16* __restrict__ out, int n4)
{
  int i = blockIdx.x * 256 + threadIdx.x;
  if (i >= n4) return;
  float4 v = ((const float4*)in)[i];
  u16 r[4] = {f2b(v.x), f2b(v.y), f2b(v.z), f2b(v.w)};
  *(uint2*)(out + (size_t)i*4) = *(uint2*)r;
}

// ===================== bf16 MFMA GEMM: C[M,N] = A[M,K] @ B[N,K]^T + bias =====================
// MODE 0: f32 out. MODE 1: relu + bf16 out. MODE 3: qkv scatter (Qb/Kb row-major, Vt transposed+pi-permuted)
template<int MODE>
__global__ __launch_bounds__(256) void k_gemm_mfma(
    const u16* __restrict__ A, const u16* __restrict__ B,
    const float* __restrict__ bias, float* __restrict__ Cf, u16* __restrict__ Cb,
    u16* __restrict__ Qb, u16* __restrict__ Kb, u16* __restrict__ Vt,
    int M, int N, int K)
{
  __shared__ u16 Al[64*64];
  __shared__ u16 Bl[64*64];
  char* Ab = (char*)Al;
  char* Bb = (char*)Bl;
  const int t = threadIdx.x;
  const int lane = t & 63;
  const int lr = lane & 15, lk = lane >> 4;
  const int wid = t >> 6;
  const int wm = wid & 1, wn = wid >> 1;
  const int m0 = blockIdx.y * 64, n0 = blockIdx.x * 64;

  f4v acc[2][2];
  #pragma unroll
  for (int mi = 0; mi < 2; ++mi)
    #pragma unroll
    for (int ni = 0; ni < 2; ++ni)
      acc[mi][ni] = f4v{0.f, 0.f, 0.f, 0.f};

  for (int k0 = 0; k0 < K; k0 += 64) {
    #pragma unroll
    for (int i = 0; i < 2; ++i) {
      int idx = t + i*256;
      int row = idx >> 3, ch = idx & 7;
      s8v av = *(const s8v*)(A + (size_t)(m0 + row)*K + k0 + ch*8);
      *(s8v*)(Ab + row*128 + ((ch*16) ^ ((row & 7) << 4))) = av;
      s8v bv = *(const s8v*)(B + (size_t)(n0 + row)*K + k0 + ch*8);
      *(s8v*)(Bb + row*128 + ((ch*16) ^ ((row & 7) << 4))) = bv;
    }
    __syncthreads();
    #pragma unroll
    for (int ks = 0; ks < 2; ++ks) {
      s8v af[2], bfr[2];
      #pragma unroll
      for (int mi = 0; mi < 2; ++mi) {
        int row = wm*32 + mi*16 + lr;
        int ch = ks*4 + lk;
        af[mi] = *(const s8v*)(Ab + row*128 + ((ch*16) ^ ((row & 7) << 4)));
      }
      #pragma unroll
      for (int ni = 0; ni < 2; ++ni) {
        int row = wn*32 + ni*16 + lr;
        int ch = ks*4 + lk;
        bfr[ni] = *(const s8v*)(Bb + row*128 + ((ch*16) ^ ((row & 7) << 4)));
      }
      #pragma unroll
      for (int mi = 0; mi < 2; ++mi)
        #pragma unroll
        for (int ni = 0; ni < 2; ++ni)
          acc[mi][ni] = __builtin_amdgcn_mfma_f32_16x16x32_bf16(af[mi], bfr[ni], acc[mi][ni], 0, 0, 0);
    }
    __syncthreads();
  }
  #pragma unroll
  for (int ni = 0; ni < 2; ++ni) {
    int col = n0 + wn*32 + ni*16 + lr;
    float bc = bias[col];
    #pragma unroll
    for (int mi = 0; mi < 2; ++mi) {
      int row0 = m0 + wm*32 + mi*16 + lk*4;
      float v[4];
      #pragma unroll
      for (int r = 0; r < 4; ++r) {
        v[r] = acc[mi][ni][r] + bc;
        if (MODE == 1) v[r] = fmaxf(v[r], 0.f);
      }
      if (MODE == 0) {
        #pragma unroll
        for (int r = 0; r < 4; ++r) Cf[(size_t)(row0 + r)*N + col] = v[r];
      } else if (MODE == 1) {
        #pragma unroll
        for (int r = 0; r < 4; ++r) Cb[(size_t)(row0 + r)*N + col] = f2b(v[r]);
      } else { // MODE 3: qkv scatter
        if (col < 512) {
          int head = (col >> 6) & 3;
          int d = col & 63;
          u16* dst = ((col < 256) ? Qb : Kb) + (size_t)head*262144 + d;
          #pragma unroll
          for (int r = 0; r < 4; ++r) dst[(size_t)(row0 + r)*64] = f2b(v[r]);
        } else {
          int cc = col - 512;
          int head = cc >> 6;
          int d = cc & 63;
          int quad = row0 & 12;
          int qs = (quad == 4) ? 8 : ((quad == 8) ? 4 : quad);
          size_t nphys = (size_t)((row0 & ~15) | qs);
          u16 o4[4];
          #pragma unroll
          for (int r = 0; r < 4; ++r) o4[r] = f2b(v[r]);
          *(uint2*)(Vt + (size_t)head*262144 + (size_t)d*4096 + nphys) = *(uint2*)o4;
        }
      }
    }
  }
}

// ===================== LayerNorm(a + res) =====================
template<bool WB>
__global__ __launch_bounds__(256) void k_ln(
    const float* __restrict__ a, const float* __restrict__ res,
    const float* __restrict__ g, const float* __restrict__ bb,
    float* __restrict__ out, u16* __restrict__ outb)
{
  int n = blockIdx.x, t = threadIdx.x;
  __shared__ float part[4];
  float v = a[(size_t)n*256 + t] + res[(size_t)n*256 + t];
  float s = v;
  #pragma unroll
  for (int off = 32; off; off >>= 1) s += __shfl_xor(s, off);
  if ((t & 63) == 0) part[t >> 6] = s;
  __syncthreads();
  float mean = (part[0] + part[1] + part[2] + part[3]) * (1.f/256.f);
  __syncthreads();
  float d = v - mean;
  float s2 = d * d;
  #pragma unroll
  for (int off = 32; off; off >>= 1) s2 += __shfl_xor(s2, off);
  if ((t & 63) == 0) part[t >> 6] = s2;
  __syncthreads();
  float var = (part[0] + part[1] + part[2] + part[3]) * (1.f/256.f);
  float rstd = rsqrtf(var + 1e-5f);
  float o = d * rstd * g[t] + bb[t];
  out[(size_t)n*256 + t] = o;
  if (WB) outb[(size_t)n*256 + t] = f2b(o);
}

// ===================== bf16 MFMA flash attention v2 =====================
// 8-wave blocks; wave s covers keys [s*512, s*512+512) for a 32-query strip.
// Swapped QK^T (mfma(K,Q)) -> per-lane row softmax (2 shfl_xor(32) per tile).
// P stays in registers; V is pre-permuted (bits 2<->3 of n&15) so PV needs no exchange.
// In-LDS tree merge across the 8 splits.
__global__ __launch_bounds__(512) void k_attn2(
    const u16* __restrict__ Qb, const u16* __restrict__ Kb,
    const u16* __restrict__ Vt, u16* __restrict__ attno_b)
{
  const int strip = blockIdx.x;
  const int head  = blockIdx.y;
  const int q0 = strip * 32;
  const int t = threadIdx.x;
  const int s = t >> 6;
  const int l = t & 63;
  const int lq = l & 31;
  const int lh = l >> 5;

  __shared__ float lds_O[4][32][68];
  __shared__ float lds_m[4][32];
  __shared__ float lds_l[4][32];

  const u16* Qh = Qb + (size_t)head * (4096*64);
  const u16* Kh = Kb + (size_t)head * (4096*64);
  const u16* Vh = Vt + (size_t)head * (64*4096);

  s8v qf[4];
#pragma unroll
  for (int dc = 0; dc < 4; ++dc)
    qf[dc] = *(const s8v*)(Qh + (size_t)(q0 + lq)*64 + dc*16 + lh*8);

  f16v accO[2];
#pragma unroll
  for (int dm = 0; dm < 2; ++dm)
#pragma unroll
    for (int i = 0; i < 16; ++i) accO[dm][i] = 0.f;

  float mrow = -INFINITY, lrow = 0.f;
  const float CE = 0.18033688011112042f;  // log2(e)/8

  const int kt0 = s * 512;
  for (int kt = kt0; kt < kt0 + 512; kt += 64) {
    f16v st[2];
#pragma unroll
    for (int c = 0; c < 2; ++c)
#pragma unroll
      for (int i = 0; i < 16; ++i) st[c][i] = 0.f;
#pragma unroll
    for (int dc = 0; dc < 4; ++dc) {
      s8v kf0 = *(const s8v*)(Kh + (size_t)(kt + lq)*64 + dc*16 + lh*8);
      s8v kf1 = *(const s8v*)(Kh + (size_t)(kt + 32 + lq)*64 + dc*16 + lh*8);
      st[0] = __builtin_amdgcn_mfma_f32_32x32x16_bf16(kf0, qf[dc], st[0], 0, 0, 0);
      st[1] = __builtin_amdgcn_mfma_f32_32x32x16_bf16(kf1, qf[dc], st[1], 0, 0, 0);
    }
    // row softmax: lane holds 32 scores for query q=lq (dup across lane halves)
    float mx = st[0][0];
#pragma unroll
    for (int i = 1; i < 16; ++i) mx = fmaxf(mx, st[0][i]);
#pragma unroll
    for (int i = 0; i < 16; ++i) mx = fmaxf(mx, st[1][i]);
    mx = fmaxf(mx, __shfl_xor(mx, 32));
    float mn = fmaxf(mrow, mx);
    float sc = exp2f((mrow - mn) * CE);
    mrow = mn;
    float ps = 0.f;
#pragma unroll
    for (int c = 0; c < 2; ++c)
#pragma unroll
      for (int i = 0; i < 16; ++i) {
        float p = exp2f((st[c][i] - mn) * CE);
        st[c][i] = p;
        ps += p;
      }
    ps += __shfl_xor(ps, 32);
    lrow = lrow * sc + ps;
#pragma unroll
    for (int dm = 0; dm < 2; ++dm)
#pragma unroll
      for (int i = 0; i < 16; ++i) accO[dm][i] *= sc;

    // PV: P packed from registers in natural order; V layout pre-permuted to match
#pragma unroll
    for (int c = 0; c < 2; ++c) {
#pragma unroll
      for (int kc = 0; kc < 2; ++kc) {
        union { s8v v; unsigned int w[4]; } pb;
#pragma unroll
        for (int wd = 0; wd < 4; ++wd) {
          u16 lo16 = f2b(st[c][kc*8 + wd*2]);
          u16 hi16 = f2b(st[c][kc*8 + wd*2 + 1]);
          pb.w[wd] = (unsigned int)lo16 | ((unsigned int)hi16 << 16);
        }
#pragma unroll
        for (int dm = 0; dm < 2; ++dm) {
          s8v vf = *(const s8v*)(Vh + (size_t)(dm*32 + lq)*4096 + kt + c*32 + kc*16 + lh*8);
          accO[dm] = __builtin_amdgcn_mfma_f32_32x32x16_bf16(vf, pb.v, accO[dm], 0, 0, 0);
        }
      }
    }
  }

  // tree merge across the 8 split-waves
#pragma unroll
  for (int lev = 0; lev < 3; ++lev) {
    const int step = 1 << lev;
    __syncthreads();
    if ((s & (2*step - 1)) == step) {
      int slot = (s - step) >> (lev + 1);
      if (l < 32) { lds_m[slot][lq] = mrow; lds_l[slot][lq] = lrow; }
#pragma unroll
      for (int dm = 0; dm < 2; ++dm)
#pragma unroll
        for (int g = 0; g < 4; ++g) {
          f4v v;
#pragma unroll
          for (int rr = 0; rr < 4; ++rr) v[rr] = accO[dm][g*4 + rr];
          *(f4v*)&lds_O[slot][lq][dm*32 + lh*4 + g*8] = v;
        }
    }
    __syncthreads();
    if ((s & (2*step - 1)) == 0) {
      int slot = s >> (lev + 1);
      float mp = lds_m[slot][lq], lp = lds_l[slot][lq];
      float M = fmaxf(mrow, mp);
      float w0 = exp2f((mrow - M) * CE);
      float w1 = exp2f((mp - M) * CE);
      lrow = lrow * w0 + lp * w1;
      mrow = M;
#pragma unroll
      for (int dm = 0; dm < 2; ++dm)
#pragma unroll
        for (int g = 0; g < 4; ++g) {
          f4v vp = *(const f4v*)&lds_O[slot][lq][dm*32 + lh*4 + g*8];
#pragma unroll
          for (int rr = 0; rr < 4; ++rr)
            accO[dm][g*4 + rr] = accO[dm][g*4 + rr] * w0 + vp[rr] * w1;
        }
    }
  }

  if (s == 0) {
    float inv = 1.f / lrow;
#pragma unroll
    for (int dm = 0; dm < 2; ++dm)
#pragma unroll
      for (int g = 0; g < 4; ++g) {
        u16 o4[4];
#pragma unroll
        for (int rr = 0; rr < 4; ++rr) o4[rr] = f2b(accO[dm][g*4 + rr] * inv);
        *(uint2*)(attno_b + (size_t)(q0 + lq)*256 + head*64 + dm*32 + lh*4 + g*8) = *(uint2*)o4;
      }
  }
}

// ===================== host launcher =====================
extern "C" void kernel_launch(void* const* d_in, const int* in_sizes, int n_in,
                              void* d_out, int out_size, void* d_ws, size_t ws_size,
                              hipStream_t stream)
{
  const float* x       = (const float*)d_in[0];
  const int*   ei      = (const int*)d_in[1];
  const float* gat1_w  = (const float*)d_in[2];
  const float* gat1_as = (const float*)d_in[3];
  const float* gat1_ad = (const float*)d_in[4];
  const float* gat1_b  = (const float*)d_in[5];
  const float* inp_w   = (const float*)d_in[6];
  const float* inp_b   = (const float*)d_in[7];
  const float* outp_w  = (const float*)d_in[8];
  const float* outp_b  = (const float*)d_in[9];
  const float* lin1_w  = (const float*)d_in[10];
  const float* lin1_b  = (const float*)d_in[11];
  const float* lin2_w  = (const float*)d_in[12];
  const float* lin2_b  = (const float*)d_in[13];
  const float* ln1_g   = (const float*)d_in[14];
  const float* ln1_bb  = (const float*)d_in[15];
  const float* ln2_g   = (const float*)d_in[16];
  const float* ln2_bb  = (const float*)d_in[17];
  const float* gat2_w  = (const float*)d_in[18];
  const float* gat2_as = (const float*)d_in[19];
  const float* gat2_ad = (const float*)d_in[20];
  const float* gat2_b  = (const float*)d_in[21];
  float* out = (float*)d_out;
  (void)in_sizes; (void)n_in; (void)out_size; (void)ws_size;

  char* ws = (char*)d_ws;
  size_t off = 0;
  auto nxt = [&](size_t bytes) { size_t r = off; off += (bytes + 255) & ~(size_t)255; return r; };
  int* deg      = (int*)(ws + nxt((size_t)NN*4));
  int* cursor   = (int*)(ws + nxt((size_t)NN*4));
  int* rowptr   = (int*)(ws + nxt((size_t)(NN+1)*4));
  int* csr_src  = (int*)(ws + nxt((size_t)EE*4));
  float* feat1  = (float*)(ws + nxt((size_t)NN*256*4));
  float* al1s   = (float*)(ws + nxt((size_t)NN*4*4));
  float* al1d   = (float*)(ws + nxt((size_t)NN*4*4));
  float* hgat1  = (float*)(ws + nxt((size_t)NN*256*4));
  float* tmp256 = (float*)(ws + nxt((size_t)NN*256*4));
  float* hln1   = (float*)(ws + nxt((size_t)NN*256*4));
  float* hln2   = (float*)(ws + nxt((size_t)NN*256*4));
  float* feat2  = (float*)(ws + nxt((size_t)NN*128*4));
  float* al2s   = (float*)(ws + nxt((size_t)NN*4));
  float* al2d   = (float*)(ws + nxt((size_t)NN*4));
  u16* hgat1_b  = (u16*)(ws + nxt((size_t)NN*256*2));
  u16* attno_b  = (u16*)(ws + nxt((size_t)NN*256*2));
  u16* hln1_b   = (u16*)(ws + nxt((size_t)NN*256*2));
  u16* ff1_b    = (u16*)(ws + nxt((size_t)NN*2048*2));
  u16* Qb       = (u16*)(ws + nxt((size_t)4*4096*64*2));
  u16* Kb       = (u16*)(ws + nxt((size_t)4*4096*64*2));
  u16* Vt       = (u16*)(ws + nxt((size_t)4*4096*64*2));
  u16* inp_w_b  = (u16*)(ws + nxt((size_t)768*256*2));
  u16* outp_w_b = (u16*)(ws + nxt((size_t)256*256*2));
  u16* lin1_w_b = (u16*)(ws + nxt((size_t)2048*256*2));
  u16* lin2_w_b = (u16*)(ws + nxt((size_t)256*2048*2));

  hipMemsetAsync(deg, 0, (size_t)NN*4, stream);
  hipMemsetAsync(cursor, 0, (size_t)NN*4, stream);
  k_count<<<(EE+255)/256, 256, 0, stream>>>(ei, deg);
  k_scan<<<1, 1024, 0, stream>>>(deg, rowptr);
  k_scatter<<<(EE+255)/256, 256, 0, stream>>>(ei, rowptr, cursor, csr_src);

  // weights -> bf16 (one-time per launch)
  k_f2b<<<192, 256, 0, stream>>>(inp_w, inp_w_b, 768*256/4);
  k_f2b<<<64, 256, 0, stream>>>(outp_w, outp_w_b, 256*256/4);
  k_f2b<<<512, 256, 0, stream>>>(lin1_w, lin1_w_b, 2048*256/4);
  k_f2b<<<512, 256, 0, stream>>>(lin2_w, lin2_w_b, 256*2048/4);

  // GAT layer 1 + ELU (writes f32 + bf16)
  k_gat_proj<128,256,4,64><<<NN, 256, 0, stream>>>(x, gat1_w, gat1_as, gat1_ad, feat1, al1s, al1d);
  k_gat_agg<4,64,true,true><<<NN, 256, 0, stream>>>(feat1, al1s, al1d, gat1_b, rowptr, csr_src, hgat1, hgat1_b);

  // Transformer encoder layer
  k_gemm_mfma<3><<<dim3(768/64, NN/64), 256, 0, stream>>>(hgat1_b, inp_w_b, inp_b, nullptr, nullptr, Qb, Kb, Vt, NN, 768, 256);
  k_attn2<<<dim3(128, 4), 512, 0, stream>>>(Qb, Kb, Vt, attno_b);
  k_gemm_mfma<0><<<dim3(256/64, NN/64), 256, 0, stream>>>(attno_b, outp_w_b, outp_b, tmp256, nullptr, nullptr, nullptr, nullptr, NN, 256, 256);
  k_ln<true><<<NN, 256, 0, stream>>>(tmp256, hgat1, ln1_g, ln1_bb, hln1, hln1_b);
  k_gemm_mfma<1><<<dim3(2048/64, NN/64), 256, 0, stream>>>(hln1_b, lin1_w_b, lin1_b, nullptr, ff1_b, nullptr, nullptr, nullptr, NN, 2048, 256);
  k_gemm_mfma<0><<<dim3(256/64, NN/64), 256, 0, stream>>>(ff1_b, lin2_w_b, lin2_b, tmp256, nullptr, nullptr, nullptr, nullptr, NN, 256, 2048);
  k_ln<false><<<NN, 256, 0, stream>>>(tmp256, hln1, ln2_g, ln2_bb, hln2, nullptr);

  // GAT layer 2 -> final output
  k_gat_proj<256,128,1,128><<<NN, 128, 0, stream>>>(hln2, gat2_w, gat2_as, gat2_ad, feat2, al2s, al2d);
  k_gat_agg<1,128,false,false><<<NN, 128, 0, stream>>>(feat2, al2s, al2d, gat2_b, rowptr, csr_src, out, nullptr);
}

// Round 6
// 307.576 us; speedup vs baseline: 3.1662x; 1.3930x over previous
//
#include <hip/hip_runtime.h>
#include <hip/hip_bf16.h>
#include <math.h>

#define NN 4096
#define NE 131072
#define EE (NE + NN)

typedef unsigned short u16;
typedef short s8v __attribute__((ext_vector_type(8)));
typedef float f4v __attribute__((ext_vector_type(4)));
typedef float f16v __attribute__((ext_vector_type(16)));

__device__ inline u16 f2b(float f) {
  __hip_bfloat16 h = __float2bfloat16(f);
  return __builtin_bit_cast(u16, h);
}
__device__ inline float b2f(u16 v) {
  unsigned int u = ((unsigned int)v) << 16;
  return __builtin_bit_cast(float, u);
}

// ===================== CSR build =====================
__global__ void k_count(const int* __restrict__ ei, int* __restrict__ deg) {
  int e = blockIdx.x * 256 + threadIdx.x;
  if (e >= EE) return;
  int dst = (e < NE) ? ei[NE + e] : (e - NE);
  atomicAdd(&deg[dst], 1);
}

__global__ __launch_bounds__(1024) void k_scan(const int* __restrict__ deg, int* __restrict__ rowptr) {
  __shared__ int lds[1024];
  int t = threadIdx.x;
  int v0 = deg[t*4+0], v1 = deg[t*4+1], v2 = deg[t*4+2], v3 = deg[t*4+3];
  int s1 = v0+v1, s2 = s1+v2, s3 = s2+v3;
  lds[t] = s3;
  __syncthreads();
  for (int off = 1; off < 1024; off <<= 1) {
    int add = (t >= off) ? lds[t-off] : 0;
    __syncthreads();
    lds[t] += add;
    __syncthreads();
  }
  int base = lds[t] - s3;
  rowptr[t*4+1] = base + v0;
  rowptr[t*4+2] = base + s1;
  rowptr[t*4+3] = base + s2;
  rowptr[t*4+4] = base + s3;
  if (t == 0) rowptr[0] = 0;
}

__global__ void k_scatter(const int* __restrict__ ei, const int* __restrict__ rowptr,
                          int* __restrict__ cursor, int* __restrict__ csr_src) {
  int e = blockIdx.x * 256 + threadIdx.x;
  if (e >= EE) return;
  int src, dst;
  if (e < NE) { src = ei[e]; dst = ei[NE + e]; }
  else { src = e - NE; dst = src; }
  int pos = rowptr[dst] + atomicAdd(&cursor[dst], 1);
  csr_src[pos] = src;
}

// ===================== batched fp32 -> bf16 conversion =====================
__global__ __launch_bounds__(256) void k_f2b_all(
    const float* a0, u16* b0, int e0, const float* a1, u16* b1, int e1,
    const float* a2, u16* b2, int e2, const float* a3, u16* b3, int e3,
    const float* a4, u16* b4, int e4, const float* a5, u16* b5, int e5,
    const float* a6, u16* b6, int e6)
{
  int i = blockIdx.x * 256 + threadIdx.x;
  const float* s; u16* d; int base;
  if      (i < e0) { s=a0; d=b0; base=0;  }
  else if (i < e1) { s=a1; d=b1; base=e0; }
  else if (i < e2) { s=a2; d=b2; base=e1; }
  else if (i < e3) { s=a3; d=b3; base=e2; }
  else if (i < e4) { s=a4; d=b4; base=e3; }
  else if (i < e5) { s=a5; d=b5; base=e4; }
  else if (i < e6) { s=a6; d=b6; base=e5; }
  else return;
  int j = i - base;
  float4 v = ((const float4*)s)[j];
  u16 r[4] = {f2b(v.x), f2b(v.y), f2b(v.z), f2b(v.w)};
  *(uint2*)(d + (size_t)j*4) = *(uint2*)r;
}

// ===================== a-logits: als/ald[n,h] = sum_c feat[n,h,c]*a[h,c] =====================
template<int HEADS, int C>
__global__ __launch_bounds__(256) void k_alogits(
    const u16* __restrict__ featb, const float* __restrict__ asrc,
    const float* __restrict__ adst, float* __restrict__ als, float* __restrict__ ald)
{
  constexpr int F = HEADS * C;
  int n = blockIdx.x, t = threadIdx.x;
  __shared__ float red[F];
  float f = b2f(featb[(size_t)n*F + t]);
  int hh = t / C, cc = t % C;
  red[t] = f * asrc[t];
  __syncthreads();
  for (int off = C/2; off > 0; off >>= 1) {
    float add = (cc < off) ? red[t + off] : 0.f;
    __syncthreads();
    if (cc < off) red[t] += add;
    __syncthreads();
  }
  if (cc == 0) als[(size_t)n*HEADS + hh] = red[t];
  __syncthreads();
  red[t] = f * adst[t];
  __syncthreads();
  for (int off = C/2; off > 0; off >>= 1) {
    float add = (cc < off) ? red[t + off] : 0.f;
    __syncthreads();
    if (cc < off) red[t] += add;
    __syncthreads();
  }
  if (cc == 0) ald[(size_t)n*HEADS + hh] = red[t];
}

// ===================== GAT aggregation (bf16 feat gather) =====================
template<int HEADS, int C, bool DO_ELU, bool WB>
__global__ __launch_bounds__(256) void k_gat_agg(
    const u16* __restrict__ featb, const float* __restrict__ als,
    const float* __restrict__ ald, const float* __restrict__ bias,
    const int* __restrict__ rowptr, const int* __restrict__ csr_src,
    float* __restrict__ out, u16* __restrict__ outb)
{
  constexpr int F = HEADS * C;
  int n = blockIdx.x, t = threadIdx.x;
  __shared__ float m_sh[HEADS], s_sh[HEADS];
  int start = rowptr[n];
  int deg = rowptr[n+1] - start;
  int lane = t & 63, wv = t >> 6;
  for (int hh = wv; hh < HEADS; hh += F/64) {
    float adl = ald[(size_t)n*HEADS + hh];
    float mx = -INFINITY;
    for (int i = lane; i < deg; i += 64) {
      int s = csr_src[start + i];
      float lg = als[(size_t)s*HEADS + hh] + adl;
      lg = (lg > 0.f) ? lg : 0.2f * lg;
      mx = fmaxf(mx, lg);
    }
    #pragma unroll
    for (int off = 32; off; off >>= 1) mx = fmaxf(mx, __shfl_xor(mx, off));
    float sm = 0.f;
    for (int i = lane; i < deg; i += 64) {
      int s = csr_src[start + i];
      float lg = als[(size_t)s*HEADS + hh] + adl;
      lg = (lg > 0.f) ? lg : 0.2f * lg;
      sm += expf(lg - mx);
    }
    #pragma unroll
    for (int off = 32; off; off >>= 1) sm += __shfl_xor(sm, off);
    if (lane == 0) { m_sh[hh] = mx; s_sh[hh] = sm; }
  }
  __syncthreads();
  int hh = t / C;
  float adl = ald[(size_t)n*HEADS + hh];
  float mh = m_sh[hh];
  float acc0 = 0.f, acc1 = 0.f;
  int i = 0;
  for (; i + 1 < deg; i += 2) {
    int s0 = csr_src[start + i];
    int s1 = csr_src[start + i + 1];
    float lg0 = als[(size_t)s0*HEADS + hh] + adl;
    float lg1 = als[(size_t)s1*HEADS + hh] + adl;
    lg0 = (lg0 > 0.f) ? lg0 : 0.2f * lg0;
    lg1 = (lg1 > 0.f) ? lg1 : 0.2f * lg1;
    float p0 = expf(lg0 - mh);
    float p1 = expf(lg1 - mh);
    acc0 += p0 * b2f(featb[(size_t)s0*F + t]);
    acc1 += p1 * b2f(featb[(size_t)s1*F + t]);
  }
  if (i < deg) {
    int s0 = csr_src[start + i];
    float lg0 = als[(size_t)s0*HEADS + hh] + adl;
    lg0 = (lg0 > 0.f) ? lg0 : 0.2f * lg0;
    acc0 += expf(lg0 - mh) * b2f(featb[(size_t)s0*F + t]);
  }
  float o = (acc0 + acc1) / (s_sh[hh] + 1e-16f) + bias[t];
  if (DO_ELU) o = (o > 0.f) ? o : (expf(o) - 1.f);
  out[(size_t)n*F + t] = o;
  if (WB) outb[(size_t)n*F + t] = f2b(o);
}

// ===================== bf16 MFMA GEMM: C[M,N] = A[M,K] @ B[N,K]^T + bias =====================
// MODE 0: f32 out. MODE 1: relu+bf16 out. MODE 2: bf16 out. MODE 3: qkv scatter.
template<int MODE>
__global__ __launch_bounds__(256) void k_gemm_mfma(
    const u16* __restrict__ A, const u16* __restrict__ B,
    const float* __restrict__ bias, float* __restrict__ Cf, u16* __restrict__ Cb,
    u16* __restrict__ Qb, u16* __restrict__ Kb, u16* __restrict__ Vt,
    int M, int N, int K)
{
  __shared__ u16 Al[64*64];
  __shared__ u16 Bl[64*64];
  char* Ab = (char*)Al;
  char* Bb = (char*)Bl;
  const int t = threadIdx.x;
  const int lane = t & 63;
  const int lr = lane & 15, lk = lane >> 4;
  const int wid = t >> 6;
  const int wm = wid & 1, wn = wid >> 1;
  const int m0 = blockIdx.y * 64, n0 = blockIdx.x * 64;

  f4v acc[2][2];
  #pragma unroll
  for (int mi = 0; mi < 2; ++mi)
    #pragma unroll
    for (int ni = 0; ni < 2; ++ni)
      acc[mi][ni] = f4v{0.f, 0.f, 0.f, 0.f};

  for (int k0 = 0; k0 < K; k0 += 64) {
    #pragma unroll
    for (int i = 0; i < 2; ++i) {
      int idx = t + i*256;
      int row = idx >> 3, ch = idx & 7;
      s8v av = *(const s8v*)(A + (size_t)(m0 + row)*K + k0 + ch*8);
      *(s8v*)(Ab + row*128 + ((ch*16) ^ ((row & 7) << 4))) = av;
      s8v bv = *(const s8v*)(B + (size_t)(n0 + row)*K + k0 + ch*8);
      *(s8v*)(Bb + row*128 + ((ch*16) ^ ((row & 7) << 4))) = bv;
    }
    __syncthreads();
    #pragma unroll
    for (int ks = 0; ks < 2; ++ks) {
      s8v af[2], bfr[2];
      #pragma unroll
      for (int mi = 0; mi < 2; ++mi) {
        int row = wm*32 + mi*16 + lr;
        int ch = ks*4 + lk;
        af[mi] = *(const s8v*)(Ab + row*128 + ((ch*16) ^ ((row & 7) << 4)));
      }
      #pragma unroll
      for (int ni = 0; ni < 2; ++ni) {
        int row = wn*32 + ni*16 + lr;
        int ch = ks*4 + lk;
        bfr[ni] = *(const s8v*)(Bb + row*128 + ((ch*16) ^ ((row & 7) << 4)));
      }
      #pragma unroll
      for (int mi = 0; mi < 2; ++mi)
        #pragma unroll
        for (int ni = 0; ni < 2; ++ni)
          acc[mi][ni] = __builtin_amdgcn_mfma_f32_16x16x32_bf16(af[mi], bfr[ni], acc[mi][ni], 0, 0, 0);
    }
    __syncthreads();
  }
  #pragma unroll
  for (int ni = 0; ni < 2; ++ni) {
    int col = n0 + wn*32 + ni*16 + lr;
    float bc = bias ? bias[col] : 0.f;
    #pragma unroll
    for (int mi = 0; mi < 2; ++mi) {
      int row0 = m0 + wm*32 + mi*16 + lk*4;
      float v[4];
      #pragma unroll
      for (int r = 0; r < 4; ++r) {
        v[r] = acc[mi][ni][r] + bc;
        if (MODE == 1) v[r] = fmaxf(v[r], 0.f);
      }
      if (MODE == 0) {
        #pragma unroll
        for (int r = 0; r < 4; ++r) Cf[(size_t)(row0 + r)*N + col] = v[r];
      } else if (MODE == 1 || MODE == 2) {
        #pragma unroll
        for (int r = 0; r < 4; ++r) Cb[(size_t)(row0 + r)*N + col] = f2b(v[r]);
      } else { // MODE 3: qkv scatter
        if (col < 512) {
          int head = (col >> 6) & 3;
          int d = col & 63;
          u16* dst = ((col < 256) ? Qb : Kb) + (size_t)head*262144 + d;
          #pragma unroll
          for (int r = 0; r < 4; ++r) dst[(size_t)(row0 + r)*64] = f2b(v[r]);
        } else {
          int cc = col - 512;
          int head = cc >> 6;
          int d = cc & 63;
          int quad = row0 & 12;
          int qs = (quad == 4) ? 8 : ((quad == 8) ? 4 : quad);
          size_t nphys = (size_t)((row0 & ~15) | qs);
          u16 o4[4];
          #pragma unroll
          for (int r = 0; r < 4; ++r) o4[r] = f2b(v[r]);
          *(uint2*)(Vt + (size_t)head*262144 + (size_t)d*4096 + nphys) = *(uint2*)o4;
        }
      }
    }
  }
}

// ===================== split-K bf16 MFMA GEMM partials (f32, no bias) =====================
__global__ __launch_bounds__(256) void k_gemm_sk(
    const u16* __restrict__ A, const u16* __restrict__ B,
    float* __restrict__ Po, int M, int N, int K)
{
  __shared__ u16 Al[64*64];
  __shared__ u16 Bl[64*64];
  char* Ab = (char*)Al;
  char* Bb = (char*)Bl;
  const int t = threadIdx.x;
  const int lane = t & 63;
  const int lr = lane & 15, lk = lane >> 4;
  const int wid = t >> 6;
  const int wm = wid & 1, wn = wid >> 1;
  const int m0 = blockIdx.y * 64, n0 = blockIdx.x * 64;
  const int z = blockIdx.z;
  const int ksl = K >> 2;

  f4v acc[2][2];
  #pragma unroll
  for (int mi = 0; mi < 2; ++mi)
    #pragma unroll
    for (int ni = 0; ni < 2; ++ni)
      acc[mi][ni] = f4v{0.f, 0.f, 0.f, 0.f};

  for (int k0 = z*ksl; k0 < (z+1)*ksl; k0 += 64) {
    #pragma unroll
    for (int i = 0; i < 2; ++i) {
      int idx = t + i*256;
      int row = idx >> 3, ch = idx & 7;
      s8v av = *(const s8v*)(A + (size_t)(m0 + row)*K + k0 + ch*8);
      *(s8v*)(Ab + row*128 + ((ch*16) ^ ((row & 7) << 4))) = av;
      s8v bv = *(const s8v*)(B + (size_t)(n0 + row)*K + k0 + ch*8);
      *(s8v*)(Bb + row*128 + ((ch*16) ^ ((row & 7) << 4))) = bv;
    }
    __syncthreads();
    #pragma unroll
    for (int ks = 0; ks < 2; ++ks) {
      s8v af[2], bfr[2];
      #pragma unroll
      for (int mi = 0; mi < 2; ++mi) {
        int row = wm*32 + mi*16 + lr;
        int ch = ks*4 + lk;
        af[mi] = *(const s8v*)(Ab + row*128 + ((ch*16) ^ ((row & 7) << 4)));
      }
      #pragma unroll
      for (int ni = 0; ni < 2; ++ni) {
        int row = wn*32 + ni*16 + lr;
        int ch = ks*4 + lk;
        bfr[ni] = *(const s8v*)(Bb + row*128 + ((ch*16) ^ ((row & 7) << 4)));
      }
      #pragma unroll
      for (int mi = 0; mi < 2; ++mi)
        #pragma unroll
        for (int ni = 0; ni < 2; ++ni)
          acc[mi][ni] = __builtin_amdgcn_mfma_f32_16x16x32_bf16(af[mi], bfr[ni], acc[mi][ni], 0, 0, 0);
    }
    __syncthreads();
  }
  float* Pz = Po + (size_t)z * M * N;
  #pragma unroll
  for (int ni = 0; ni < 2; ++ni) {
    int col = n0 + wn*32 + ni*16 + lr;
    #pragma unroll
    for (int mi = 0; mi < 2; ++mi) {
      int row0 = m0 + wm*32 + mi*16 + lk*4;
      #pragma unroll
      for (int r = 0; r < 4; ++r)
        Pz[(size_t)(row0 + r)*N + col] = acc[mi][ni][r];
    }
  }
}

// ===================== LayerNorm(a + res) =====================
template<bool WB>
__global__ __launch_bounds__(256) void k_ln(
    const float* __restrict__ a, const float* __restrict__ res,
    const float* __restrict__ g, const float* __restrict__ bb,
    float* __restrict__ out, u16* __restrict__ outb)
{
  int n = blockIdx.x, t = threadIdx.x;
  __shared__ float part[4];
  float v = a[(size_t)n*256 + t] + res[(size_t)n*256 + t];
  float s = v;
  #pragma unroll
  for (int off = 32; off; off >>= 1) s += __shfl_xor(s, off);
  if ((t & 63) == 0) part[t >> 6] = s;
  __syncthreads();
  float mean = (part[0] + part[1] + part[2] + part[3]) * (1.f/256.f);
  __syncthreads();
  float d = v - mean;
  float s2 = d * d;
  #pragma unroll
  for (int off = 32; off; off >>= 1) s2 += __shfl_xor(s2, off);
  if ((t & 63) == 0) part[t >> 6] = s2;
  __syncthreads();
  float var = (part[0] + part[1] + part[2] + part[3]) * (1.f/256.f);
  float rstd = rsqrtf(var + 1e-5f);
  float o = d * rstd * g[t] + bb[t];
  out[(size_t)n*256 + t] = o;
  if (WB) outb[(size_t)n*256 + t] = f2b(o);
}

// ===================== LayerNorm over 4 split-K partials + bias + res =====================
template<bool WB>
__global__ __launch_bounds__(256) void k_ln_sk(
    const float* __restrict__ Po, const float* __restrict__ bias,
    const float* __restrict__ res, const float* __restrict__ g,
    const float* __restrict__ bb, float* __restrict__ out, u16* __restrict__ outb)
{
  int n = blockIdx.x, t = threadIdx.x;
  __shared__ float part[4];
  const size_t MN = (size_t)NN * 256;
  size_t idx = (size_t)n*256 + t;
  float v = Po[idx] + Po[MN + idx] + Po[2*MN + idx] + Po[3*MN + idx]
          + bias[t] + res[idx];
  float s = v;
  #pragma unroll
  for (int off = 32; off; off >>= 1) s += __shfl_xor(s, off);
  if ((t & 63) == 0) part[t >> 6] = s;
  __syncthreads();
  float mean = (part[0] + part[1] + part[2] + part[3]) * (1.f/256.f);
  __syncthreads();
  float d = v - mean;
  float s2 = d * d;
  #pragma unroll
  for (int off = 32; off; off >>= 1) s2 += __shfl_xor(s2, off);
  if ((t & 63) == 0) part[t >> 6] = s2;
  __syncthreads();
  float var = (part[0] + part[1] + part[2] + part[3]) * (1.f/256.f);
  float rstd = rsqrtf(var + 1e-5f);
  float o = d * rstd * g[t] + bb[t];
  out[idx] = o;
  if (WB) outb[idx] = f2b(o);
}

// ===================== bf16 MFMA flash attention v2.1 =====================
// 8-wave blocks; wave s covers keys [s*512, s*512+512) for a 32-query strip.
// Swapped QK^T; tree max/sum; defer-max rescale (T13); setprio (T5).
__global__ __launch_bounds__(512) void k_attn2(
    const u16* __restrict__ Qb, const u16* __restrict__ Kb,
    const u16* __restrict__ Vt, u16* __restrict__ attno_b)
{
  const int strip = blockIdx.x;
  const int head  = blockIdx.y;
  const int q0 = strip * 32;
  const int t = threadIdx.x;
  const int s = t >> 6;
  const int l = t & 63;
  const int lq = l & 31;
  const int lh = l >> 5;

  __shared__ float lds_O[4][32][68];
  __shared__ float lds_m[4][32];
  __shared__ float lds_l[4][32];

  const u16* Qh = Qb + (size_t)head * (4096*64);
  const u16* Kh = Kb + (size_t)head * (4096*64);
  const u16* Vh = Vt + (size_t)head * (64*4096);

  s8v qf[4];
#pragma unroll
  for (int dc = 0; dc < 4; ++dc)
    qf[dc] = *(const s8v*)(Qh + (size_t)(q0 + lq)*64 + dc*16 + lh*8);

  f16v accO[2];
#pragma unroll
  for (int dm = 0; dm < 2; ++dm)
#pragma unroll
    for (int i = 0; i < 16; ++i) accO[dm][i] = 0.f;

  float mrow = -INFINITY, lrow = 0.f;
  const float CE = 0.18033688011112042f;  // log2(e)/8

  const int kt0 = s * 512;
  for (int kt = kt0; kt < kt0 + 512; kt += 64) {
    f16v st[2];
#pragma unroll
    for (int c = 0; c < 2; ++c)
#pragma unroll
      for (int i = 0; i < 16; ++i) st[c][i] = 0.f;
    __builtin_amdgcn_s_setprio(1);
#pragma unroll
    for (int dc = 0; dc < 4; ++dc) {
      s8v kf0 = *(const s8v*)(Kh + (size_t)(kt + lq)*64 + dc*16 + lh*8);
      s8v kf1 = *(const s8v*)(Kh + (size_t)(kt + 32 + lq)*64 + dc*16 + lh*8);
      st[0] = __builtin_amdgcn_mfma_f32_32x32x16_bf16(kf0, qf[dc], st[0], 0, 0, 0);
      st[1] = __builtin_amdgcn_mfma_f32_32x32x16_bf16(kf1, qf[dc], st[1], 0, 0, 0);
    }
    __builtin_amdgcn_s_setprio(0);
    // tree max over the lane's 32 scores (depth 5), then fold lane halves
    float tm[16];
#pragma unroll
    for (int i = 0; i < 8; ++i) tm[i]   = fmaxf(st[0][2*i], st[0][2*i+1]);
#pragma unroll
    for (int i = 0; i < 8; ++i) tm[8+i] = fmaxf(st[1][2*i], st[1][2*i+1]);
#pragma unroll
    for (int w = 8; w >= 1; w >>= 1)
#pragma unroll
      for (int i = 0; i < 8; ++i) if (i < w) tm[i] = fmaxf(tm[i], tm[i+w]);
    float mx = fmaxf(tm[0], __shfl_xor(tm[0], 32));
    // defer-max: skip rescale unless the max moved a lot (66 raw = 8.25 scaled)
    float mn;
    if (__all(mx - mrow <= 66.0f)) {
      mn = mrow;
    } else {
      mn = fmaxf(mrow, mx);
      float sc = exp2f((mrow - mn) * CE);
      mrow = mn;
      lrow *= sc;
#pragma unroll
      for (int dm = 0; dm < 2; ++dm)
#pragma unroll
        for (int i = 0; i < 16; ++i) accO[dm][i] *= sc;
    }
    // exp + tree sum
    float ts[16];
#pragma unroll
    for (int c = 0; c < 2; ++c)
#pragma unroll
      for (int i = 0; i < 16; ++i)
        st[c][i] = exp2f((st[c][i] - mn) * CE);
#pragma unroll
    for (int i = 0; i < 8; ++i) ts[i]   = st[0][2*i] + st[0][2*i+1];
#pragma unroll
    for (int i = 0; i < 8; ++i) ts[8+i] = st[1][2*i] + st[1][2*i+1];
#pragma unroll
    for (int w = 8; w >= 1; w >>= 1)
#pragma unroll
      for (int i = 0; i < 8; ++i) if (i < w) ts[i] += ts[i+w];
    float ps = ts[0] + __shfl_xor(ts[0], 32);
    lrow += ps;

    // PV: P packed from registers in natural order; V pre-permuted to match
#pragma unroll
    for (int c = 0; c < 2; ++c) {
#pragma unroll
      for (int kc = 0; kc < 2; ++kc) {
        union { s8v v; unsigned int w[4]; } pb;
#pragma unroll
        for (int wd = 0; wd < 4; ++wd) {
          u16 lo16 = f2b(st[c][kc*8 + wd*2]);
          u16 hi16 = f2b(st[c][kc*8 + wd*2 + 1]);
          pb.w[wd] = (unsigned int)lo16 | ((unsigned int)hi16 << 16);
        }
        __builtin_amdgcn_s_setprio(1);
#pragma unroll
        for (int dm = 0; dm < 2; ++dm) {
          s8v vf = *(const s8v*)(Vh + (size_t)(dm*32 + lq)*4096 + kt + c*32 + kc*16 + lh*8);
          accO[dm] = __builtin_amdgcn_mfma_f32_32x32x16_bf16(vf, pb.v, accO[dm], 0, 0, 0);
        }
        __builtin_amdgcn_s_setprio(0);
      }
    }
  }

  // tree merge across the 8 split-waves
#pragma unroll
  for (int lev = 0; lev < 3; ++lev) {
    const int step = 1 << lev;
    __syncthreads();
    if ((s & (2*step - 1)) == step) {
      int slot = (s - step) >> (lev + 1);
      if (l < 32) { lds_m[slot][lq] = mrow; lds_l[slot][lq] = lrow; }
#pragma unroll
      for (int dm = 0; dm < 2; ++dm)
#pragma unroll
        for (int g = 0; g < 4; ++g) {
          f4v v;
#pragma unroll
          for (int rr = 0; rr < 4; ++rr) v[rr] = accO[dm][g*4 + rr];
          *(f4v*)&lds_O[slot][lq][dm*32 + lh*4 + g*8] = v;
        }
    }
    __syncthreads();
    if ((s & (2*step - 1)) == 0) {
      int slot = s >> (lev + 1);
      float mp = lds_m[slot][lq], lp = lds_l[slot][lq];
      float M = fmaxf(mrow, mp);
      float w0 = exp2f((mrow - M) * CE);
      float w1 = exp2f((mp - M) * CE);
      lrow = lrow * w0 + lp * w1;
      mrow = M;
#pragma unroll
      for (int dm = 0; dm < 2; ++dm)
#pragma unroll
        for (int g = 0; g < 4; ++g) {
          f4v vp = *(const f4v*)&lds_O[slot][lq][dm*32 + lh*4 + g*8];
#pragma unroll
          for (int rr = 0; rr < 4; ++rr)
            accO[dm][g*4 + rr] = accO[dm][g*4 + rr] * w0 + vp[rr] * w1;
        }
    }
  }

  if (s == 0) {
    float inv = 1.f / lrow;
#pragma unroll
    for (int dm = 0; dm < 2; ++dm)
#pragma unroll
      for (int g = 0; g < 4; ++g) {
        u16 o4[4];
#pragma unroll
        for (int rr = 0; rr < 4; ++rr) o4[rr] = f2b(accO[dm][g*4 + rr] * inv);
        *(uint2*)(attno_b + (size_t)(q0 + lq)*256 + head*64 + dm*32 + lh*4 + g*8) = *(uint2*)o4;
      }
  }
}

// ===================== host launcher =====================
extern "C" void kernel_launch(void* const* d_in, const int* in_sizes, int n_in,
                              void* d_out, int out_size, void* d_ws, size_t ws_size,
                              hipStream_t stream)
{
  const float* x       = (const float*)d_in[0];
  const int*   ei      = (const int*)d_in[1];
  const float* gat1_w  = (const float*)d_in[2];
  const float* gat1_as = (const float*)d_in[3];
  const float* gat1_ad = (const float*)d_in[4];
  const float* gat1_b  = (const float*)d_in[5];
  const float* inp_w   = (const float*)d_in[6];
  const float* inp_b   = (const float*)d_in[7];
  const float* outp_w  = (const float*)d_in[8];
  const float* outp_b  = (const float*)d_in[9];
  const float* lin1_w  = (const float*)d_in[10];
  const float* lin1_b  = (const float*)d_in[11];
  const float* lin2_w  = (const float*)d_in[12];
  const float* lin2_b  = (const float*)d_in[13];
  const float* ln1_g   = (const float*)d_in[14];
  const float* ln1_bb  = (const float*)d_in[15];
  const float* ln2_g   = (const float*)d_in[16];
  const float* ln2_bb  = (const float*)d_in[17];
  const float* gat2_w  = (const float*)d_in[18];
  const float* gat2_as = (const float*)d_in[19];
  const float* gat2_ad = (const float*)d_in[20];
  const float* gat2_b  = (const float*)d_in[21];
  float* out = (float*)d_out;
  (void)in_sizes; (void)n_in; (void)out_size; (void)ws_size;

  char* ws = (char*)d_ws;
  size_t off = 0;
  auto nxt = [&](size_t bytes) { size_t r = off; off += (bytes + 255) & ~(size_t)255; return r; };
  int* deg      = (int*)(ws + nxt((size_t)NN*4));
  int* cursor   = (int*)(ws + nxt((size_t)NN*4));
  int* rowptr   = (int*)(ws + nxt((size_t)(NN+1)*4));
  int* csr_src  = (int*)(ws + nxt((size_t)EE*4));
  float* al1s   = (float*)(ws + nxt((size_t)NN*4*4));
  float* al1d   = (float*)(ws + nxt((size_t)NN*4*4));
  float* hgat1  = (float*)(ws + nxt((size_t)NN*256*4));
  float* tmp256 = (float*)(ws + nxt((size_t)NN*256*4));
  float* hln1   = (float*)(ws + nxt((size_t)NN*256*4));
  float* hln2   = (float*)(ws + nxt((size_t)NN*256*4));
  float* Po     = (float*)(ws + nxt((size_t)4*NN*256*4));   // 16MB split-K partials
  float* al2s   = (float*)(ws + nxt((size_t)NN*4));
  float* al2d   = (float*)(ws + nxt((size_t)NN*4));
  u16* x_b      = (u16*)(ws + nxt((size_t)NN*128*2));
  u16* feat1_b  = (u16*)(ws + nxt((size_t)NN*256*2));
  u16* feat2_b  = (u16*)(ws + nxt((size_t)NN*128*2));
  u16* hgat1_b  = (u16*)(ws + nxt((size_t)NN*256*2));
  u16* attno_b  = (u16*)(ws + nxt((size_t)NN*256*2));
  u16* hln1_b   = (u16*)(ws + nxt((size_t)NN*256*2));
  u16* hln2_b   = (u16*)(ws + nxt((size_t)NN*256*2));
  u16* ff1_b    = (u16*)(ws + nxt((size_t)NN*2048*2));
  u16* Qb       = (u16*)(ws + nxt((size_t)4*4096*64*2));
  u16* Kb       = (u16*)(ws + nxt((size_t)4*4096*64*2));
  u16* Vt       = (u16*)(ws + nxt((size_t)4*4096*64*2));
  u16* inp_w_b  = (u16*)(ws + nxt((size_t)768*256*2));
  u16* outp_w_b = (u16*)(ws + nxt((size_t)256*256*2));
  u16* lin1_w_b = (u16*)(ws + nxt((size_t)2048*256*2));
  u16* lin2_w_b = (u16*)(ws + nxt((size_t)256*2048*2));
  u16* gat1_w_b = (u16*)(ws + nxt((size_t)256*128*2));
  u16* gat2_w_b = (u16*)(ws + nxt((size_t)128*256*2));

  hipMemsetAsync(deg, 0, (size_t)NN*4, stream);
  hipMemsetAsync(cursor, 0, (size_t)NN*4, stream);
  k_count<<<(EE+255)/256, 256, 0, stream>>>(ei, deg);
  k_scan<<<1, 1024, 0, stream>>>(deg, rowptr);
  k_scatter<<<(EE+255)/256, 256, 0, stream>>>(ei, rowptr, cursor, csr_src);

  // all fp32->bf16 conversions in one launch (cumulative float4 ends)
  k_f2b_all<<<1856, 256, 0, stream>>>(
      inp_w,  inp_w_b,  49152,
      outp_w, outp_w_b, 65536,
      lin1_w, lin1_w_b, 196608,
      lin2_w, lin2_w_b, 327680,
      gat1_w, gat1_w_b, 335872,
      gat2_w, gat2_w_b, 344064,
      x,      x_b,      475136);

  // GAT layer 1: proj (MFMA) + logits + aggregate (+ELU)
  k_gemm_mfma<2><<<dim3(4, 64), 256, 0, stream>>>(x_b, gat1_w_b, nullptr, nullptr, feat1_b, nullptr, nullptr, nullptr, NN, 256, 128);
  k_alogits<4,64><<<NN, 256, 0, stream>>>(feat1_b, gat1_as, gat1_ad, al1s, al1d);
  k_gat_agg<4,64,true,true><<<NN, 256, 0, stream>>>(feat1_b, al1s, al1d, gat1_b, rowptr, csr_src, hgat1, hgat1_b);

  // Transformer encoder layer
  k_gemm_mfma<3><<<dim3(12, 64), 256, 0, stream>>>(hgat1_b, inp_w_b, inp_b, nullptr, nullptr, Qb, Kb, Vt, NN, 768, 256);
  k_attn2<<<dim3(128, 4), 512, 0, stream>>>(Qb, Kb, Vt, attno_b);
  k_gemm_mfma<0><<<dim3(4, 64), 256, 0, stream>>>(attno_b, outp_w_b, outp_b, tmp256, nullptr, nullptr, nullptr, nullptr, NN, 256, 256);
  k_ln<true><<<NN, 256, 0, stream>>>(tmp256, hgat1, ln1_g, ln1_bb, hln1, hln1_b);
  k_gemm_mfma<1><<<dim3(32, 64), 256, 0, stream>>>(hln1_b, lin1_w_b, lin1_b, nullptr, ff1_b, nullptr, nullptr, nullptr, NN, 2048, 256);
  k_gemm_sk<<<dim3(4, 64, 4), 256, 0, stream>>>(ff1_b, lin2_w_b, Po, NN, 256, 2048);
  k_ln_sk<true><<<NN, 256, 0, stream>>>(Po, lin2_b, hln1, ln2_g, ln2_bb, hln2, hln2_b);

  // GAT layer 2 -> final output
  k_gemm_mfma<2><<<dim3(2, 64), 256, 0, stream>>>(hln2_b, gat2_w_b, nullptr, nullptr, feat2_b, nullptr, nullptr, nullptr, NN, 128, 256);
  k_alogits<1,128><<<NN, 128, 0, stream>>>(feat2_b, gat2_as, gat2_ad, al2s, al2d);
  k_gat_agg<1,128,false,false><<<NN, 128, 0, stream>>>(feat2_b, al2s, al2d, gat2_b, rowptr, csr_src, out, nullptr);
}

// Round 7
// 306.198 us; speedup vs baseline: 3.1804x; 1.0045x over previous
//
#include <hip/hip_runtime.h>
#include <hip/hip_bf16.h>
#include <math.h>

#define NN 4096
#define NE 131072
#define EE (NE + NN)

typedef unsigned short u16;
typedef short s8v __attribute__((ext_vector_type(8)));
typedef float f4v __attribute__((ext_vector_type(4)));
typedef float f16v __attribute__((ext_vector_type(16)));

__device__ inline u16 f2b(float f) {
  __hip_bfloat16 h = __float2bfloat16(f);
  return __builtin_bit_cast(u16, h);
}
__device__ inline float b2f(u16 v) {
  unsigned int u = ((unsigned int)v) << 16;
  return __builtin_bit_cast(float, u);
}

// ===================== CSR build =====================
__global__ void k_count(const int* __restrict__ ei, int* __restrict__ deg) {
  int e = blockIdx.x * 256 + threadIdx.x;
  if (e >= EE) return;
  int dst = (e < NE) ? ei[NE + e] : (e - NE);
  atomicAdd(&deg[dst], 1);
}

__global__ __launch_bounds__(1024) void k_scan(const int* __restrict__ deg, int* __restrict__ rowptr) {
  __shared__ int lds[1024];
  int t = threadIdx.x;
  int v0 = deg[t*4+0], v1 = deg[t*4+1], v2 = deg[t*4+2], v3 = deg[t*4+3];
  int s1 = v0+v1, s2 = s1+v2, s3 = s2+v3;
  lds[t] = s3;
  __syncthreads();
  for (int off = 1; off < 1024; off <<= 1) {
    int add = (t >= off) ? lds[t-off] : 0;
    __syncthreads();
    lds[t] += add;
    __syncthreads();
  }
  int base = lds[t] - s3;
  rowptr[t*4+1] = base + v0;
  rowptr[t*4+2] = base + s1;
  rowptr[t*4+3] = base + s2;
  rowptr[t*4+4] = base + s3;
  if (t == 0) rowptr[0] = 0;
}

__global__ void k_scatter(const int* __restrict__ ei, const int* __restrict__ rowptr,
                          int* __restrict__ cursor, int* __restrict__ csr_src) {
  int e = blockIdx.x * 256 + threadIdx.x;
  if (e >= EE) return;
  int src, dst;
  if (e < NE) { src = ei[e]; dst = ei[NE + e]; }
  else { src = e - NE; dst = src; }
  int pos = rowptr[dst] + atomicAdd(&cursor[dst], 1);
  csr_src[pos] = src;
}

// ===================== batched fp32 -> bf16 conversion =====================
__global__ __launch_bounds__(256) void k_f2b_all(
    const float* a0, u16* b0, int e0, const float* a1, u16* b1, int e1,
    const float* a2, u16* b2, int e2, const float* a3, u16* b3, int e3,
    const float* a4, u16* b4, int e4, const float* a5, u16* b5, int e5,
    const float* a6, u16* b6, int e6)
{
  int i = blockIdx.x * 256 + threadIdx.x;
  const float* s; u16* d; int base;
  if      (i < e0) { s=a0; d=b0; base=0;  }
  else if (i < e1) { s=a1; d=b1; base=e0; }
  else if (i < e2) { s=a2; d=b2; base=e1; }
  else if (i < e3) { s=a3; d=b3; base=e2; }
  else if (i < e4) { s=a4; d=b4; base=e3; }
  else if (i < e5) { s=a5; d=b5; base=e4; }
  else if (i < e6) { s=a6; d=b6; base=e5; }
  else return;
  int j = i - base;
  float4 v = ((const float4*)s)[j];
  u16 r[4] = {f2b(v.x), f2b(v.y), f2b(v.z), f2b(v.w)};
  *(uint2*)(d + (size_t)j*4) = *(uint2*)r;
}

// ===================== a-logits via wave shuffles =====================
template<int HEADS, int C>
__global__ __launch_bounds__(256) void k_alogits(
    const u16* __restrict__ featb, const float* __restrict__ asrc,
    const float* __restrict__ adst, float* __restrict__ als, float* __restrict__ ald)
{
  constexpr int F = HEADS * C;
  int n = blockIdx.x, t = threadIdx.x;
  float f = b2f(featb[(size_t)n*F + t]);
  float ps = f * asrc[t];
  float pd = f * adst[t];
  #pragma unroll
  for (int off = 32; off; off >>= 1) {
    ps += __shfl_xor(ps, off);
    pd += __shfl_xor(pd, off);
  }
  if constexpr (C == 64) {
    if ((t & 63) == 0) {
      int hh = t >> 6;
      als[(size_t)n*HEADS + hh] = ps;
      ald[(size_t)n*HEADS + hh] = pd;
    }
  } else {
    __shared__ float sh[2][2];
    if ((t & 63) == 0) { sh[t>>6][0] = ps; sh[t>>6][1] = pd; }
    __syncthreads();
    if (t == 0) {
      als[n] = sh[0][0] + sh[1][0];
      ald[n] = sh[0][1] + sh[1][1];
    }
  }
}

// ===================== GAT aggregation (bf16 feat gather) =====================
template<int HEADS, int C, bool DO_ELU, bool WB>
__global__ __launch_bounds__(256) void k_gat_agg(
    const u16* __restrict__ featb, const float* __restrict__ als,
    const float* __restrict__ ald, const float* __restrict__ bias,
    const int* __restrict__ rowptr, const int* __restrict__ csr_src,
    float* __restrict__ out, u16* __restrict__ outb)
{
  constexpr int F = HEADS * C;
  int n = blockIdx.x, t = threadIdx.x;
  __shared__ float m_sh[HEADS], s_sh[HEADS];
  int start = rowptr[n];
  int deg = rowptr[n+1] - start;
  int lane = t & 63, wv = t >> 6;
  for (int hh = wv; hh < HEADS; hh += F/64) {
    float adl = ald[(size_t)n*HEADS + hh];
    float mx = -INFINITY;
    for (int i = lane; i < deg; i += 64) {
      int s = csr_src[start + i];
      float lg = als[(size_t)s*HEADS + hh] + adl;
      lg = (lg > 0.f) ? lg : 0.2f * lg;
      mx = fmaxf(mx, lg);
    }
    #pragma unroll
    for (int off = 32; off; off >>= 1) mx = fmaxf(mx, __shfl_xor(mx, off));
    float sm = 0.f;
    for (int i = lane; i < deg; i += 64) {
      int s = csr_src[start + i];
      float lg = als[(size_t)s*HEADS + hh] + adl;
      lg = (lg > 0.f) ? lg : 0.2f * lg;
      sm += expf(lg - mx);
    }
    #pragma unroll
    for (int off = 32; off; off >>= 1) sm += __shfl_xor(sm, off);
    if (lane == 0) { m_sh[hh] = mx; s_sh[hh] = sm; }
  }
  __syncthreads();
  int hh = t / C;
  float adl = ald[(size_t)n*HEADS + hh];
  float mh = m_sh[hh];
  float acc0 = 0.f, acc1 = 0.f;
  int i = 0;
  for (; i + 1 < deg; i += 2) {
    int s0 = csr_src[start + i];
    int s1 = csr_src[start + i + 1];
    float lg0 = als[(size_t)s0*HEADS + hh] + adl;
    float lg1 = als[(size_t)s1*HEADS + hh] + adl;
    lg0 = (lg0 > 0.f) ? lg0 : 0.2f * lg0;
    lg1 = (lg1 > 0.f) ? lg1 : 0.2f * lg1;
    float p0 = expf(lg0 - mh);
    float p1 = expf(lg1 - mh);
    acc0 += p0 * b2f(featb[(size_t)s0*F + t]);
    acc1 += p1 * b2f(featb[(size_t)s1*F + t]);
  }
  if (i < deg) {
    int s0 = csr_src[start + i];
    float lg0 = als[(size_t)s0*HEADS + hh] + adl;
    lg0 = (lg0 > 0.f) ? lg0 : 0.2f * lg0;
    acc0 += expf(lg0 - mh) * b2f(featb[(size_t)s0*F + t]);
  }
  float o = (acc0 + acc1) / (s_sh[hh] + 1e-16f) + bias[t];
  if (DO_ELU) o = (o > 0.f) ? o : (expf(o) - 1.f);
  out[(size_t)n*F + t] = o;
  if (WB) outb[(size_t)n*F + t] = f2b(o);
}

// ===================== bf16 MFMA GEMM 64x64: MODE 0 f32, 2 bf16, 3 qkv scatter =====================
template<int MODE>
__global__ __launch_bounds__(256) void k_gemm_mfma(
    const u16* __restrict__ A, const u16* __restrict__ B,
    const float* __restrict__ bias, float* __restrict__ Cf, u16* __restrict__ Cb,
    u16* __restrict__ Qb, u16* __restrict__ Kb, u16* __restrict__ Vt,
    int M, int N, int K)
{
  __shared__ u16 Al[64*64];
  __shared__ u16 Bl[64*64];
  char* Ab = (char*)Al;
  char* Bb = (char*)Bl;
  const int t = threadIdx.x;
  const int lane = t & 63;
  const int lr = lane & 15, lk = lane >> 4;
  const int wid = t >> 6;
  const int wm = wid & 1, wn = wid >> 1;
  const int m0 = blockIdx.y * 64, n0 = blockIdx.x * 64;

  f4v acc[2][2];
  #pragma unroll
  for (int mi = 0; mi < 2; ++mi)
    #pragma unroll
    for (int ni = 0; ni < 2; ++ni)
      acc[mi][ni] = f4v{0.f, 0.f, 0.f, 0.f};

  for (int k0 = 0; k0 < K; k0 += 64) {
    #pragma unroll
    for (int i = 0; i < 2; ++i) {
      int idx = t + i*256;
      int row = idx >> 3, ch = idx & 7;
      s8v av = *(const s8v*)(A + (size_t)(m0 + row)*K + k0 + ch*8);
      *(s8v*)(Ab + row*128 + ((ch*16) ^ ((row & 7) << 4))) = av;
      s8v bv = *(const s8v*)(B + (size_t)(n0 + row)*K + k0 + ch*8);
      *(s8v*)(Bb + row*128 + ((ch*16) ^ ((row & 7) << 4))) = bv;
    }
    __syncthreads();
    #pragma unroll
    for (int ks = 0; ks < 2; ++ks) {
      s8v af[2], bfr[2];
      #pragma unroll
      for (int mi = 0; mi < 2; ++mi) {
        int row = wm*32 + mi*16 + lr;
        int ch = ks*4 + lk;
        af[mi] = *(const s8v*)(Ab + row*128 + ((ch*16) ^ ((row & 7) << 4)));
      }
      #pragma unroll
      for (int ni = 0; ni < 2; ++ni) {
        int row = wn*32 + ni*16 + lr;
        int ch = ks*4 + lk;
        bfr[ni] = *(const s8v*)(Bb + row*128 + ((ch*16) ^ ((row & 7) << 4)));
      }
      #pragma unroll
      for (int mi = 0; mi < 2; ++mi)
        #pragma unroll
        for (int ni = 0; ni < 2; ++ni)
          acc[mi][ni] = __builtin_amdgcn_mfma_f32_16x16x32_bf16(af[mi], bfr[ni], acc[mi][ni], 0, 0, 0);
    }
    __syncthreads();
  }
  #pragma unroll
  for (int ni = 0; ni < 2; ++ni) {
    int col = n0 + wn*32 + ni*16 + lr;
    float bc = bias ? bias[col] : 0.f;
    #pragma unroll
    for (int mi = 0; mi < 2; ++mi) {
      int row0 = m0 + wm*32 + mi*16 + lk*4;
      float v[4];
      #pragma unroll
      for (int r = 0; r < 4; ++r) v[r] = acc[mi][ni][r] + bc;
      if (MODE == 0) {
        #pragma unroll
        for (int r = 0; r < 4; ++r) Cf[(size_t)(row0 + r)*N + col] = v[r];
      } else if (MODE == 2) {
        #pragma unroll
        for (int r = 0; r < 4; ++r) Cb[(size_t)(row0 + r)*N + col] = f2b(v[r]);
      } else { // MODE 3: qkv scatter
        if (col < 512) {
          int head = (col >> 6) & 3;
          int d = col & 63;
          u16* dst = ((col < 256) ? Qb : Kb) + (size_t)head*262144 + d;
          #pragma unroll
          for (int r = 0; r < 4; ++r) dst[(size_t)(row0 + r)*64] = f2b(v[r]);
        } else {
          int cc = col - 512;
          int head = cc >> 6;
          int d = cc & 63;
          int quad = row0 & 12;
          int qs = (quad == 4) ? 8 : ((quad == 8) ? 4 : quad);
          size_t nphys = (size_t)((row0 & ~15) | qs);
          u16 o4[4];
          #pragma unroll
          for (int r = 0; r < 4; ++r) o4[r] = f2b(v[r]);
          *(uint2*)(Vt + (size_t)head*262144 + (size_t)d*4096 + nphys) = *(uint2*)o4;
        }
      }
    }
  }
}

// ===================== bf16 MFMA GEMM 128x64 tile: MODE 1 relu+bf16, MODE 4 split-K f32 partials =====================
template<int MODE>
__global__ __launch_bounds__(256) void k_gemm2(
    const u16* __restrict__ A, const u16* __restrict__ B,
    const float* __restrict__ bias, float* __restrict__ Cf, u16* __restrict__ Cb,
    int M, int N, int K, int ksl)
{
  __shared__ u16 Al[128*64];
  __shared__ u16 Bl[64*64];
  char* Ab = (char*)Al;
  char* Bb = (char*)Bl;
  const int t = threadIdx.x;
  const int lane = t & 63;
  const int lr = lane & 15, lk = lane >> 4;
  const int wv = t >> 6;
  const int m0 = blockIdx.y * 128, n0 = blockIdx.x * 64;
  const int z = blockIdx.z;
  const int kbeg = z * ksl, kend = kbeg + ksl;

  f4v acc[2][4];
  #pragma unroll
  for (int mi = 0; mi < 2; ++mi)
    #pragma unroll
    for (int ni = 0; ni < 4; ++ni)
      acc[mi][ni] = f4v{0.f, 0.f, 0.f, 0.f};

  for (int k0 = kbeg; k0 < kend; k0 += 64) {
    #pragma unroll
    for (int i = 0; i < 4; ++i) {
      int idx = t + i*256;
      int row = idx >> 3, ch = idx & 7;
      s8v av = *(const s8v*)(A + (size_t)(m0 + row)*K + k0 + ch*8);
      *(s8v*)(Ab + row*128 + ((ch*16) ^ ((row & 7) << 4))) = av;
    }
    #pragma unroll
    for (int i = 0; i < 2; ++i) {
      int idx = t + i*256;
      int row = idx >> 3, ch = idx & 7;
      s8v bv = *(const s8v*)(B + (size_t)(n0 + row)*K + k0 + ch*8);
      *(s8v*)(Bb + row*128 + ((ch*16) ^ ((row & 7) << 4))) = bv;
    }
    __syncthreads();
    #pragma unroll
    for (int ks = 0; ks < 2; ++ks) {
      s8v af[2], bfr[4];
      #pragma unroll
      for (int mi = 0; mi < 2; ++mi) {
        int row = wv*32 + mi*16 + lr;
        int ch = ks*4 + lk;
        af[mi] = *(const s8v*)(Ab + row*128 + ((ch*16) ^ ((row & 7) << 4)));
      }
      #pragma unroll
      for (int ni = 0; ni < 4; ++ni) {
        int row = ni*16 + lr;
        int ch = ks*4 + lk;
        bfr[ni] = *(const s8v*)(Bb + row*128 + ((ch*16) ^ ((row & 7) << 4)));
      }
      #pragma unroll
      for (int mi = 0; mi < 2; ++mi)
        #pragma unroll
        for (int ni = 0; ni < 4; ++ni)
          acc[mi][ni] = __builtin_amdgcn_mfma_f32_16x16x32_bf16(af[mi], bfr[ni], acc[mi][ni], 0, 0, 0);
    }
    __syncthreads();
  }
  #pragma unroll
  for (int ni = 0; ni < 4; ++ni) {
    int col = n0 + ni*16 + lr;
    float bc = (MODE == 4) ? 0.f : bias[col];
    #pragma unroll
    for (int mi = 0; mi < 2; ++mi) {
      int row0 = m0 + wv*32 + mi*16 + lk*4;
      #pragma unroll
      for (int r = 0; r < 4; ++r) {
        float v = acc[mi][ni][r] + bc;
        if (MODE == 1) {
          v = fmaxf(v, 0.f);
          Cb[(size_t)(row0 + r)*N + col] = f2b(v);
        } else {
          (Cf + (size_t)z*M*N)[(size_t)(row0 + r)*N + col] = v;
        }
      }
    }
  }
}

// ===================== LayerNorm(a + res) =====================
template<bool WB>
__global__ __launch_bounds__(256) void k_ln(
    const float* __restrict__ a, const float* __restrict__ res,
    const float* __restrict__ g, const float* __restrict__ bb,
    float* __restrict__ out, u16* __restrict__ outb)
{
  int n = blockIdx.x, t = threadIdx.x;
  __shared__ float part[4];
  float v = a[(size_t)n*256 + t] + res[(size_t)n*256 + t];
  float s = v;
  #pragma unroll
  for (int off = 32; off; off >>= 1) s += __shfl_xor(s, off);
  if ((t & 63) == 0) part[t >> 6] = s;
  __syncthreads();
  float mean = (part[0] + part[1] + part[2] + part[3]) * (1.f/256.f);
  __syncthreads();
  float d = v - mean;
  float s2 = d * d;
  #pragma unroll
  for (int off = 32; off; off >>= 1) s2 += __shfl_xor(s2, off);
  if ((t & 63) == 0) part[t >> 6] = s2;
  __syncthreads();
  float var = (part[0] + part[1] + part[2] + part[3]) * (1.f/256.f);
  float rstd = rsqrtf(var + 1e-5f);
  float o = d * rstd * g[t] + bb[t];
  out[(size_t)n*256 + t] = o;
  if (WB) outb[(size_t)n*256 + t] = f2b(o);
}

// ===================== LayerNorm over 4 split-K partials + bias + res =====================
template<bool WB>
__global__ __launch_bounds__(256) void k_ln_sk(
    const float* __restrict__ Po, const float* __restrict__ bias,
    const float* __restrict__ res, const float* __restrict__ g,
    const float* __restrict__ bb, float* __restrict__ out, u16* __restrict__ outb)
{
  int n = blockIdx.x, t = threadIdx.x;
  __shared__ float part[4];
  const size_t MN = (size_t)NN * 256;
  size_t idx = (size_t)n*256 + t;
  float v = Po[idx] + Po[MN + idx] + Po[2*MN + idx] + Po[3*MN + idx]
          + bias[t] + res[idx];
  float s = v;
  #pragma unroll
  for (int off = 32; off; off >>= 1) s += __shfl_xor(s, off);
  if ((t & 63) == 0) part[t >> 6] = s;
  __syncthreads();
  float mean = (part[0] + part[1] + part[2] + part[3]) * (1.f/256.f);
  __syncthreads();
  float d = v - mean;
  float s2 = d * d;
  #pragma unroll
  for (int off = 32; off; off >>= 1) s2 += __shfl_xor(s2, off);
  if ((t & 63) == 0) part[t >> 6] = s2;
  __syncthreads();
  float var = (part[0] + part[1] + part[2] + part[3]) * (1.f/256.f);
  float rstd = rsqrtf(var + 1e-5f);
  float o = d * rstd * g[t] + bb[t];
  out[idx] = o;
  if (WB) outb[idx] = f2b(o);
}

// ===================== bf16 MFMA flash attention v3 =====================
// 8-wave blocks; wave s covers keys [s*512, s*512+512) for a 32-query strip.
// Swapped QK^T; K double-buffered in registers one tile ahead; V issued
// right after QK so softmax hides its latency; exact rescale-skip.
#define LOADK(KB, ktn) do { \
  _Pragma("unroll") \
  for (int dc = 0; dc < 4; ++dc) { \
    KB[dc*2+0] = *(const s8v*)(Kh + (size_t)((ktn) + lq)*64 + dc*16 + lh*8); \
    KB[dc*2+1] = *(const s8v*)(Kh + (size_t)((ktn) + 32 + lq)*64 + dc*16 + lh*8); \
  } \
} while (0)

#define TILE(ktc, KB) do { \
  f16v st0, st1; \
  _Pragma("unroll") \
  for (int i = 0; i < 16; ++i) { st0[i] = 0.f; st1[i] = 0.f; } \
  _Pragma("unroll") \
  for (int dc = 0; dc < 4; ++dc) { \
    st0 = __builtin_amdgcn_mfma_f32_32x32x16_bf16(KB[dc*2+0], qf[dc], st0, 0, 0, 0); \
    st1 = __builtin_amdgcn_mfma_f32_32x32x16_bf16(KB[dc*2+1], qf[dc], st1, 0, 0, 0); \
  } \
  s8v vb[8]; \
  _Pragma("unroll") \
  for (int c = 0; c < 2; ++c) \
    _Pragma("unroll") \
    for (int kc = 0; kc < 2; ++kc) \
      _Pragma("unroll") \
      for (int dm = 0; dm < 2; ++dm) \
        vb[(c*2+kc)*2+dm] = *(const s8v*)(Vh + (size_t)(dm*32 + lq)*4096 + (ktc) + c*32 + kc*16 + lh*8); \
  float tm[16]; \
  _Pragma("unroll") \
  for (int i = 0; i < 8; ++i) tm[i]   = fmaxf(st0[2*i], st0[2*i+1]); \
  _Pragma("unroll") \
  for (int i = 0; i < 8; ++i) tm[8+i] = fmaxf(st1[2*i], st1[2*i+1]); \
  _Pragma("unroll") \
  for (int w = 8; w >= 1; w >>= 1) \
    _Pragma("unroll") \
    for (int i = 0; i < 8; ++i) if (i < w) tm[i] = fmaxf(tm[i], tm[i+w]); \
  float mx = fmaxf(tm[0], __shfl_xor(tm[0], 32)); \
  float mn; \
  if (__all(mx <= mrow)) { \
    mn = mrow; \
  } else { \
    mn = fmaxf(mrow, mx); \
    float sc = exp2f((mrow - mn) * CE); \
    mrow = mn; \
    lrow *= sc; \
    _Pragma("unroll") \
    for (int dm = 0; dm < 2; ++dm) \
      _Pragma("unroll") \
      for (int i = 0; i < 16; ++i) accO[dm][i] *= sc; \
  } \
  float ts[16]; \
  _Pragma("unroll") \
  for (int i = 0; i < 16; ++i) st0[i] = exp2f((st0[i] - mn) * CE); \
  _Pragma("unroll") \
  for (int i = 0; i < 16; ++i) st1[i] = exp2f((st1[i] - mn) * CE); \
  _Pragma("unroll") \
  for (int i = 0; i < 8; ++i) ts[i]   = st0[2*i] + st0[2*i+1]; \
  _Pragma("unroll") \
  for (int i = 0; i < 8; ++i) ts[8+i] = st1[2*i] + st1[2*i+1]; \
  _Pragma("unroll") \
  for (int w = 8; w >= 1; w >>= 1) \
    _Pragma("unroll") \
    for (int i = 0; i < 8; ++i) if (i < w) ts[i] += ts[i+w]; \
  lrow += ts[0] + __shfl_xor(ts[0], 32); \
  _Pragma("unroll") \
  for (int c = 0; c < 2; ++c) { \
    _Pragma("unroll") \
    for (int kc = 0; kc < 2; ++kc) { \
      union { s8v v; unsigned int w[4]; } pb; \
      _Pragma("unroll") \
      for (int wd = 0; wd < 4; ++wd) { \
        float e0 = (c == 0) ? st0[kc*8 + wd*2]     : st1[kc*8 + wd*2]; \
        float e1 = (c == 0) ? st0[kc*8 + wd*2 + 1] : st1[kc*8 + wd*2 + 1]; \
        pb.w[wd] = (unsigned int)f2b(e0) | ((unsigned int)f2b(e1) << 16); \
      } \
      _Pragma("unroll") \
      for (int dm = 0; dm < 2; ++dm) \
        accO[dm] = __builtin_amdgcn_mfma_f32_32x32x16_bf16(vb[(c*2+kc)*2+dm], pb.v, accO[dm], 0, 0, 0); \
    } \
  } \
} while (0)

__global__ __launch_bounds__(512) void k_attn2(
    const u16* __restrict__ Qb, const u16* __restrict__ Kb,
    const u16* __restrict__ Vt, u16* __restrict__ attno_b)
{
  const int strip = blockIdx.x;
  const int head  = blockIdx.y;
  const int q0 = strip * 32;
  const int t = threadIdx.x;
  const int s = t >> 6;
  const int l = t & 63;
  const int lq = l & 31;
  const int lh = l >> 5;

  __shared__ float lds_O[4][32][68];
  __shared__ float lds_m[4][32];
  __shared__ float lds_l[4][32];

  const u16* Qh = Qb + (size_t)head * (4096*64);
  const u16* Kh = Kb + (size_t)head * (4096*64);
  const u16* Vh = Vt + (size_t)head * (64*4096);

  s8v qf[4];
#pragma unroll
  for (int dc = 0; dc < 4; ++dc)
    qf[dc] = *(const s8v*)(Qh + (size_t)(q0 + lq)*64 + dc*16 + lh*8);

  f16v accO[2];
#pragma unroll
  for (int dm = 0; dm < 2; ++dm)
#pragma unroll
    for (int i = 0; i < 16; ++i) accO[dm][i] = 0.f;

  float mrow = -INFINITY, lrow = 0.f;
  const float CE = 0.18033688011112042f;  // log2(e)/8

  const int kt0 = s * 512;
  s8v kbA[8], kbB[8];
  LOADK(kbA, kt0);
  for (int kt = kt0; kt < kt0 + 512; kt += 128) {
    LOADK(kbB, kt + 64);
    TILE(kt, kbA);
    int ktn = kt + 128;
    if (ktn >= kt0 + 512) ktn = kt0;
    LOADK(kbA, ktn);
    TILE(kt + 64, kbB);
  }

  // tree merge across the 8 split-waves
#pragma unroll
  for (int lev = 0; lev < 3; ++lev) {
    const int step = 1 << lev;
    __syncthreads();
    if ((s & (2*step - 1)) == step) {
      int slot = (s - step) >> (lev + 1);
      if (l < 32) { lds_m[slot][lq] = mrow; lds_l[slot][lq] = lrow; }
#pragma unroll
      for (int dm = 0; dm < 2; ++dm)
#pragma unroll
        for (int g = 0; g < 4; ++g) {
          f4v v;
#pragma unroll
          for (int rr = 0; rr < 4; ++rr) v[rr] = accO[dm][g*4 + rr];
          *(f4v*)&lds_O[slot][lq][dm*32 + lh*4 + g*8] = v;
        }
    }
    __syncthreads();
    if ((s & (2*step - 1)) == 0) {
      int slot = s >> (lev + 1);
      float mp = lds_m[slot][lq], lp = lds_l[slot][lq];
      float M = fmaxf(mrow, mp);
      float w0 = exp2f((mrow - M) * CE);
      float w1 = exp2f((mp - M) * CE);
      lrow = lrow * w0 + lp * w1;
      mrow = M;
#pragma unroll
      for (int dm = 0; dm < 2; ++dm)
#pragma unroll
        for (int g = 0; g < 4; ++g) {
          f4v vp = *(const f4v*)&lds_O[slot][lq][dm*32 + lh*4 + g*8];
#pragma unroll
          for (int rr = 0; rr < 4; ++rr)
            accO[dm][g*4 + rr] = accO[dm][g*4 + rr] * w0 + vp[rr] * w1;
        }
    }
  }

  if (s == 0) {
    float inv = 1.f / lrow;
#pragma unroll
    for (int dm = 0; dm < 2; ++dm)
#pragma unroll
      for (int g = 0; g < 4; ++g) {
        u16 o4[4];
#pragma unroll
        for (int rr = 0; rr < 4; ++rr) o4[rr] = f2b(accO[dm][g*4 + rr] * inv);
        *(uint2*)(attno_b + (size_t)(q0 + lq)*256 + head*64 + dm*32 + lh*4 + g*8) = *(uint2*)o4;
      }
  }
}

// ===================== host launcher =====================
extern "C" void kernel_launch(void* const* d_in, const int* in_sizes, int n_in,
                              void* d_out, int out_size, void* d_ws, size_t ws_size,
                              hipStream_t stream)
{
  const float* x       = (const float*)d_in[0];
  const int*   ei      = (const int*)d_in[1];
  const float* gat1_w  = (const float*)d_in[2];
  const float* gat1_as = (const float*)d_in[3];
  const float* gat1_ad = (const float*)d_in[4];
  const float* gat1_b  = (const float*)d_in[5];
  const float* inp_w   = (const float*)d_in[6];
  const float* inp_b   = (const float*)d_in[7];
  const float* outp_w  = (const float*)d_in[8];
  const float* outp_b  = (const float*)d_in[9];
  const float* lin1_w  = (const float*)d_in[10];
  const float* lin1_b  = (const float*)d_in[11];
  const float* lin2_w  = (const float*)d_in[12];
  const float* lin2_b  = (const float*)d_in[13];
  const float* ln1_g   = (const float*)d_in[14];
  const float* ln1_bb  = (const float*)d_in[15];
  const float* ln2_g   = (const float*)d_in[16];
  const float* ln2_bb  = (const float*)d_in[17];
  const float* gat2_w  = (const float*)d_in[18];
  const float* gat2_as = (const float*)d_in[19];
  const float* gat2_ad = (const float*)d_in[20];
  const float* gat2_b  = (const float*)d_in[21];
  float* out = (float*)d_out;
  (void)in_sizes; (void)n_in; (void)out_size; (void)ws_size;

  char* ws = (char*)d_ws;
  size_t off = 0;
  auto nxt = [&](size_t bytes) { size_t r = off; off += (bytes + 255) & ~(size_t)255; return r; };
  int* deg      = (int*)(ws + nxt((size_t)NN*4));
  int* cursor   = (int*)(ws + nxt((size_t)NN*4));
  int* rowptr   = (int*)(ws + nxt((size_t)(NN+1)*4));
  int* csr_src  = (int*)(ws + nxt((size_t)EE*4));
  float* al1s   = (float*)(ws + nxt((size_t)NN*4*4));
  float* al1d   = (float*)(ws + nxt((size_t)NN*4*4));
  float* hgat1  = (float*)(ws + nxt((size_t)NN*256*4));
  float* tmp256 = (float*)(ws + nxt((size_t)NN*256*4));
  float* hln1   = (float*)(ws + nxt((size_t)NN*256*4));
  float* hln2   = (float*)(ws + nxt((size_t)NN*256*4));
  float* Po     = (float*)(ws + nxt((size_t)4*NN*256*4));   // 16MB split-K partials
  float* al2s   = (float*)(ws + nxt((size_t)NN*4));
  float* al2d   = (float*)(ws + nxt((size_t)NN*4));
  u16* x_b      = (u16*)(ws + nxt((size_t)NN*128*2));
  u16* feat1_b  = (u16*)(ws + nxt((size_t)NN*256*2));
  u16* feat2_b  = (u16*)(ws + nxt((size_t)NN*128*2));
  u16* hgat1_b  = (u16*)(ws + nxt((size_t)NN*256*2));
  u16* attno_b  = (u16*)(ws + nxt((size_t)NN*256*2));
  u16* hln1_b   = (u16*)(ws + nxt((size_t)NN*256*2));
  u16* hln2_b   = (u16*)(ws + nxt((size_t)NN*256*2));
  u16* ff1_b    = (u16*)(ws + nxt((size_t)NN*2048*2));
  u16* Qb       = (u16*)(ws + nxt((size_t)4*4096*64*2));
  u16* Kb       = (u16*)(ws + nxt((size_t)4*4096*64*2));
  u16* Vt       = (u16*)(ws + nxt((size_t)4*4096*64*2));
  u16* inp_w_b  = (u16*)(ws + nxt((size_t)768*256*2));
  u16* outp_w_b = (u16*)(ws + nxt((size_t)256*256*2));
  u16* lin1_w_b = (u16*)(ws + nxt((size_t)2048*256*2));
  u16* lin2_w_b = (u16*)(ws + nxt((size_t)256*2048*2));
  u16* gat1_w_b = (u16*)(ws + nxt((size_t)256*128*2));
  u16* gat2_w_b = (u16*)(ws + nxt((size_t)128*256*2));

  hipMemsetAsync(deg, 0, (size_t)NN*4, stream);
  hipMemsetAsync(cursor, 0, (size_t)NN*4, stream);
  k_count<<<(EE+255)/256, 256, 0, stream>>>(ei, deg);
  k_scan<<<1, 1024, 0, stream>>>(deg, rowptr);
  k_scatter<<<(EE+255)/256, 256, 0, stream>>>(ei, rowptr, cursor, csr_src);

  // all fp32->bf16 conversions in one launch (cumulative float4 ends)
  k_f2b_all<<<1856, 256, 0, stream>>>(
      inp_w,  inp_w_b,  49152,
      outp_w, outp_w_b, 65536,
      lin1_w, lin1_w_b, 196608,
      lin2_w, lin2_w_b, 327680,
      gat1_w, gat1_w_b, 335872,
      gat2_w, gat2_w_b, 344064,
      x,      x_b,      475136);

  // GAT layer 1: proj (MFMA) + logits + aggregate (+ELU)
  k_gemm_mfma<2><<<dim3(4, 64), 256, 0, stream>>>(x_b, gat1_w_b, nullptr, nullptr, feat1_b, nullptr, nullptr, nullptr, NN, 256, 128);
  k_alogits<4,64><<<NN, 256, 0, stream>>>(feat1_b, gat1_as, gat1_ad, al1s, al1d);
  k_gat_agg<4,64,true,true><<<NN, 256, 0, stream>>>(feat1_b, al1s, al1d, gat1_b, rowptr, csr_src, hgat1, hgat1_b);

  // Transformer encoder layer
  k_gemm_mfma<3><<<dim3(12, 64), 256, 0, stream>>>(hgat1_b, inp_w_b, inp_b, nullptr, nullptr, Qb, Kb, Vt, NN, 768, 256);
  k_attn2<<<dim3(128, 4), 512, 0, stream>>>(Qb, Kb, Vt, attno_b);
  k_gemm_mfma<0><<<dim3(4, 64), 256, 0, stream>>>(attno_b, outp_w_b, outp_b, tmp256, nullptr, nullptr, nullptr, nullptr, NN, 256, 256);
  k_ln<true><<<NN, 256, 0, stream>>>(tmp256, hgat1, ln1_g, ln1_bb, hln1, hln1_b);
  k_gemm2<1><<<dim3(32, 32), 256, 0, stream>>>(hln1_b, lin1_w_b, lin1_b, nullptr, ff1_b, NN, 2048, 256, 256);
  k_gemm2<4><<<dim3(4, 32, 4), 256, 0, stream>>>(ff1_b, lin2_w_b, nullptr, Po, nullptr, NN, 256, 2048, 512);
  k_ln_sk<true><<<NN, 256, 0, stream>>>(Po, lin2_b, hln1, ln2_g, ln2_bb, hln2, hln2_b);

  // GAT layer 2 -> final output
  k_gemm_mfma<2><<<dim3(2, 64), 256, 0, stream>>>(hln2_b, gat2_w_b, nullptr, nullptr, feat2_b, nullptr, nullptr, nullptr, NN, 128, 256);
  k_alogits<1,128><<<NN, 128, 0, stream>>>(feat2_b, gat2_as, gat2_ad, al2s, al2d);
  k_gat_agg<1,128,false,false><<<NN, 128, 0, stream>>>(feat2_b, al2s, al2d, gat2_b, rowptr, csr_src, out, nullptr);
}

// Round 8
// 300.069 us; speedup vs baseline: 3.2454x; 1.0204x over previous
//
#include <hip/hip_runtime.h>
#include <hip/hip_bf16.h>
#include <math.h>

#define NN 4096
#define NE 131072
#define EE (NE + NN)

typedef unsigned short u16;
typedef short s8v __attribute__((ext_vector_type(8)));
typedef float f4v __attribute__((ext_vector_type(4)));
typedef float f16v __attribute__((ext_vector_type(16)));

__device__ inline u16 f2b(float f) {
  __hip_bfloat16 h = __float2bfloat16(f);
  return __builtin_bit_cast(u16, h);
}
__device__ inline float b2f(u16 v) {
  unsigned int u = ((unsigned int)v) << 16;
  return __builtin_bit_cast(float, u);
}

// ===================== CSR build =====================
__global__ void k_count(const int* __restrict__ ei, int* __restrict__ deg) {
  int e = blockIdx.x * 256 + threadIdx.x;
  if (e >= EE) return;
  int dst = (e < NE) ? ei[NE + e] : (e - NE);
  atomicAdd(&deg[dst], 1);
}

__global__ __launch_bounds__(1024) void k_scan(const int* __restrict__ deg, int* __restrict__ rowptr) {
  __shared__ int lds[1024];
  int t = threadIdx.x;
  int v0 = deg[t*4+0], v1 = deg[t*4+1], v2 = deg[t*4+2], v3 = deg[t*4+3];
  int s1 = v0+v1, s2 = s1+v2, s3 = s2+v3;
  lds[t] = s3;
  __syncthreads();
  for (int off = 1; off < 1024; off <<= 1) {
    int add = (t >= off) ? lds[t-off] : 0;
    __syncthreads();
    lds[t] += add;
    __syncthreads();
  }
  int base = lds[t] - s3;
  rowptr[t*4+1] = base + v0;
  rowptr[t*4+2] = base + s1;
  rowptr[t*4+3] = base + s2;
  rowptr[t*4+4] = base + s3;
  if (t == 0) rowptr[0] = 0;
}

__global__ void k_scatter(const int* __restrict__ ei, const int* __restrict__ rowptr,
                          int* __restrict__ cursor, int* __restrict__ csr_src) {
  int e = blockIdx.x * 256 + threadIdx.x;
  if (e >= EE) return;
  int src, dst;
  if (e < NE) { src = ei[e]; dst = ei[NE + e]; }
  else { src = e - NE; dst = src; }
  int pos = rowptr[dst] + atomicAdd(&cursor[dst], 1);
  csr_src[pos] = src;
}

// ===================== batched fp32 -> bf16 conversion =====================
__global__ __launch_bounds__(256) void k_f2b_all(
    const float* a0, u16* b0, int e0, const float* a1, u16* b1, int e1,
    const float* a2, u16* b2, int e2, const float* a3, u16* b3, int e3,
    const float* a4, u16* b4, int e4, const float* a5, u16* b5, int e5,
    const float* a6, u16* b6, int e6)
{
  int i = blockIdx.x * 256 + threadIdx.x;
  const float* s; u16* d; int base;
  if      (i < e0) { s=a0; d=b0; base=0;  }
  else if (i < e1) { s=a1; d=b1; base=e0; }
  else if (i < e2) { s=a2; d=b2; base=e1; }
  else if (i < e3) { s=a3; d=b3; base=e2; }
  else if (i < e4) { s=a4; d=b4; base=e3; }
  else if (i < e5) { s=a5; d=b5; base=e4; }
  else if (i < e6) { s=a6; d=b6; base=e5; }
  else return;
  int j = i - base;
  float4 v = ((const float4*)s)[j];
  u16 r[4] = {f2b(v.x), f2b(v.y), f2b(v.z), f2b(v.w)};
  *(uint2*)(d + (size_t)j*4) = *(uint2*)r;
}

// ===================== a-logits via wave shuffles =====================
template<int HEADS, int C>
__global__ __launch_bounds__(256) void k_alogits(
    const u16* __restrict__ featb, const float* __restrict__ asrc,
    const float* __restrict__ adst, float* __restrict__ als, float* __restrict__ ald)
{
  constexpr int F = HEADS * C;
  int n = blockIdx.x, t = threadIdx.x;
  float f = b2f(featb[(size_t)n*F + t]);
  float ps = f * asrc[t];
  float pd = f * adst[t];
  #pragma unroll
  for (int off = 32; off; off >>= 1) {
    ps += __shfl_xor(ps, off);
    pd += __shfl_xor(pd, off);
  }
  if constexpr (C == 64) {
    if ((t & 63) == 0) {
      int hh = t >> 6;
      als[(size_t)n*HEADS + hh] = ps;
      ald[(size_t)n*HEADS + hh] = pd;
    }
  } else {
    __shared__ float sh[2][2];
    if ((t & 63) == 0) { sh[t>>6][0] = ps; sh[t>>6][1] = pd; }
    __syncthreads();
    if (t == 0) {
      als[n] = sh[0][0] + sh[1][0];
      ald[n] = sh[0][1] + sh[1][1];
    }
  }
}

// ===================== GAT aggregation v2: chunked alpha in LDS =====================
template<int HEADS, int C, bool DO_ELU, bool WB>
__global__ __launch_bounds__(256) void k_gat_agg(
    const u16* __restrict__ featb, const float* __restrict__ als,
    const float* __restrict__ ald, const float* __restrict__ bias,
    const int* __restrict__ rowptr, const int* __restrict__ csr_src,
    float* __restrict__ out, u16* __restrict__ outb)
{
  constexpr int F = HEADS * C;
  int n = blockIdx.x, t = threadIdx.x;
  __shared__ float m_sh[HEADS], s_sh[HEADS];
  __shared__ float alpha_sh[HEADS][64];
  __shared__ int src_sh[64];
  int start = rowptr[n];
  int deg = rowptr[n+1] - start;
  int lane = t & 63, wv = t >> 6;
  // phase 0: per-head running max + denom (wave per head)
  for (int hh = wv; hh < HEADS; hh += F/64) {
    float adl = ald[(size_t)n*HEADS + hh];
    float mx = -INFINITY;
    for (int i = lane; i < deg; i += 64) {
      int s = csr_src[start + i];
      float lg = als[(size_t)s*HEADS + hh] + adl;
      lg = (lg > 0.f) ? lg : 0.2f * lg;
      mx = fmaxf(mx, lg);
    }
    #pragma unroll
    for (int off = 32; off; off >>= 1) mx = fmaxf(mx, __shfl_xor(mx, off));
    float sm = 0.f;
    for (int i = lane; i < deg; i += 64) {
      int s = csr_src[start + i];
      float lg = als[(size_t)s*HEADS + hh] + adl;
      lg = (lg > 0.f) ? lg : 0.2f * lg;
      sm += expf(lg - mx);
    }
    #pragma unroll
    for (int off = 32; off; off >>= 1) sm += __shfl_xor(sm, off);
    if (lane == 0) { m_sh[hh] = mx; s_sh[hh] = sm; }
  }
  __syncthreads();
  int hh = t / C;
  int hh2 = t >> 6;       // alpha-compute role: (head hh2, edge slot t&63)
  int ia = t & 63;
  float acc0 = 0.f, acc1 = 0.f;
  for (int c0 = 0; c0 < deg; c0 += 64) {
    int cn = min(64, deg - c0);
    // phase A: one alpha per (edge, head)
    if (hh2 < HEADS && ia < cn) {
      int s = csr_src[start + c0 + ia];
      if (hh2 == 0) src_sh[ia] = s;
      float lg = als[(size_t)s*HEADS + hh2] + ald[(size_t)n*HEADS + hh2];
      lg = (lg > 0.f) ? lg : 0.2f * lg;
      alpha_sh[hh2][ia] = expf(lg - m_sh[hh2]);
    }
    __syncthreads();
    // phase B: gather + fma (alpha/src broadcast from LDS)
    int i = 0;
    for (; i + 1 < cn; i += 2) {
      int s0 = src_sh[i], s1 = src_sh[i+1];
      float a0 = alpha_sh[hh][i], a1 = alpha_sh[hh][i+1];
      acc0 += a0 * b2f(featb[(size_t)s0*F + t]);
      acc1 += a1 * b2f(featb[(size_t)s1*F + t]);
    }
    if (i < cn)
      acc0 += alpha_sh[hh][i] * b2f(featb[(size_t)src_sh[i]*F + t]);
    __syncthreads();
  }
  float o = (acc0 + acc1) / (s_sh[hh] + 1e-16f) + bias[t];
  if (DO_ELU) o = (o > 0.f) ? o : (expf(o) - 1.f);
  out[(size_t)n*F + t] = o;
  if (WB) outb[(size_t)n*F + t] = f2b(o);
}

// ===================== bf16 MFMA GEMM 64x64: MODE 0 f32, 2 bf16, 3 qkv scatter =====================
template<int MODE>
__global__ __launch_bounds__(256) void k_gemm_mfma(
    const u16* __restrict__ A, const u16* __restrict__ B,
    const float* __restrict__ bias, float* __restrict__ Cf, u16* __restrict__ Cb,
    u16* __restrict__ Qb, u16* __restrict__ Kb, u16* __restrict__ Vt,
    int M, int N, int K)
{
  __shared__ u16 Al[64*64];
  __shared__ u16 Bl[64*64];
  char* Ab = (char*)Al;
  char* Bb = (char*)Bl;
  const int t = threadIdx.x;
  const int lane = t & 63;
  const int lr = lane & 15, lk = lane >> 4;
  const int wid = t >> 6;
  const int wm = wid & 1, wn = wid >> 1;
  const int m0 = blockIdx.y * 64, n0 = blockIdx.x * 64;

  f4v acc[2][2];
  #pragma unroll
  for (int mi = 0; mi < 2; ++mi)
    #pragma unroll
    for (int ni = 0; ni < 2; ++ni)
      acc[mi][ni] = f4v{0.f, 0.f, 0.f, 0.f};

  for (int k0 = 0; k0 < K; k0 += 64) {
    #pragma unroll
    for (int i = 0; i < 2; ++i) {
      int idx = t + i*256;
      int row = idx >> 3, ch = idx & 7;
      s8v av = *(const s8v*)(A + (size_t)(m0 + row)*K + k0 + ch*8);
      *(s8v*)(Ab + row*128 + ((ch*16) ^ ((row & 7) << 4))) = av;
      s8v bv = *(const s8v*)(B + (size_t)(n0 + row)*K + k0 + ch*8);
      *(s8v*)(Bb + row*128 + ((ch*16) ^ ((row & 7) << 4))) = bv;
    }
    __syncthreads();
    #pragma unroll
    for (int ks = 0; ks < 2; ++ks) {
      s8v af[2], bfr[2];
      #pragma unroll
      for (int mi = 0; mi < 2; ++mi) {
        int row = wm*32 + mi*16 + lr;
        int ch = ks*4 + lk;
        af[mi] = *(const s8v*)(Ab + row*128 + ((ch*16) ^ ((row & 7) << 4)));
      }
      #pragma unroll
      for (int ni = 0; ni < 2; ++ni) {
        int row = wn*32 + ni*16 + lr;
        int ch = ks*4 + lk;
        bfr[ni] = *(const s8v*)(Bb + row*128 + ((ch*16) ^ ((row & 7) << 4)));
      }
      #pragma unroll
      for (int mi = 0; mi < 2; ++mi)
        #pragma unroll
        for (int ni = 0; ni < 2; ++ni)
          acc[mi][ni] = __builtin_amdgcn_mfma_f32_16x16x32_bf16(af[mi], bfr[ni], acc[mi][ni], 0, 0, 0);
    }
    __syncthreads();
  }
  #pragma unroll
  for (int ni = 0; ni < 2; ++ni) {
    int col = n0 + wn*32 + ni*16 + lr;
    float bc = bias ? bias[col] : 0.f;
    #pragma unroll
    for (int mi = 0; mi < 2; ++mi) {
      int row0 = m0 + wm*32 + mi*16 + lk*4;
      float v[4];
      #pragma unroll
      for (int r = 0; r < 4; ++r) v[r] = acc[mi][ni][r] + bc;
      if (MODE == 0) {
        #pragma unroll
        for (int r = 0; r < 4; ++r) Cf[(size_t)(row0 + r)*N + col] = v[r];
      } else if (MODE == 2) {
        #pragma unroll
        for (int r = 0; r < 4; ++r) Cb[(size_t)(row0 + r)*N + col] = f2b(v[r]);
      } else { // MODE 3: qkv scatter
        if (col < 512) {
          int head = (col >> 6) & 3;
          int d = col & 63;
          u16* dst = ((col < 256) ? Qb : Kb) + (size_t)head*262144 + d;
          #pragma unroll
          for (int r = 0; r < 4; ++r) dst[(size_t)(row0 + r)*64] = f2b(v[r]);
        } else {
          int cc = col - 512;
          int head = cc >> 6;
          int d = cc & 63;
          int quad = row0 & 12;
          int qs = (quad == 4) ? 8 : ((quad == 8) ? 4 : quad);
          size_t nphys = (size_t)((row0 & ~15) | qs);
          u16 o4[4];
          #pragma unroll
          for (int r = 0; r < 4; ++r) o4[r] = f2b(v[r]);
          *(uint2*)(Vt + (size_t)head*262144 + (size_t)d*4096 + nphys) = *(uint2*)o4;
        }
      }
    }
  }
}

// ===================== bf16 MFMA GEMM 128x64 tile: MODE 1 relu+bf16, MODE 4 split-K f32 partials =====================
template<int MODE>
__global__ __launch_bounds__(256) void k_gemm2(
    const u16* __restrict__ A, const u16* __restrict__ B,
    const float* __restrict__ bias, float* __restrict__ Cf, u16* __restrict__ Cb,
    int M, int N, int K, int ksl)
{
  __shared__ u16 Al[128*64];
  __shared__ u16 Bl[64*64];
  char* Ab = (char*)Al;
  char* Bb = (char*)Bl;
  const int t = threadIdx.x;
  const int lane = t & 63;
  const int lr = lane & 15, lk = lane >> 4;
  const int wv = t >> 6;
  const int m0 = blockIdx.y * 128, n0 = blockIdx.x * 64;
  const int z = blockIdx.z;
  const int kbeg = z * ksl, kend = kbeg + ksl;

  f4v acc[2][4];
  #pragma unroll
  for (int mi = 0; mi < 2; ++mi)
    #pragma unroll
    for (int ni = 0; ni < 4; ++ni)
      acc[mi][ni] = f4v{0.f, 0.f, 0.f, 0.f};

  for (int k0 = kbeg; k0 < kend; k0 += 64) {
    #pragma unroll
    for (int i = 0; i < 4; ++i) {
      int idx = t + i*256;
      int row = idx >> 3, ch = idx & 7;
      s8v av = *(const s8v*)(A + (size_t)(m0 + row)*K + k0 + ch*8);
      *(s8v*)(Ab + row*128 + ((ch*16) ^ ((row & 7) << 4))) = av;
    }
    #pragma unroll
    for (int i = 0; i < 2; ++i) {
      int idx = t + i*256;
      int row = idx >> 3, ch = idx & 7;
      s8v bv = *(const s8v*)(B + (size_t)(n0 + row)*K + k0 + ch*8);
      *(s8v*)(Bb + row*128 + ((ch*16) ^ ((row & 7) << 4))) = bv;
    }
    __syncthreads();
    #pragma unroll
    for (int ks = 0; ks < 2; ++ks) {
      s8v af[2], bfr[4];
      #pragma unroll
      for (int mi = 0; mi < 2; ++mi) {
        int row = wv*32 + mi*16 + lr;
        int ch = ks*4 + lk;
        af[mi] = *(const s8v*)(Ab + row*128 + ((ch*16) ^ ((row & 7) << 4)));
      }
      #pragma unroll
      for (int ni = 0; ni < 4; ++ni) {
        int row = ni*16 + lr;
        int ch = ks*4 + lk;
        bfr[ni] = *(const s8v*)(Bb + row*128 + ((ch*16) ^ ((row & 7) << 4)));
      }
      #pragma unroll
      for (int mi = 0; mi < 2; ++mi)
        #pragma unroll
        for (int ni = 0; ni < 4; ++ni)
          acc[mi][ni] = __builtin_amdgcn_mfma_f32_16x16x32_bf16(af[mi], bfr[ni], acc[mi][ni], 0, 0, 0);
    }
    __syncthreads();
  }
  #pragma unroll
  for (int ni = 0; ni < 4; ++ni) {
    int col = n0 + ni*16 + lr;
    float bc = (MODE == 4) ? 0.f : bias[col];
    #pragma unroll
    for (int mi = 0; mi < 2; ++mi) {
      int row0 = m0 + wv*32 + mi*16 + lk*4;
      #pragma unroll
      for (int r = 0; r < 4; ++r) {
        float v = acc[mi][ni][r] + bc;
        if (MODE == 1) {
          v = fmaxf(v, 0.f);
          Cb[(size_t)(row0 + r)*N + col] = f2b(v);
        } else {
          (Cf + (size_t)z*M*N)[(size_t)(row0 + r)*N + col] = v;
        }
      }
    }
  }
}

// ===================== LayerNorm(a + res) =====================
template<bool WB>
__global__ __launch_bounds__(256) void k_ln(
    const float* __restrict__ a, const float* __restrict__ res,
    const float* __restrict__ g, const float* __restrict__ bb,
    float* __restrict__ out, u16* __restrict__ outb)
{
  int n = blockIdx.x, t = threadIdx.x;
  __shared__ float part[4];
  float v = a[(size_t)n*256 + t] + res[(size_t)n*256 + t];
  float s = v;
  #pragma unroll
  for (int off = 32; off; off >>= 1) s += __shfl_xor(s, off);
  if ((t & 63) == 0) part[t >> 6] = s;
  __syncthreads();
  float mean = (part[0] + part[1] + part[2] + part[3]) * (1.f/256.f);
  __syncthreads();
  float d = v - mean;
  float s2 = d * d;
  #pragma unroll
  for (int off = 32; off; off >>= 1) s2 += __shfl_xor(s2, off);
  if ((t & 63) == 0) part[t >> 6] = s2;
  __syncthreads();
  float var = (part[0] + part[1] + part[2] + part[3]) * (1.f/256.f);
  float rstd = rsqrtf(var + 1e-5f);
  float o = d * rstd * g[t] + bb[t];
  out[(size_t)n*256 + t] = o;
  if (WB) outb[(size_t)n*256 + t] = f2b(o);
}

// ===================== LayerNorm over 4 split-K partials + bias + res =====================
template<bool WB>
__global__ __launch_bounds__(256) void k_ln_sk(
    const float* __restrict__ Po, const float* __restrict__ bias,
    const float* __restrict__ res, const float* __restrict__ g,
    const float* __restrict__ bb, float* __restrict__ out, u16* __restrict__ outb)
{
  int n = blockIdx.x, t = threadIdx.x;
  __shared__ float part[4];
  const size_t MN = (size_t)NN * 256;
  size_t idx = (size_t)n*256 + t;
  float v = Po[idx] + Po[MN + idx] + Po[2*MN + idx] + Po[3*MN + idx]
          + bias[t] + res[idx];
  float s = v;
  #pragma unroll
  for (int off = 32; off; off >>= 1) s += __shfl_xor(s, off);
  if ((t & 63) == 0) part[t >> 6] = s;
  __syncthreads();
  float mean = (part[0] + part[1] + part[2] + part[3]) * (1.f/256.f);
  __syncthreads();
  float d = v - mean;
  float s2 = d * d;
  #pragma unroll
  for (int off = 32; off; off >>= 1) s2 += __shfl_xor(s2, off);
  if ((t & 63) == 0) part[t >> 6] = s2;
  __syncthreads();
  float var = (part[0] + part[1] + part[2] + part[3]) * (1.f/256.f);
  float rstd = rsqrtf(var + 1e-5f);
  float o = d * rstd * g[t] + bb[t];
  out[idx] = o;
  if (WB) outb[idx] = f2b(o);
}

// ===================== bf16 MFMA flash attention v4 =====================
// grid (128 strips, 4 heads, 2 key-halves); 8-wave blocks; wave s covers
// keys [z*2048 + s*256, +256). Round-5 tile body (fastest measured).
// In-LDS merge of the block's 8 waves, then global partial (m,l,O);
// k_attn_mrg combines the 2 key-halves.
__global__ __launch_bounds__(512) void k_attn2(
    const u16* __restrict__ Qb, const u16* __restrict__ Kb,
    const u16* __restrict__ Vt, float* __restrict__ op,
    float* __restrict__ mb, float* __restrict__ lb)
{
  const int strip = blockIdx.x;
  const int head  = blockIdx.y;
  const int z     = blockIdx.z;
  const int q0 = strip * 32;
  const int t = threadIdx.x;
  const int s = t >> 6;
  const int l = t & 63;
  const int lq = l & 31;
  const int lh = l >> 5;

  __shared__ float lds_O[4][32][68];
  __shared__ float lds_m[4][32];
  __shared__ float lds_l[4][32];

  const u16* Qh = Qb + (size_t)head * (4096*64);
  const u16* Kh = Kb + (size_t)head * (4096*64);
  const u16* Vh = Vt + (size_t)head * (64*4096);

  s8v qf[4];
#pragma unroll
  for (int dc = 0; dc < 4; ++dc)
    qf[dc] = *(const s8v*)(Qh + (size_t)(q0 + lq)*64 + dc*16 + lh*8);

  f16v accO[2];
#pragma unroll
  for (int dm = 0; dm < 2; ++dm)
#pragma unroll
    for (int i = 0; i < 16; ++i) accO[dm][i] = 0.f;

  float mrow = -INFINITY, lrow = 0.f;
  const float CE = 0.18033688011112042f;  // log2(e)/8

  const int kt0 = z * 2048 + s * 256;
  for (int kt = kt0; kt < kt0 + 256; kt += 64) {
    f16v st[2];
#pragma unroll
    for (int c = 0; c < 2; ++c)
#pragma unroll
      for (int i = 0; i < 16; ++i) st[c][i] = 0.f;
#pragma unroll
    for (int dc = 0; dc < 4; ++dc) {
      s8v kf0 = *(const s8v*)(Kh + (size_t)(kt + lq)*64 + dc*16 + lh*8);
      s8v kf1 = *(const s8v*)(Kh + (size_t)(kt + 32 + lq)*64 + dc*16 + lh*8);
      st[0] = __builtin_amdgcn_mfma_f32_32x32x16_bf16(kf0, qf[dc], st[0], 0, 0, 0);
      st[1] = __builtin_amdgcn_mfma_f32_32x32x16_bf16(kf1, qf[dc], st[1], 0, 0, 0);
    }
    float mx = st[0][0];
#pragma unroll
    for (int i = 1; i < 16; ++i) mx = fmaxf(mx, st[0][i]);
#pragma unroll
    for (int i = 0; i < 16; ++i) mx = fmaxf(mx, st[1][i]);
    mx = fmaxf(mx, __shfl_xor(mx, 32));
    float mn = fmaxf(mrow, mx);
    float sc = exp2f((mrow - mn) * CE);
    mrow = mn;
    float ps = 0.f;
#pragma unroll
    for (int c = 0; c < 2; ++c)
#pragma unroll
      for (int i = 0; i < 16; ++i) {
        float p = exp2f((st[c][i] - mn) * CE);
        st[c][i] = p;
        ps += p;
      }
    ps += __shfl_xor(ps, 32);
    lrow = lrow * sc + ps;
#pragma unroll
    for (int dm = 0; dm < 2; ++dm)
#pragma unroll
      for (int i = 0; i < 16; ++i) accO[dm][i] *= sc;

#pragma unroll
    for (int c = 0; c < 2; ++c) {
#pragma unroll
      for (int kc = 0; kc < 2; ++kc) {
        union { s8v v; unsigned int w[4]; } pb;
#pragma unroll
        for (int wd = 0; wd < 4; ++wd) {
          u16 lo16 = f2b(st[c][kc*8 + wd*2]);
          u16 hi16 = f2b(st[c][kc*8 + wd*2 + 1]);
          pb.w[wd] = (unsigned int)lo16 | ((unsigned int)hi16 << 16);
        }
#pragma unroll
        for (int dm = 0; dm < 2; ++dm) {
          s8v vf = *(const s8v*)(Vh + (size_t)(dm*32 + lq)*4096 + kt + c*32 + kc*16 + lh*8);
          accO[dm] = __builtin_amdgcn_mfma_f32_32x32x16_bf16(vf, pb.v, accO[dm], 0, 0, 0);
        }
      }
    }
  }

  // tree merge across the 8 split-waves
#pragma unroll
  for (int lev = 0; lev < 3; ++lev) {
    const int step = 1 << lev;
    __syncthreads();
    if ((s & (2*step - 1)) == step) {
      int slot = (s - step) >> (lev + 1);
      if (l < 32) { lds_m[slot][lq] = mrow; lds_l[slot][lq] = lrow; }
#pragma unroll
      for (int dm = 0; dm < 2; ++dm)
#pragma unroll
        for (int g = 0; g < 4; ++g) {
          f4v v;
#pragma unroll
          for (int rr = 0; rr < 4; ++rr) v[rr] = accO[dm][g*4 + rr];
          *(f4v*)&lds_O[slot][lq][dm*32 + lh*4 + g*8] = v;
        }
    }
    __syncthreads();
    if ((s & (2*step - 1)) == 0) {
      int slot = s >> (lev + 1);
      float mp = lds_m[slot][lq], lp = lds_l[slot][lq];
      float M = fmaxf(mrow, mp);
      float w0 = exp2f((mrow - M) * CE);
      float w1 = exp2f((mp - M) * CE);
      lrow = lrow * w0 + lp * w1;
      mrow = M;
#pragma unroll
      for (int dm = 0; dm < 2; ++dm)
#pragma unroll
        for (int g = 0; g < 4; ++g) {
          f4v vp = *(const f4v*)&lds_O[slot][lq][dm*32 + lh*4 + g*8];
#pragma unroll
          for (int rr = 0; rr < 4; ++rr)
            accO[dm][g*4 + rr] = accO[dm][g*4 + rr] * w0 + vp[rr] * w1;
        }
    }
  }

  if (s == 0) {
    int pb = (z*4 + head)*128 + strip;
    if (l < 32) { mb[pb*32 + lq] = mrow; lb[pb*32 + lq] = lrow; }
#pragma unroll
    for (int dm = 0; dm < 2; ++dm)
#pragma unroll
      for (int g = 0; g < 4; ++g) {
        f4v v;
#pragma unroll
        for (int rr = 0; rr < 4; ++rr) v[rr] = accO[dm][g*4 + rr];
        *(f4v*)&op[(size_t)pb*2048 + lq*64 + dm*32 + lh*4 + g*8] = v;
      }
  }
}

// merge the 2 key-half partials -> bf16 attn output
__global__ __launch_bounds__(256) void k_attn_mrg(
    const float* __restrict__ op, const float* __restrict__ mb,
    const float* __restrict__ lb, u16* __restrict__ attno_b)
{
  const int strip = blockIdx.x;
  const int head = blockIdx.y;
  const int t = threadIdx.x;
  const int q = t >> 3;
  const int d0 = (t & 7) * 8;
  const float CE = 0.18033688011112042f;
  int p0 = (0*4 + head)*128 + strip;
  int p1 = (1*4 + head)*128 + strip;
  float m0 = mb[p0*32 + q], m1 = mb[p1*32 + q];
  float M = fmaxf(m0, m1);
  float w0 = exp2f((m0 - M) * CE);
  float w1 = exp2f((m1 - M) * CE);
  float L = w0 * lb[p0*32 + q] + w1 * lb[p1*32 + q];
  float inv = 1.f / L;
  const float* o0 = op + (size_t)p0*2048 + q*64 + d0;
  const float* o1 = op + (size_t)p1*2048 + q*64 + d0;
  u16 o8[8];
#pragma unroll
  for (int i = 0; i < 8; ++i)
    o8[i] = f2b((w0 * o0[i] + w1 * o1[i]) * inv);
  *(uint4*)(attno_b + (size_t)(strip*32 + q)*256 + head*64 + d0) = *(uint4*)o8;
}

// ===================== host launcher =====================
extern "C" void kernel_launch(void* const* d_in, const int* in_sizes, int n_in,
                              void* d_out, int out_size, void* d_ws, size_t ws_size,
                              hipStream_t stream)
{
  const float* x       = (const float*)d_in[0];
  const int*   ei      = (const int*)d_in[1];
  const float* gat1_w  = (const float*)d_in[2];
  const float* gat1_as = (const float*)d_in[3];
  const float* gat1_ad = (const float*)d_in[4];
  const float* gat1_b  = (const float*)d_in[5];
  const float* inp_w   = (const float*)d_in[6];
  const float* inp_b   = (const float*)d_in[7];
  const float* outp_w  = (const float*)d_in[8];
  const float* outp_b  = (const float*)d_in[9];
  const float* lin1_w  = (const float*)d_in[10];
  const float* lin1_b  = (const float*)d_in[11];
  const float* lin2_w  = (const float*)d_in[12];
  const float* lin2_b  = (const float*)d_in[13];
  const float* ln1_g   = (const float*)d_in[14];
  const float* ln1_bb  = (const float*)d_in[15];
  const float* ln2_g   = (const float*)d_in[16];
  const float* ln2_bb  = (const float*)d_in[17];
  const float* gat2_w  = (const float*)d_in[18];
  const float* gat2_as = (const float*)d_in[19];
  const float* gat2_ad = (const float*)d_in[20];
  const float* gat2_b  = (const float*)d_in[21];
  float* out = (float*)d_out;
  (void)in_sizes; (void)n_in; (void)out_size; (void)ws_size;

  char* ws = (char*)d_ws;
  size_t off = 0;
  auto nxt = [&](size_t bytes) { size_t r = off; off += (bytes + 255) & ~(size_t)255; return r; };
  int* deg      = (int*)(ws + nxt((size_t)NN*4));
  int* cursor   = (int*)(ws + nxt((size_t)NN*4));
  int* rowptr   = (int*)(ws + nxt((size_t)(NN+1)*4));
  int* csr_src  = (int*)(ws + nxt((size_t)EE*4));
  float* al1s   = (float*)(ws + nxt((size_t)NN*4*4));
  float* al1d   = (float*)(ws + nxt((size_t)NN*4*4));
  float* hgat1  = (float*)(ws + nxt((size_t)NN*256*4));
  float* tmp256 = (float*)(ws + nxt((size_t)NN*256*4));
  float* hln1   = (float*)(ws + nxt((size_t)NN*256*4));
  float* hln2   = (float*)(ws + nxt((size_t)NN*256*4));
  float* Po     = (float*)(ws + nxt((size_t)4*NN*256*4));   // 16MB: attn partials, then lin2 split-K
  float* al2s   = (float*)(ws + nxt((size_t)NN*4));
  float* al2d   = (float*)(ws + nxt((size_t)NN*4));
  u16* x_b      = (u16*)(ws + nxt((size_t)NN*128*2));
  u16* feat1_b  = (u16*)(ws + nxt((size_t)NN*256*2));
  u16* feat2_b  = (u16*)(ws + nxt((size_t)NN*128*2));
  u16* hgat1_b  = (u16*)(ws + nxt((size_t)NN*256*2));
  u16* attno_b  = (u16*)(ws + nxt((size_t)NN*256*2));
  u16* hln1_b   = (u16*)(ws + nxt((size_t)NN*256*2));
  u16* hln2_b   = (u16*)(ws + nxt((size_t)NN*256*2));
  u16* ff1_b    = (u16*)(ws + nxt((size_t)NN*2048*2));
  u16* Qb       = (u16*)(ws + nxt((size_t)4*4096*64*2));
  u16* Kb       = (u16*)(ws + nxt((size_t)4*4096*64*2));
  u16* Vt       = (u16*)(ws + nxt((size_t)4*4096*64*2));
  u16* inp_w_b  = (u16*)(ws + nxt((size_t)768*256*2));
  u16* outp_w_b = (u16*)(ws + nxt((size_t)256*256*2));
  u16* lin1_w_b = (u16*)(ws + nxt((size_t)2048*256*2));
  u16* lin2_w_b = (u16*)(ws + nxt((size_t)256*2048*2));
  u16* gat1_w_b = (u16*)(ws + nxt((size_t)256*128*2));
  u16* gat2_w_b = (u16*)(ws + nxt((size_t)128*256*2));

  // attn partial arena inside Po (dead before lin2 uses Po)
  float* a_op = Po;                          // 1024 * 2048 f32 = 8.4MB
  float* a_mb = Po + (size_t)1024*2048;      // 32768 f32
  float* a_lb = a_mb + 32768;                // 32768 f32

  hipMemsetAsync(deg, 0, (size_t)NN*4, stream);
  hipMemsetAsync(cursor, 0, (size_t)NN*4, stream);
  k_count<<<(EE+255)/256, 256, 0, stream>>>(ei, deg);
  k_scan<<<1, 1024, 0, stream>>>(deg, rowptr);
  k_scatter<<<(EE+255)/256, 256, 0, stream>>>(ei, rowptr, cursor, csr_src);

  // all fp32->bf16 conversions in one launch (cumulative float4 ends)
  k_f2b_all<<<1856, 256, 0, stream>>>(
      inp_w,  inp_w_b,  49152,
      outp_w, outp_w_b, 65536,
      lin1_w, lin1_w_b, 196608,
      lin2_w, lin2_w_b, 327680,
      gat1_w, gat1_w_b, 335872,
      gat2_w, gat2_w_b, 344064,
      x,      x_b,      475136);

  // GAT layer 1: proj (MFMA) + logits + aggregate (+ELU)
  k_gemm_mfma<2><<<dim3(4, 64), 256, 0, stream>>>(x_b, gat1_w_b, nullptr, nullptr, feat1_b, nullptr, nullptr, nullptr, NN, 256, 128);
  k_alogits<4,64><<<NN, 256, 0, stream>>>(feat1_b, gat1_as, gat1_ad, al1s, al1d);
  k_gat_agg<4,64,true,true><<<NN, 256, 0, stream>>>(feat1_b, al1s, al1d, gat1_b, rowptr, csr_src, hgat1, hgat1_b);

  // Transformer encoder layer
  k_gemm_mfma<3><<<dim3(12, 64), 256, 0, stream>>>(hgat1_b, inp_w_b, inp_b, nullptr, nullptr, Qb, Kb, Vt, NN, 768, 256);
  k_attn2<<<dim3(128, 4, 2), 512, 0, stream>>>(Qb, Kb, Vt, a_op, a_mb, a_lb);
  k_attn_mrg<<<dim3(128, 4), 256, 0, stream>>>(a_op, a_mb, a_lb, attno_b);
  k_gemm_mfma<0><<<dim3(4, 64), 256, 0, stream>>>(attno_b, outp_w_b, outp_b, tmp256, nullptr, nullptr, nullptr, nullptr, NN, 256, 256);
  k_ln<true><<<NN, 256, 0, stream>>>(tmp256, hgat1, ln1_g, ln1_bb, hln1, hln1_b);
  k_gemm2<1><<<dim3(32, 32), 256, 0, stream>>>(hln1_b, lin1_w_b, lin1_b, nullptr, ff1_b, NN, 2048, 256, 256);
  k_gemm2<4><<<dim3(4, 32, 4), 256, 0, stream>>>(ff1_b, lin2_w_b, nullptr, Po, nullptr, NN, 256, 2048, 512);
  k_ln_sk<true><<<NN, 256, 0, stream>>>(Po, lin2_b, hln1, ln2_g, ln2_bb, hln2, hln2_b);

  // GAT layer 2 -> final output
  k_gemm_mfma<2><<<dim3(2, 64), 256, 0, stream>>>(hln2_b, gat2_w_b, nullptr, nullptr, feat2_b, nullptr, nullptr, nullptr, NN, 128, 256);
  k_alogits<1,128><<<NN, 128, 0, stream>>>(feat2_b, gat2_as, gat2_ad, al2s, al2d);
  k_gat_agg<1,128,false,false><<<NN, 128, 0, stream>>>(feat2_b, al2s, al2d, gat2_b, rowptr, csr_src, out, nullptr);
}

// Round 9
// 275.015 us; speedup vs baseline: 3.5410x; 1.0911x over previous
//
#include <hip/hip_runtime.h>
#include <hip/hip_bf16.h>
#include <math.h>

#define NN 4096
#define NE 131072
#define EE (NE + NN)

typedef unsigned short u16;
typedef short s8v __attribute__((ext_vector_type(8)));
typedef float f4v __attribute__((ext_vector_type(4)));
typedef float f16v __attribute__((ext_vector_type(16)));

__device__ inline u16 f2b(float f) {
  __hip_bfloat16 h = __float2bfloat16(f);
  return __builtin_bit_cast(u16, h);
}
__device__ inline float b2f(u16 v) {
  unsigned int u = ((unsigned int)v) << 16;
  return __builtin_bit_cast(float, u);
}

// ===================== CSR build =====================
__global__ void k_count(const int* __restrict__ ei, int* __restrict__ deg) {
  int e = blockIdx.x * 256 + threadIdx.x;
  if (e >= EE) return;
  int dst = (e < NE) ? ei[NE + e] : (e - NE);
  atomicAdd(&deg[dst], 1);
}

__global__ __launch_bounds__(1024) void k_scan(const int* __restrict__ deg, int* __restrict__ rowptr) {
  __shared__ int lds[1024];
  int t = threadIdx.x;
  int v0 = deg[t*4+0], v1 = deg[t*4+1], v2 = deg[t*4+2], v3 = deg[t*4+3];
  int s1 = v0+v1, s2 = s1+v2, s3 = s2+v3;
  lds[t] = s3;
  __syncthreads();
  for (int off = 1; off < 1024; off <<= 1) {
    int add = (t >= off) ? lds[t-off] : 0;
    __syncthreads();
    lds[t] += add;
    __syncthreads();
  }
  int base = lds[t] - s3;
  rowptr[t*4+1] = base + v0;
  rowptr[t*4+2] = base + s1;
  rowptr[t*4+3] = base + s2;
  rowptr[t*4+4] = base + s3;
  if (t == 0) rowptr[0] = 0;
}

__global__ void k_scatter(const int* __restrict__ ei, const int* __restrict__ rowptr,
                          int* __restrict__ cursor, int* __restrict__ csr_src) {
  int e = blockIdx.x * 256 + threadIdx.x;
  if (e >= EE) return;
  int src, dst;
  if (e < NE) { src = ei[e]; dst = ei[NE + e]; }
  else { src = e - NE; dst = src; }
  int pos = rowptr[dst] + atomicAdd(&cursor[dst], 1);
  csr_src[pos] = src;
}

// ===================== batched fp32 -> bf16 conversion =====================
__global__ __launch_bounds__(256) void k_f2b_all(
    const float* a0, u16* b0, int e0, const float* a1, u16* b1, int e1,
    const float* a2, u16* b2, int e2, const float* a3, u16* b3, int e3,
    const float* a4, u16* b4, int e4, const float* a5, u16* b5, int e5,
    const float* a6, u16* b6, int e6)
{
  int i = blockIdx.x * 256 + threadIdx.x;
  const float* s; u16* d; int base;
  if      (i < e0) { s=a0; d=b0; base=0;  }
  else if (i < e1) { s=a1; d=b1; base=e0; }
  else if (i < e2) { s=a2; d=b2; base=e1; }
  else if (i < e3) { s=a3; d=b3; base=e2; }
  else if (i < e4) { s=a4; d=b4; base=e3; }
  else if (i < e5) { s=a5; d=b5; base=e4; }
  else if (i < e6) { s=a6; d=b6; base=e5; }
  else return;
  int j = i - base;
  float4 v = ((const float4*)s)[j];
  u16 r[4] = {f2b(v.x), f2b(v.y), f2b(v.z), f2b(v.w)};
  *(uint2*)(d + (size_t)j*4) = *(uint2*)r;
}

// ===================== a-logits via wave shuffles =====================
template<int HEADS, int C>
__global__ __launch_bounds__(256) void k_alogits(
    const u16* __restrict__ featb, const float* __restrict__ asrc,
    const float* __restrict__ adst, float* __restrict__ als, float* __restrict__ ald)
{
  constexpr int F = HEADS * C;
  int n = blockIdx.x, t = threadIdx.x;
  float f = b2f(featb[(size_t)n*F + t]);
  float ps = f * asrc[t];
  float pd = f * adst[t];
  #pragma unroll
  for (int off = 32; off; off >>= 1) {
    ps += __shfl_xor(ps, off);
    pd += __shfl_xor(pd, off);
  }
  if constexpr (C == 64) {
    if ((t & 63) == 0) {
      int hh = t >> 6;
      als[(size_t)n*HEADS + hh] = ps;
      ald[(size_t)n*HEADS + hh] = pd;
    }
  } else {
    __shared__ float sh[2][2];
    if ((t & 63) == 0) { sh[t>>6][0] = ps; sh[t>>6][1] = pd; }
    __syncthreads();
    if (t == 0) {
      als[n] = sh[0][0] + sh[1][0];
      ald[n] = sh[0][1] + sh[1][1];
    }
  }
}

// ===================== GAT aggregation v2: chunked alpha in LDS =====================
template<int HEADS, int C, bool DO_ELU, bool WB>
__global__ __launch_bounds__(256) void k_gat_agg(
    const u16* __restrict__ featb, const float* __restrict__ als,
    const float* __restrict__ ald, const float* __restrict__ bias,
    const int* __restrict__ rowptr, const int* __restrict__ csr_src,
    float* __restrict__ out, u16* __restrict__ outb)
{
  constexpr int F = HEADS * C;
  int n = blockIdx.x, t = threadIdx.x;
  __shared__ float m_sh[HEADS], s_sh[HEADS];
  __shared__ float alpha_sh[HEADS][64];
  __shared__ int src_sh[64];
  int start = rowptr[n];
  int deg = rowptr[n+1] - start;
  int lane = t & 63, wv = t >> 6;
  for (int hh = wv; hh < HEADS; hh += F/64) {
    float adl = ald[(size_t)n*HEADS + hh];
    float mx = -INFINITY;
    for (int i = lane; i < deg; i += 64) {
      int s = csr_src[start + i];
      float lg = als[(size_t)s*HEADS + hh] + adl;
      lg = (lg > 0.f) ? lg : 0.2f * lg;
      mx = fmaxf(mx, lg);
    }
    #pragma unroll
    for (int off = 32; off; off >>= 1) mx = fmaxf(mx, __shfl_xor(mx, off));
    float sm = 0.f;
    for (int i = lane; i < deg; i += 64) {
      int s = csr_src[start + i];
      float lg = als[(size_t)s*HEADS + hh] + adl;
      lg = (lg > 0.f) ? lg : 0.2f * lg;
      sm += expf(lg - mx);
    }
    #pragma unroll
    for (int off = 32; off; off >>= 1) sm += __shfl_xor(sm, off);
    if (lane == 0) { m_sh[hh] = mx; s_sh[hh] = sm; }
  }
  __syncthreads();
  int hh = t / C;
  int hh2 = t >> 6;
  int ia = t & 63;
  float acc0 = 0.f, acc1 = 0.f;
  for (int c0 = 0; c0 < deg; c0 += 64) {
    int cn = min(64, deg - c0);
    if (hh2 < HEADS && ia < cn) {
      int s = csr_src[start + c0 + ia];
      if (hh2 == 0) src_sh[ia] = s;
      float lg = als[(size_t)s*HEADS + hh2] + ald[(size_t)n*HEADS + hh2];
      lg = (lg > 0.f) ? lg : 0.2f * lg;
      alpha_sh[hh2][ia] = expf(lg - m_sh[hh2]);
    }
    __syncthreads();
    int i = 0;
    for (; i + 1 < cn; i += 2) {
      int s0 = src_sh[i], s1 = src_sh[i+1];
      float a0 = alpha_sh[hh][i], a1 = alpha_sh[hh][i+1];
      acc0 += a0 * b2f(featb[(size_t)s0*F + t]);
      acc1 += a1 * b2f(featb[(size_t)s1*F + t]);
    }
    if (i < cn)
      acc0 += alpha_sh[hh][i] * b2f(featb[(size_t)src_sh[i]*F + t]);
    __syncthreads();
  }
  float o = (acc0 + acc1) / (s_sh[hh] + 1e-16f) + bias[t];
  if (DO_ELU) o = (o > 0.f) ? o : (expf(o) - 1.f);
  out[(size_t)n*F + t] = o;
  if (WB) outb[(size_t)n*F + t] = f2b(o);
}

// ===================== bf16 MFMA GEMM 64x64: MODE 0 f32, 2 bf16, 3 qkv scatter =====================
template<int MODE>
__global__ __launch_bounds__(256) void k_gemm_mfma(
    const u16* __restrict__ A, const u16* __restrict__ B,
    const float* __restrict__ bias, float* __restrict__ Cf, u16* __restrict__ Cb,
    u16* __restrict__ Qb, u16* __restrict__ Kb, u16* __restrict__ Vt,
    int M, int N, int K)
{
  __shared__ u16 Al[64*64];
  __shared__ u16 Bl[64*64];
  char* Ab = (char*)Al;
  char* Bb = (char*)Bl;
  const int t = threadIdx.x;
  const int lane = t & 63;
  const int lr = lane & 15, lk = lane >> 4;
  const int wid = t >> 6;
  const int wm = wid & 1, wn = wid >> 1;
  const int m0 = blockIdx.y * 64, n0 = blockIdx.x * 64;

  f4v acc[2][2];
  #pragma unroll
  for (int mi = 0; mi < 2; ++mi)
    #pragma unroll
    for (int ni = 0; ni < 2; ++ni)
      acc[mi][ni] = f4v{0.f, 0.f, 0.f, 0.f};

  for (int k0 = 0; k0 < K; k0 += 64) {
    #pragma unroll
    for (int i = 0; i < 2; ++i) {
      int idx = t + i*256;
      int row = idx >> 3, ch = idx & 7;
      s8v av = *(const s8v*)(A + (size_t)(m0 + row)*K + k0 + ch*8);
      *(s8v*)(Ab + row*128 + ((ch*16) ^ ((row & 7) << 4))) = av;
      s8v bv = *(const s8v*)(B + (size_t)(n0 + row)*K + k0 + ch*8);
      *(s8v*)(Bb + row*128 + ((ch*16) ^ ((row & 7) << 4))) = bv;
    }
    __syncthreads();
    #pragma unroll
    for (int ks = 0; ks < 2; ++ks) {
      s8v af[2], bfr[2];
      #pragma unroll
      for (int mi = 0; mi < 2; ++mi) {
        int row = wm*32 + mi*16 + lr;
        int ch = ks*4 + lk;
        af[mi] = *(const s8v*)(Ab + row*128 + ((ch*16) ^ ((row & 7) << 4)));
      }
      #pragma unroll
      for (int ni = 0; ni < 2; ++ni) {
        int row = wn*32 + ni*16 + lr;
        int ch = ks*4 + lk;
        bfr[ni] = *(const s8v*)(Bb + row*128 + ((ch*16) ^ ((row & 7) << 4)));
      }
      #pragma unroll
      for (int mi = 0; mi < 2; ++mi)
        #pragma unroll
        for (int ni = 0; ni < 2; ++ni)
          acc[mi][ni] = __builtin_amdgcn_mfma_f32_16x16x32_bf16(af[mi], bfr[ni], acc[mi][ni], 0, 0, 0);
    }
    __syncthreads();
  }
  #pragma unroll
  for (int ni = 0; ni < 2; ++ni) {
    int col = n0 + wn*32 + ni*16 + lr;
    float bc = bias ? bias[col] : 0.f;
    #pragma unroll
    for (int mi = 0; mi < 2; ++mi) {
      int row0 = m0 + wm*32 + mi*16 + lk*4;
      float v[4];
      #pragma unroll
      for (int r = 0; r < 4; ++r) v[r] = acc[mi][ni][r] + bc;
      if (MODE == 0) {
        #pragma unroll
        for (int r = 0; r < 4; ++r) Cf[(size_t)(row0 + r)*N + col] = v[r];
      } else if (MODE == 2) {
        #pragma unroll
        for (int r = 0; r < 4; ++r) Cb[(size_t)(row0 + r)*N + col] = f2b(v[r]);
      } else { // MODE 3: qkv scatter
        if (col < 512) {
          int head = (col >> 6) & 3;
          int d = col & 63;
          u16* dst = ((col < 256) ? Qb : Kb) + (size_t)head*262144 + d;
          #pragma unroll
          for (int r = 0; r < 4; ++r) dst[(size_t)(row0 + r)*64] = f2b(v[r]);
        } else {
          int cc = col - 512;
          int head = cc >> 6;
          int d = cc & 63;
          int quad = row0 & 12;
          int qs = (quad == 4) ? 8 : ((quad == 8) ? 4 : quad);
          size_t nphys = (size_t)((row0 & ~15) | qs);
          u16 o4[4];
          #pragma unroll
          for (int r = 0; r < 4; ++r) o4[r] = f2b(v[r]);
          *(uint2*)(Vt + (size_t)head*262144 + (size_t)d*4096 + nphys) = *(uint2*)o4;
        }
      }
    }
  }
}

// ===================== bf16 MFMA GEMM 128x64 tile: MODE 1 relu+bf16, MODE 4 split-K f32 partials =====================
template<int MODE>
__global__ __launch_bounds__(256) void k_gemm2(
    const u16* __restrict__ A, const u16* __restrict__ B,
    const float* __restrict__ bias, float* __restrict__ Cf, u16* __restrict__ Cb,
    int M, int N, int K, int ksl)
{
  __shared__ u16 Al[128*64];
  __shared__ u16 Bl[64*64];
  char* Ab = (char*)Al;
  char* Bb = (char*)Bl;
  const int t = threadIdx.x;
  const int lane = t & 63;
  const int lr = lane & 15, lk = lane >> 4;
  const int wv = t >> 6;
  const int m0 = blockIdx.y * 128, n0 = blockIdx.x * 64;
  const int z = blockIdx.z;
  const int kbeg = z * ksl, kend = kbeg + ksl;

  f4v acc[2][4];
  #pragma unroll
  for (int mi = 0; mi < 2; ++mi)
    #pragma unroll
    for (int ni = 0; ni < 4; ++ni)
      acc[mi][ni] = f4v{0.f, 0.f, 0.f, 0.f};

  for (int k0 = kbeg; k0 < kend; k0 += 64) {
    #pragma unroll
    for (int i = 0; i < 4; ++i) {
      int idx = t + i*256;
      int row = idx >> 3, ch = idx & 7;
      s8v av = *(const s8v*)(A + (size_t)(m0 + row)*K + k0 + ch*8);
      *(s8v*)(Ab + row*128 + ((ch*16) ^ ((row & 7) << 4))) = av;
    }
    #pragma unroll
    for (int i = 0; i < 2; ++i) {
      int idx = t + i*256;
      int row = idx >> 3, ch = idx & 7;
      s8v bv = *(const s8v*)(B + (size_t)(n0 + row)*K + k0 + ch*8);
      *(s8v*)(Bb + row*128 + ((ch*16) ^ ((row & 7) << 4))) = bv;
    }
    __syncthreads();
    #pragma unroll
    for (int ks = 0; ks < 2; ++ks) {
      s8v af[2], bfr[4];
      #pragma unroll
      for (int mi = 0; mi < 2; ++mi) {
        int row = wv*32 + mi*16 + lr;
        int ch = ks*4 + lk;
        af[mi] = *(const s8v*)(Ab + row*128 + ((ch*16) ^ ((row & 7) << 4)));
      }
      #pragma unroll
      for (int ni = 0; ni < 4; ++ni) {
        int row = ni*16 + lr;
        int ch = ks*4 + lk;
        bfr[ni] = *(const s8v*)(Bb + row*128 + ((ch*16) ^ ((row & 7) << 4)));
      }
      #pragma unroll
      for (int mi = 0; mi < 2; ++mi)
        #pragma unroll
        for (int ni = 0; ni < 4; ++ni)
          acc[mi][ni] = __builtin_amdgcn_mfma_f32_16x16x32_bf16(af[mi], bfr[ni], acc[mi][ni], 0, 0, 0);
    }
    __syncthreads();
  }
  #pragma unroll
  for (int ni = 0; ni < 4; ++ni) {
    int col = n0 + ni*16 + lr;
    float bc = (MODE == 4) ? 0.f : bias[col];
    #pragma unroll
    for (int mi = 0; mi < 2; ++mi) {
      int row0 = m0 + wv*32 + mi*16 + lk*4;
      #pragma unroll
      for (int r = 0; r < 4; ++r) {
        float v = acc[mi][ni][r] + bc;
        if (MODE == 1) {
          v = fmaxf(v, 0.f);
          Cb[(size_t)(row0 + r)*N + col] = f2b(v);
        } else {
          (Cf + (size_t)z*M*N)[(size_t)(row0 + r)*N + col] = v;
        }
      }
    }
  }
}

// ===================== LayerNorm(a + res) =====================
template<bool WB>
__global__ __launch_bounds__(256) void k_ln(
    const float* __restrict__ a, const float* __restrict__ res,
    const float* __restrict__ g, const float* __restrict__ bb,
    float* __restrict__ out, u16* __restrict__ outb)
{
  int n = blockIdx.x, t = threadIdx.x;
  __shared__ float part[4];
  float v = a[(size_t)n*256 + t] + res[(size_t)n*256 + t];
  float s = v;
  #pragma unroll
  for (int off = 32; off; off >>= 1) s += __shfl_xor(s, off);
  if ((t & 63) == 0) part[t >> 6] = s;
  __syncthreads();
  float mean = (part[0] + part[1] + part[2] + part[3]) * (1.f/256.f);
  __syncthreads();
  float d = v - mean;
  float s2 = d * d;
  #pragma unroll
  for (int off = 32; off; off >>= 1) s2 += __shfl_xor(s2, off);
  if ((t & 63) == 0) part[t >> 6] = s2;
  __syncthreads();
  float var = (part[0] + part[1] + part[2] + part[3]) * (1.f/256.f);
  float rstd = rsqrtf(var + 1e-5f);
  float o = d * rstd * g[t] + bb[t];
  out[(size_t)n*256 + t] = o;
  if (WB) outb[(size_t)n*256 + t] = f2b(o);
}

// ===================== LayerNorm over 4 split-K partials + bias + res =====================
template<bool WB>
__global__ __launch_bounds__(256) void k_ln_sk(
    const float* __restrict__ Po, const float* __restrict__ bias,
    const float* __restrict__ res, const float* __restrict__ g,
    const float* __restrict__ bb, float* __restrict__ out, u16* __restrict__ outb)
{
  int n = blockIdx.x, t = threadIdx.x;
  __shared__ float part[4];
  const size_t MN = (size_t)NN * 256;
  size_t idx = (size_t)n*256 + t;
  float v = Po[idx] + Po[MN + idx] + Po[2*MN + idx] + Po[3*MN + idx]
          + bias[t] + res[idx];
  float s = v;
  #pragma unroll
  for (int off = 32; off; off >>= 1) s += __shfl_xor(s, off);
  if ((t & 63) == 0) part[t >> 6] = s;
  __syncthreads();
  float mean = (part[0] + part[1] + part[2] + part[3]) * (1.f/256.f);
  __syncthreads();
  float d = v - mean;
  float s2 = d * d;
  #pragma unroll
  for (int off = 32; off; off >>= 1) s2 += __shfl_xor(s2, off);
  if ((t & 63) == 0) part[t >> 6] = s2;
  __syncthreads();
  float var = (part[0] + part[1] + part[2] + part[3]) * (1.f/256.f);
  float rstd = rsqrtf(var + 1e-5f);
  float o = d * rstd * g[t] + bb[t];
  out[idx] = o;
  if (WB) outb[idx] = f2b(o);
}

// ===================== bf16 MFMA flash attention v5: LDS-staged K/V tiles =====================
// grid (32 strips, 4 heads, 8 z); 4-wave blocks; block covers 128 queries,
// keys [z*512, +512) in 8 tiles of 64. K/V tile staged in LDS once per block
// (shared by 4 waves), XOR-swizzled. T14: next tile's global loads issued
// before current compute, ds_write after barrier (single buffer).
__global__ __launch_bounds__(256) void k_attn3(
    const u16* __restrict__ Qb, const u16* __restrict__ Kb,
    const u16* __restrict__ Vt, float* __restrict__ op0, float* __restrict__ op1,
    float* __restrict__ mball, float* __restrict__ lball)
{
  const int strip = blockIdx.x;
  const int head  = blockIdx.y;
  const int z     = blockIdx.z;
  const int t = threadIdx.x;
  const int wv = t >> 6;
  const int l = t & 63;
  const int lq = l & 31;
  const int lh = l >> 5;
  const int q0 = strip*128 + wv*32;

  __shared__ u16 Kl[64*64];
  __shared__ u16 Vl[64*64];
  char* Kc = (char*)Kl;
  char* Vc = (char*)Vl;

  const u16* Qh = Qb + (size_t)head * (4096*64);
  const u16* Kh = Kb + (size_t)head * (4096*64);
  const u16* Vh = Vt + (size_t)head * (64*4096);

  s8v qf[4];
#pragma unroll
  for (int dc = 0; dc < 4; ++dc)
    qf[dc] = *(const s8v*)(Qh + (size_t)(q0 + lq)*64 + dc*16 + lh*8);

  // staging: thread t owns 16B chunks {t, t+256} of both K and V tiles
  const int c0 = t, c1 = t + 256;
  const int kr0 = c0 >> 3, kc0 = c0 & 7;
  const int kr1 = c1 >> 3, kc1 = c1 & 7;
  const int kt0 = z * 512;
  const u16* gK0 = Kh + (size_t)(kt0 + kr0)*64 + kc0*8;
  const u16* gK1 = Kh + (size_t)(kt0 + kr1)*64 + kc1*8;
  const u16* gV0 = Vh + (size_t)kr0*4096 + kt0 + kc0*8;
  const u16* gV1 = Vh + (size_t)kr1*4096 + kt0 + kc1*8;
  const int lo0 = kr0*128 + ((kc0*16) ^ ((kr0 & 7) << 4));
  const int lo1 = kr1*128 + ((kc1*16) ^ ((kr1 & 7) << 4));

  // stage tile 0
  {
    s8v a = *(const s8v*)gK0, b = *(const s8v*)gK1;
    s8v c = *(const s8v*)gV0, d = *(const s8v*)gV1;
    *(s8v*)(Kc + lo0) = a; *(s8v*)(Kc + lo1) = b;
    *(s8v*)(Vc + lo0) = c; *(s8v*)(Vc + lo1) = d;
  }
  __syncthreads();

  // constant LDS read offsets (tile-independent)
  int roK[2][4];
#pragma unroll
  for (int c = 0; c < 2; ++c) {
    int row = c*32 + lq;
#pragma unroll
    for (int dc = 0; dc < 4; ++dc)
      roK[c][dc] = row*128 + ((dc*32 + lh*16) ^ ((row & 7) << 4));
  }
  int roV[2][2][2];
#pragma unroll
  for (int dm = 0; dm < 2; ++dm) {
    int row = dm*32 + lq;
#pragma unroll
    for (int c = 0; c < 2; ++c)
#pragma unroll
      for (int kc = 0; kc < 2; ++kc)
        roV[c][kc][dm] = row*128 + ((c*64 + kc*32 + lh*16) ^ ((row & 7) << 4));
  }

  f16v accO[2];
#pragma unroll
  for (int dm = 0; dm < 2; ++dm)
#pragma unroll
    for (int i = 0; i < 16; ++i) accO[dm][i] = 0.f;
  float mrow = -INFINITY, lrow = 0.f;
  const float CE = 0.18033688011112042f;  // log2(e)/8

  s8v rK0, rK1, rV0, rV1;
  for (int tt = 0; tt < 8; ++tt) {
    if (tt < 7) {            // T14 issue-early: next tile's global loads
      gK0 += 64*64; gK1 += 64*64; gV0 += 64; gV1 += 64;
      rK0 = *(const s8v*)gK0; rK1 = *(const s8v*)gK1;
      rV0 = *(const s8v*)gV0; rV1 = *(const s8v*)gV1;
    }
    // QK^T from LDS
    s8v kf[2][4];
#pragma unroll
    for (int c = 0; c < 2; ++c)
#pragma unroll
      for (int dc = 0; dc < 4; ++dc)
        kf[c][dc] = *(const s8v*)(Kc + roK[c][dc]);
    f16v st[2];
#pragma unroll
    for (int c = 0; c < 2; ++c)
#pragma unroll
      for (int i = 0; i < 16; ++i) st[c][i] = 0.f;
#pragma unroll
    for (int dc = 0; dc < 4; ++dc) {
      st[0] = __builtin_amdgcn_mfma_f32_32x32x16_bf16(kf[0][dc], qf[dc], st[0], 0, 0, 0);
      st[1] = __builtin_amdgcn_mfma_f32_32x32x16_bf16(kf[1][dc], qf[dc], st[1], 0, 0, 0);
    }
    // softmax (R5 body)
    float mx = st[0][0];
#pragma unroll
    for (int i = 1; i < 16; ++i) mx = fmaxf(mx, st[0][i]);
#pragma unroll
    for (int i = 0; i < 16; ++i) mx = fmaxf(mx, st[1][i]);
    mx = fmaxf(mx, __shfl_xor(mx, 32));
    float mn = fmaxf(mrow, mx);
    float sc = exp2f((mrow - mn) * CE);
    mrow = mn;
    float ps = 0.f;
#pragma unroll
    for (int c = 0; c < 2; ++c)
#pragma unroll
      for (int i = 0; i < 16; ++i) {
        float p = exp2f((st[c][i] - mn) * CE);
        st[c][i] = p;
        ps += p;
      }
    ps += __shfl_xor(ps, 32);
    lrow = lrow * sc + ps;
#pragma unroll
    for (int dm = 0; dm < 2; ++dm)
#pragma unroll
      for (int i = 0; i < 16; ++i) accO[dm][i] *= sc;

    // PV from LDS (V tile pre-permuted in global -> same addressing as before)
#pragma unroll
    for (int c = 0; c < 2; ++c) {
#pragma unroll
      for (int kc = 0; kc < 2; ++kc) {
        s8v vf0 = *(const s8v*)(Vc + roV[c][kc][0]);
        s8v vf1 = *(const s8v*)(Vc + roV[c][kc][1]);
        union { s8v v; unsigned int w[4]; } pb;
#pragma unroll
        for (int wd = 0; wd < 4; ++wd) {
          u16 lo16 = f2b(st[c][kc*8 + wd*2]);
          u16 hi16 = f2b(st[c][kc*8 + wd*2 + 1]);
          pb.w[wd] = (unsigned int)lo16 | ((unsigned int)hi16 << 16);
        }
        accO[0] = __builtin_amdgcn_mfma_f32_32x32x16_bf16(vf0, pb.v, accO[0], 0, 0, 0);
        accO[1] = __builtin_amdgcn_mfma_f32_32x32x16_bf16(vf1, pb.v, accO[1], 0, 0, 0);
      }
    }
    __syncthreads();           // all waves done reading this tile
    if (tt < 7) {              // T14 write-late
      *(s8v*)(Kc + lo0) = rK0; *(s8v*)(Kc + lo1) = rK1;
      *(s8v*)(Vc + lo0) = rV0; *(s8v*)(Vc + lo1) = rV1;
      __syncthreads();
    }
  }

  // write partial (m, l, O) for this z-split
  int q = q0 + lq;
  int pidx = (z*4 + head)*4096 + q;
  if (lh == 0) { mball[pidx] = mrow; lball[pidx] = lrow; }
  float* op = (z < 4) ? op0 : op1;
  size_t obase = ((size_t)((z & 3)*4 + head)*4096 + q)*64;
#pragma unroll
  for (int dm = 0; dm < 2; ++dm)
#pragma unroll
    for (int g = 0; g < 4; ++g) {
      f4v v;
#pragma unroll
      for (int rr = 0; rr < 4; ++rr) v[rr] = accO[dm][g*4 + rr];
      *(f4v*)&op[obase + dm*32 + lh*4 + g*8] = v;
    }
}

// merge the 8 z-partials -> bf16 attn output
__global__ __launch_bounds__(256) void k_attn_mrg8(
    const float* __restrict__ op0, const float* __restrict__ op1,
    const float* __restrict__ mball, const float* __restrict__ lball,
    u16* __restrict__ attno_b)
{
  const int bq = blockIdx.x;       // 0..127
  const int head = blockIdx.y;
  const int t = threadIdx.x;
  const int q = bq*32 + (t >> 3);
  const int d0 = (t & 7) * 8;
  const float CE = 0.18033688011112042f;
  float m[8], M = -INFINITY;
#pragma unroll
  for (int z = 0; z < 8; ++z) {
    m[z] = mball[(z*4 + head)*4096 + q];
    M = fmaxf(M, m[z]);
  }
  float w[8], L = 0.f;
#pragma unroll
  for (int z = 0; z < 8; ++z) {
    w[z] = exp2f((m[z] - M) * CE);
    L += w[z] * lball[(z*4 + head)*4096 + q];
  }
  float inv = 1.f / L;
  float o[8] = {0,0,0,0,0,0,0,0};
#pragma unroll
  for (int z = 0; z < 8; ++z) {
    const float* op = (z < 4) ? op0 : op1;
    size_t base = ((size_t)((z & 3)*4 + head)*4096 + q)*64 + d0;
    f4v a = *(const f4v*)&op[base];
    f4v b = *(const f4v*)&op[base + 4];
#pragma unroll
    for (int i = 0; i < 4; ++i) { o[i] += w[z]*a[i]; o[4+i] += w[z]*b[i]; }
  }
  u16 o8[8];
#pragma unroll
  for (int i = 0; i < 8; ++i) o8[i] = f2b(o[i] * inv);
  *(uint4*)(attno_b + (size_t)q*256 + head*64 + d0) = *(uint4*)o8;
}

// ===================== host launcher =====================
extern "C" void kernel_launch(void* const* d_in, const int* in_sizes, int n_in,
                              void* d_out, int out_size, void* d_ws, size_t ws_size,
                              hipStream_t stream)
{
  const float* x       = (const float*)d_in[0];
  const int*   ei      = (const int*)d_in[1];
  const float* gat1_w  = (const float*)d_in[2];
  const float* gat1_as = (const float*)d_in[3];
  const float* gat1_ad = (const float*)d_in[4];
  const float* gat1_b  = (const float*)d_in[5];
  const float* inp_w   = (const float*)d_in[6];
  const float* inp_b   = (const float*)d_in[7];
  const float* outp_w  = (const float*)d_in[8];
  const float* outp_b  = (const float*)d_in[9];
  const float* lin1_w  = (const float*)d_in[10];
  const float* lin1_b  = (const float*)d_in[11];
  const float* lin2_w  = (const float*)d_in[12];
  const float* lin2_b  = (const float*)d_in[13];
  const float* ln1_g   = (const float*)d_in[14];
  const float* ln1_bb  = (const float*)d_in[15];
  const float* ln2_g   = (const float*)d_in[16];
  const float* ln2_bb  = (const float*)d_in[17];
  const float* gat2_w  = (const float*)d_in[18];
  const float* gat2_as = (const float*)d_in[19];
  const float* gat2_ad = (const float*)d_in[20];
  const float* gat2_b  = (const float*)d_in[21];
  float* out = (float*)d_out;
  (void)in_sizes; (void)n_in; (void)out_size; (void)ws_size;

  char* ws = (char*)d_ws;
  size_t off = 0;
  auto nxt = [&](size_t bytes) { size_t r = off; off += (bytes + 255) & ~(size_t)255; return r; };
  int* deg      = (int*)(ws + nxt((size_t)NN*4));
  int* cursor   = (int*)(ws + nxt((size_t)NN*4));
  int* rowptr   = (int*)(ws + nxt((size_t)(NN+1)*4));
  int* csr_src  = (int*)(ws + nxt((size_t)EE*4));
  float* al1s   = (float*)(ws + nxt((size_t)NN*4*4));
  float* al1d   = (float*)(ws + nxt((size_t)NN*4*4));
  float* hgat1  = (float*)(ws + nxt((size_t)NN*256*4));
  float* tmp256 = (float*)(ws + nxt((size_t)NN*256*4));
  float* hln1   = (float*)(ws + nxt((size_t)NN*256*4));
  float* hln2   = (float*)(ws + nxt((size_t)NN*256*4));
  float* Po     = (float*)(ws + nxt((size_t)4*NN*256*4));   // 16MB: attn op0 (z<4), then lin2 split-K
  float* al2s   = (float*)(ws + nxt((size_t)NN*4));
  float* al2d   = (float*)(ws + nxt((size_t)NN*4));
  float* mball  = (float*)(ws + nxt((size_t)32*NN*4));      // 512KB
  float* lball  = (float*)(ws + nxt((size_t)32*NN*4));      // 512KB
  u16* x_b      = (u16*)(ws + nxt((size_t)NN*128*2));
  u16* feat1_b  = (u16*)(ws + nxt((size_t)NN*256*2));
  u16* feat2_b  = (u16*)(ws + nxt((size_t)NN*128*2));
  u16* hgat1_b  = (u16*)(ws + nxt((size_t)NN*256*2));
  u16* attno_b  = (u16*)(ws + nxt((size_t)NN*256*2));
  u16* hln1_b   = (u16*)(ws + nxt((size_t)NN*256*2));
  u16* hln2_b   = (u16*)(ws + nxt((size_t)NN*256*2));
  u16* ff1_b    = (u16*)(ws + nxt((size_t)NN*2048*2));      // 16MB: attn op1 (z>=4), then ff1
  u16* Qb       = (u16*)(ws + nxt((size_t)4*4096*64*2));
  u16* Kb       = (u16*)(ws + nxt((size_t)4*4096*64*2));
  u16* Vt       = (u16*)(ws + nxt((size_t)4*4096*64*2));
  u16* inp_w_b  = (u16*)(ws + nxt((size_t)768*256*2));
  u16* outp_w_b = (u16*)(ws + nxt((size_t)256*256*2));
  u16* lin1_w_b = (u16*)(ws + nxt((size_t)2048*256*2));
  u16* lin2_w_b = (u16*)(ws + nxt((size_t)256*2048*2));
  u16* gat1_w_b = (u16*)(ws + nxt((size_t)256*128*2));
  u16* gat2_w_b = (u16*)(ws + nxt((size_t)128*256*2));

  float* op0 = Po;               // exactly 16,777,216 B for 4 z-partials
  float* op1 = (float*)ff1_b;    // exactly 16,777,216 B for 4 z-partials

  hipMemsetAsync(deg, 0, (size_t)NN*4, stream);
  hipMemsetAsync(cursor, 0, (size_t)NN*4, stream);
  k_count<<<(EE+255)/256, 256, 0, stream>>>(ei, deg);
  k_scan<<<1, 1024, 0, stream>>>(deg, rowptr);
  k_scatter<<<(EE+255)/256, 256, 0, stream>>>(ei, rowptr, cursor, csr_src);

  // all fp32->bf16 conversions in one launch (cumulative float4 ends)
  k_f2b_all<<<1856, 256, 0, stream>>>(
      inp_w,  inp_w_b,  49152,
      outp_w, outp_w_b, 65536,
      lin1_w, lin1_w_b, 196608,
      lin2_w, lin2_w_b, 327680,
      gat1_w, gat1_w_b, 335872,
      gat2_w, gat2_w_b, 344064,
      x,      x_b,      475136);

  // GAT layer 1: proj (MFMA) + logits + aggregate (+ELU)
  k_gemm_mfma<2><<<dim3(4, 64), 256, 0, stream>>>(x_b, gat1_w_b, nullptr, nullptr, feat1_b, nullptr, nullptr, nullptr, NN, 256, 128);
  k_alogits<4,64><<<NN, 256, 0, stream>>>(feat1_b, gat1_as, gat1_ad, al1s, al1d);
  k_gat_agg<4,64,true,true><<<NN, 256, 0, stream>>>(feat1_b, al1s, al1d, gat1_b, rowptr, csr_src, hgat1, hgat1_b);

  // Transformer encoder layer
  k_gemm_mfma<3><<<dim3(12, 64), 256, 0, stream>>>(hgat1_b, inp_w_b, inp_b, nullptr, nullptr, Qb, Kb, Vt, NN, 768, 256);
  k_attn3<<<dim3(32, 4, 8), 256, 0, stream>>>(Qb, Kb, Vt, op0, op1, mball, lball);
  k_attn_mrg8<<<dim3(128, 4), 256, 0, stream>>>(op0, op1, mball, lball, attno_b);
  k_gemm_mfma<0><<<dim3(4, 64), 256, 0, stream>>>(attno_b, outp_w_b, outp_b, tmp256, nullptr, nullptr, nullptr, nullptr, NN, 256, 256);
  k_ln<true><<<NN, 256, 0, stream>>>(tmp256, hgat1, ln1_g, ln1_bb, hln1, hln1_b);
  k_gemm2<1><<<dim3(32, 32), 256, 0, stream>>>(hln1_b, lin1_w_b, lin1_b, nullptr, ff1_b, NN, 2048, 256, 256);
  k_gemm2<4><<<dim3(4, 32, 4), 256, 0, stream>>>(ff1_b, lin2_w_b, nullptr, Po, nullptr, NN, 256, 2048, 512);
  k_ln_sk<true><<<NN, 256, 0, stream>>>(Po, lin2_b, hln1, ln2_g, ln2_bb, hln2, hln2_b);

  // GAT layer 2 -> final output
  k_gemm_mfma<2><<<dim3(2, 64), 256, 0, stream>>>(hln2_b, gat2_w_b, nullptr, nullptr, feat2_b, nullptr, nullptr, nullptr, NN, 128, 256);
  k_alogits<1,128><<<NN, 128, 0, stream>>>(feat2_b, gat2_as, gat2_ad, al2s, al2d);
  k_gat_agg<1,128,false,false><<<NN, 128, 0, stream>>>(feat2_b, al2s, al2d, gat2_b, rowptr, csr_src, out, nullptr);
}

// Round 10
// 266.038 us; speedup vs baseline: 3.6605x; 1.0337x over previous
//
#include <hip/hip_runtime.h>
#include <hip/hip_bf16.h>
#include <math.h>

#define NN 4096
#define NE 131072
#define EE (NE + NN)

typedef unsigned short u16;
typedef short s8v __attribute__((ext_vector_type(8)));
typedef float f4v __attribute__((ext_vector_type(4)));
typedef float f16v __attribute__((ext_vector_type(16)));

__device__ inline u16 f2b(float f) {
  __hip_bfloat16 h = __float2bfloat16(f);
  return __builtin_bit_cast(u16, h);
}
__device__ inline u16 f2bf(float f) {   // branchless exact-RNE bf16 (no NaN path; inputs are finite)
  unsigned int b = __builtin_bit_cast(unsigned int, f);
  b += 0x7FFFu + ((b >> 16) & 1u);
  return (u16)(b >> 16);
}
__device__ inline float b2f(u16 v) {
  unsigned int u = ((unsigned int)v) << 16;
  return __builtin_bit_cast(float, u);
}

// ===================== CSR build =====================
__global__ void k_count(const int* __restrict__ ei, int* __restrict__ deg) {
  int e = blockIdx.x * 256 + threadIdx.x;
  if (e >= EE) return;
  int dst = (e < NE) ? ei[NE + e] : (e - NE);
  atomicAdd(&deg[dst], 1);
}

__global__ __launch_bounds__(1024) void k_scan(const int* __restrict__ deg, int* __restrict__ rowptr) {
  __shared__ int lds[1024];
  int t = threadIdx.x;
  int v0 = deg[t*4+0], v1 = deg[t*4+1], v2 = deg[t*4+2], v3 = deg[t*4+3];
  int s1 = v0+v1, s2 = s1+v2, s3 = s2+v3;
  lds[t] = s3;
  __syncthreads();
  for (int off = 1; off < 1024; off <<= 1) {
    int add = (t >= off) ? lds[t-off] : 0;
    __syncthreads();
    lds[t] += add;
    __syncthreads();
  }
  int base = lds[t] - s3;
  rowptr[t*4+1] = base + v0;
  rowptr[t*4+2] = base + s1;
  rowptr[t*4+3] = base + s2;
  rowptr[t*4+4] = base + s3;
  if (t == 0) rowptr[0] = 0;
}

__global__ void k_scatter(const int* __restrict__ ei, const int* __restrict__ rowptr,
                          int* __restrict__ cursor, int* __restrict__ csr_src) {
  int e = blockIdx.x * 256 + threadIdx.x;
  if (e >= EE) return;
  int src, dst;
  if (e < NE) { src = ei[e]; dst = ei[NE + e]; }
  else { src = e - NE; dst = src; }
  int pos = rowptr[dst] + atomicAdd(&cursor[dst], 1);
  csr_src[pos] = src;
}

// ===================== batched fp32 -> bf16 conversion =====================
__global__ __launch_bounds__(256) void k_f2b_all(
    const float* a0, u16* b0, int e0, const float* a1, u16* b1, int e1,
    const float* a2, u16* b2, int e2, const float* a3, u16* b3, int e3,
    const float* a4, u16* b4, int e4, const float* a5, u16* b5, int e5,
    const float* a6, u16* b6, int e6)
{
  int i = blockIdx.x * 256 + threadIdx.x;
  const float* s; u16* d; int base;
  if      (i < e0) { s=a0; d=b0; base=0;  }
  else if (i < e1) { s=a1; d=b1; base=e0; }
  else if (i < e2) { s=a2; d=b2; base=e1; }
  else if (i < e3) { s=a3; d=b3; base=e2; }
  else if (i < e4) { s=a4; d=b4; base=e3; }
  else if (i < e5) { s=a5; d=b5; base=e4; }
  else if (i < e6) { s=a6; d=b6; base=e5; }
  else return;
  int j = i - base;
  float4 v = ((const float4*)s)[j];
  u16 r[4] = {f2b(v.x), f2b(v.y), f2b(v.z), f2b(v.w)};
  *(uint2*)(d + (size_t)j*4) = *(uint2*)r;
}

// ===================== a-logits via wave shuffles =====================
template<int HEADS, int C>
__global__ __launch_bounds__(256) void k_alogits(
    const u16* __restrict__ featb, const float* __restrict__ asrc,
    const float* __restrict__ adst, float* __restrict__ als, float* __restrict__ ald)
{
  constexpr int F = HEADS * C;
  int n = blockIdx.x, t = threadIdx.x;
  float f = b2f(featb[(size_t)n*F + t]);
  float ps = f * asrc[t];
  float pd = f * adst[t];
  #pragma unroll
  for (int off = 32; off; off >>= 1) {
    ps += __shfl_xor(ps, off);
    pd += __shfl_xor(pd, off);
  }
  if constexpr (C == 64) {
    if ((t & 63) == 0) {
      int hh = t >> 6;
      als[(size_t)n*HEADS + hh] = ps;
      ald[(size_t)n*HEADS + hh] = pd;
    }
  } else {
    __shared__ float sh[2][2];
    if ((t & 63) == 0) { sh[t>>6][0] = ps; sh[t>>6][1] = pd; }
    __syncthreads();
    if (t == 0) {
      als[n] = sh[0][0] + sh[1][0];
      ald[n] = sh[0][1] + sh[1][1];
    }
  }
}

// ===================== GAT aggregation v2: chunked alpha in LDS =====================
template<int HEADS, int C, bool DO_ELU, bool WB>
__global__ __launch_bounds__(256) void k_gat_agg(
    const u16* __restrict__ featb, const float* __restrict__ als,
    const float* __restrict__ ald, const float* __restrict__ bias,
    const int* __restrict__ rowptr, const int* __restrict__ csr_src,
    float* __restrict__ out, u16* __restrict__ outb)
{
  constexpr int F = HEADS * C;
  int n = blockIdx.x, t = threadIdx.x;
  __shared__ float m_sh[HEADS], s_sh[HEADS];
  __shared__ float alpha_sh[HEADS][64];
  __shared__ int src_sh[64];
  int start = rowptr[n];
  int deg = rowptr[n+1] - start;
  int lane = t & 63, wv = t >> 6;
  for (int hh = wv; hh < HEADS; hh += F/64) {
    float adl = ald[(size_t)n*HEADS + hh];
    float mx = -INFINITY;
    for (int i = lane; i < deg; i += 64) {
      int s = csr_src[start + i];
      float lg = als[(size_t)s*HEADS + hh] + adl;
      lg = (lg > 0.f) ? lg : 0.2f * lg;
      mx = fmaxf(mx, lg);
    }
    #pragma unroll
    for (int off = 32; off; off >>= 1) mx = fmaxf(mx, __shfl_xor(mx, off));
    float sm = 0.f;
    for (int i = lane; i < deg; i += 64) {
      int s = csr_src[start + i];
      float lg = als[(size_t)s*HEADS + hh] + adl;
      lg = (lg > 0.f) ? lg : 0.2f * lg;
      sm += expf(lg - mx);
    }
    #pragma unroll
    for (int off = 32; off; off >>= 1) sm += __shfl_xor(sm, off);
    if (lane == 0) { m_sh[hh] = mx; s_sh[hh] = sm; }
  }
  __syncthreads();
  int hh = t / C;
  int hh2 = t >> 6;
  int ia = t & 63;
  float acc0 = 0.f, acc1 = 0.f, acc2 = 0.f, acc3 = 0.f;
  for (int c0 = 0; c0 < deg; c0 += 64) {
    int cn = min(64, deg - c0);
    if (hh2 < HEADS && ia < cn) {
      int s = csr_src[start + c0 + ia];
      if (hh2 == 0) src_sh[ia] = s;
      float lg = als[(size_t)s*HEADS + hh2] + ald[(size_t)n*HEADS + hh2];
      lg = (lg > 0.f) ? lg : 0.2f * lg;
      alpha_sh[hh2][ia] = expf(lg - m_sh[hh2]);
    }
    __syncthreads();
    int i = 0;
    for (; i + 3 < cn; i += 4) {
      int s0 = src_sh[i], s1 = src_sh[i+1], s2 = src_sh[i+2], s3 = src_sh[i+3];
      acc0 += alpha_sh[hh][i]   * b2f(featb[(size_t)s0*F + t]);
      acc1 += alpha_sh[hh][i+1] * b2f(featb[(size_t)s1*F + t]);
      acc2 += alpha_sh[hh][i+2] * b2f(featb[(size_t)s2*F + t]);
      acc3 += alpha_sh[hh][i+3] * b2f(featb[(size_t)s3*F + t]);
    }
    for (; i < cn; ++i)
      acc0 += alpha_sh[hh][i] * b2f(featb[(size_t)src_sh[i]*F + t]);
    __syncthreads();
  }
  float o = ((acc0 + acc1) + (acc2 + acc3)) / (s_sh[hh] + 1e-16f) + bias[t];
  if (DO_ELU) o = (o > 0.f) ? o : (expf(o) - 1.f);
  out[(size_t)n*F + t] = o;
  if (WB) outb[(size_t)n*F + t] = f2b(o);
}

// ===================== bf16 MFMA GEMM 64x64: MODE 0 f32, 2 bf16, 3 qkv scatter =====================
template<int MODE>
__global__ __launch_bounds__(256) void k_gemm_mfma(
    const u16* __restrict__ A, const u16* __restrict__ B,
    const float* __restrict__ bias, float* __restrict__ Cf, u16* __restrict__ Cb,
    u16* __restrict__ Qb, u16* __restrict__ Kb, u16* __restrict__ Vt,
    int M, int N, int K)
{
  __shared__ u16 Al[64*64];
  __shared__ u16 Bl[64*64];
  char* Ab = (char*)Al;
  char* Bb = (char*)Bl;
  const int t = threadIdx.x;
  const int lane = t & 63;
  const int lr = lane & 15, lk = lane >> 4;
  const int wid = t >> 6;
  const int wm = wid & 1, wn = wid >> 1;
  const int m0 = blockIdx.y * 64, n0 = blockIdx.x * 64;

  f4v acc[2][2];
  #pragma unroll
  for (int mi = 0; mi < 2; ++mi)
    #pragma unroll
    for (int ni = 0; ni < 2; ++ni)
      acc[mi][ni] = f4v{0.f, 0.f, 0.f, 0.f};

  for (int k0 = 0; k0 < K; k0 += 64) {
    #pragma unroll
    for (int i = 0; i < 2; ++i) {
      int idx = t + i*256;
      int row = idx >> 3, ch = idx & 7;
      s8v av = *(const s8v*)(A + (size_t)(m0 + row)*K + k0 + ch*8);
      *(s8v*)(Ab + row*128 + ((ch*16) ^ ((row & 7) << 4))) = av;
      s8v bv = *(const s8v*)(B + (size_t)(n0 + row)*K + k0 + ch*8);
      *(s8v*)(Bb + row*128 + ((ch*16) ^ ((row & 7) << 4))) = bv;
    }
    __syncthreads();
    #pragma unroll
    for (int ks = 0; ks < 2; ++ks) {
      s8v af[2], bfr[2];
      #pragma unroll
      for (int mi = 0; mi < 2; ++mi) {
        int row = wm*32 + mi*16 + lr;
        int ch = ks*4 + lk;
        af[mi] = *(const s8v*)(Ab + row*128 + ((ch*16) ^ ((row & 7) << 4)));
      }
      #pragma unroll
      for (int ni = 0; ni < 2; ++ni) {
        int row = wn*32 + ni*16 + lr;
        int ch = ks*4 + lk;
        bfr[ni] = *(const s8v*)(Bb + row*128 + ((ch*16) ^ ((row & 7) << 4)));
      }
      #pragma unroll
      for (int mi = 0; mi < 2; ++mi)
        #pragma unroll
        for (int ni = 0; ni < 2; ++ni)
          acc[mi][ni] = __builtin_amdgcn_mfma_f32_16x16x32_bf16(af[mi], bfr[ni], acc[mi][ni], 0, 0, 0);
    }
    __syncthreads();
  }
  #pragma unroll
  for (int ni = 0; ni < 2; ++ni) {
    int col = n0 + wn*32 + ni*16 + lr;
    float bc = bias ? bias[col] : 0.f;
    #pragma unroll
    for (int mi = 0; mi < 2; ++mi) {
      int row0 = m0 + wm*32 + mi*16 + lk*4;
      float v[4];
      #pragma unroll
      for (int r = 0; r < 4; ++r) v[r] = acc[mi][ni][r] + bc;
      if (MODE == 0) {
        #pragma unroll
        for (int r = 0; r < 4; ++r) Cf[(size_t)(row0 + r)*N + col] = v[r];
      } else if (MODE == 2) {
        #pragma unroll
        for (int r = 0; r < 4; ++r) Cb[(size_t)(row0 + r)*N + col] = f2b(v[r]);
      } else { // MODE 3: qkv scatter
        if (col < 512) {
          int head = (col >> 6) & 3;
          int d = col & 63;
          u16* dst = ((col < 256) ? Qb : Kb) + (size_t)head*262144 + d;
          #pragma unroll
          for (int r = 0; r < 4; ++r) dst[(size_t)(row0 + r)*64] = f2b(v[r]);
        } else {
          int cc = col - 512;
          int head = cc >> 6;
          int d = cc & 63;
          int quad = row0 & 12;
          int qs = (quad == 4) ? 8 : ((quad == 8) ? 4 : quad);
          size_t nphys = (size_t)((row0 & ~15) | qs);
          u16 o4[4];
          #pragma unroll
          for (int r = 0; r < 4; ++r) o4[r] = f2b(v[r]);
          *(uint2*)(Vt + (size_t)head*262144 + (size_t)d*4096 + nphys) = *(uint2*)o4;
        }
      }
    }
  }
}

// ===================== bf16 MFMA GEMM 128x64 tile: MODE 1 relu+bf16, MODE 4 split-K f32 partials =====================
template<int MODE>
__global__ __launch_bounds__(256) void k_gemm2(
    const u16* __restrict__ A, const u16* __restrict__ B,
    const float* __restrict__ bias, float* __restrict__ Cf, u16* __restrict__ Cb,
    int M, int N, int K, int ksl)
{
  __shared__ u16 Al[128*64];
  __shared__ u16 Bl[64*64];
  char* Ab = (char*)Al;
  char* Bb = (char*)Bl;
  const int t = threadIdx.x;
  const int lane = t & 63;
  const int lr = lane & 15, lk = lane >> 4;
  const int wv = t >> 6;
  const int m0 = blockIdx.y * 128, n0 = blockIdx.x * 64;
  const int z = blockIdx.z;
  const int kbeg = z * ksl, kend = kbeg + ksl;

  f4v acc[2][4];
  #pragma unroll
  for (int mi = 0; mi < 2; ++mi)
    #pragma unroll
    for (int ni = 0; ni < 4; ++ni)
      acc[mi][ni] = f4v{0.f, 0.f, 0.f, 0.f};

  for (int k0 = kbeg; k0 < kend; k0 += 64) {
    #pragma unroll
    for (int i = 0; i < 4; ++i) {
      int idx = t + i*256;
      int row = idx >> 3, ch = idx & 7;
      s8v av = *(const s8v*)(A + (size_t)(m0 + row)*K + k0 + ch*8);
      *(s8v*)(Ab + row*128 + ((ch*16) ^ ((row & 7) << 4))) = av;
    }
    #pragma unroll
    for (int i = 0; i < 2; ++i) {
      int idx = t + i*256;
      int row = idx >> 3, ch = idx & 7;
      s8v bv = *(const s8v*)(B + (size_t)(n0 + row)*K + k0 + ch*8);
      *(s8v*)(Bb + row*128 + ((ch*16) ^ ((row & 7) << 4))) = bv;
    }
    __syncthreads();
    #pragma unroll
    for (int ks = 0; ks < 2; ++ks) {
      s8v af[2], bfr[4];
      #pragma unroll
      for (int mi = 0; mi < 2; ++mi) {
        int row = wv*32 + mi*16 + lr;
        int ch = ks*4 + lk;
        af[mi] = *(const s8v*)(Ab + row*128 + ((ch*16) ^ ((row & 7) << 4)));
      }
      #pragma unroll
      for (int ni = 0; ni < 4; ++ni) {
        int row = ni*16 + lr;
        int ch = ks*4 + lk;
        bfr[ni] = *(const s8v*)(Bb + row*128 + ((ch*16) ^ ((row & 7) << 4)));
      }
      #pragma unroll
      for (int mi = 0; mi < 2; ++mi)
        #pragma unroll
        for (int ni = 0; ni < 4; ++ni)
          acc[mi][ni] = __builtin_amdgcn_mfma_f32_16x16x32_bf16(af[mi], bfr[ni], acc[mi][ni], 0, 0, 0);
    }
    __syncthreads();
  }
  #pragma unroll
  for (int ni = 0; ni < 4; ++ni) {
    int col = n0 + ni*16 + lr;
    float bc = (MODE == 4) ? 0.f : bias[col];
    #pragma unroll
    for (int mi = 0; mi < 2; ++mi) {
      int row0 = m0 + wv*32 + mi*16 + lk*4;
      #pragma unroll
      for (int r = 0; r < 4; ++r) {
        float v = acc[mi][ni][r] + bc;
        if (MODE == 1) {
          v = fmaxf(v, 0.f);
          Cb[(size_t)(row0 + r)*N + col] = f2b(v);
        } else {
          (Cf + (size_t)z*M*N)[(size_t)(row0 + r)*N + col] = v;
        }
      }
    }
  }
}

// ===================== LayerNorm(a + res) =====================
template<bool WB>
__global__ __launch_bounds__(256) void k_ln(
    const float* __restrict__ a, const float* __restrict__ res,
    const float* __restrict__ g, const float* __restrict__ bb,
    float* __restrict__ out, u16* __restrict__ outb)
{
  int n = blockIdx.x, t = threadIdx.x;
  __shared__ float part[4];
  float v = a[(size_t)n*256 + t] + res[(size_t)n*256 + t];
  float s = v;
  #pragma unroll
  for (int off = 32; off; off >>= 1) s += __shfl_xor(s, off);
  if ((t & 63) == 0) part[t >> 6] = s;
  __syncthreads();
  float mean = (part[0] + part[1] + part[2] + part[3]) * (1.f/256.f);
  __syncthreads();
  float d = v - mean;
  float s2 = d * d;
  #pragma unroll
  for (int off = 32; off; off >>= 1) s2 += __shfl_xor(s2, off);
  if ((t & 63) == 0) part[t >> 6] = s2;
  __syncthreads();
  float var = (part[0] + part[1] + part[2] + part[3]) * (1.f/256.f);
  float rstd = rsqrtf(var + 1e-5f);
  float o = d * rstd * g[t] + bb[t];
  out[(size_t)n*256 + t] = o;
  if (WB) outb[(size_t)n*256 + t] = f2b(o);
}

// ===================== LayerNorm over 4 split-K partials + bias + res =====================
template<bool WB>
__global__ __launch_bounds__(256) void k_ln_sk(
    const float* __restrict__ Po, const float* __restrict__ bias,
    const float* __restrict__ res, const float* __restrict__ g,
    const float* __restrict__ bb, float* __restrict__ out, u16* __restrict__ outb)
{
  int n = blockIdx.x, t = threadIdx.x;
  __shared__ float part[4];
  const size_t MN = (size_t)NN * 256;
  size_t idx = (size_t)n*256 + t;
  float v = Po[idx] + Po[MN + idx] + Po[2*MN + idx] + Po[3*MN + idx]
          + bias[t] + res[idx];
  float s = v;
  #pragma unroll
  for (int off = 32; off; off >>= 1) s += __shfl_xor(s, off);
  if ((t & 63) == 0) part[t >> 6] = s;
  __syncthreads();
  float mean = (part[0] + part[1] + part[2] + part[3]) * (1.f/256.f);
  __syncthreads();
  float d = v - mean;
  float s2 = d * d;
  #pragma unroll
  for (int off = 32; off; off >>= 1) s2 += __shfl_xor(s2, off);
  if ((t & 63) == 0) part[t >> 6] = s2;
  __syncthreads();
  float var = (part[0] + part[1] + part[2] + part[3]) * (1.f/256.f);
  float rstd = rsqrtf(var + 1e-5f);
  float o = d * rstd * g[t] + bb[t];
  out[idx] = o;
  if (WB) outb[idx] = f2b(o);
}

// ===================== bf16 MFMA flash attention v6: dbuf LDS, 1 barrier/tile =====================
// grid (32 strips, 4 heads, 4 z); 4-wave blocks; block covers 128 queries,
// keys [z*1024, +1024) in 16 tiles of 64. K/V double-buffered in LDS (32KB).
// T14 issue-early/write-late; single barrier per tile.
__global__ __launch_bounds__(256) void k_attn3(
    const u16* __restrict__ Qb, const u16* __restrict__ Kb,
    const u16* __restrict__ Vt, float* __restrict__ op,
    float* __restrict__ mball, float* __restrict__ lball)
{
  const int strip = blockIdx.x;
  const int head  = blockIdx.y;
  const int z     = blockIdx.z;
  const int t = threadIdx.x;
  const int wv = t >> 6;
  const int l = t & 63;
  const int lq = l & 31;
  const int lh = l >> 5;
  const int q0 = strip*128 + wv*32;

  __shared__ u16 Kl[2][64*64];
  __shared__ u16 Vl[2][64*64];

  const u16* Qh = Qb + (size_t)head * (4096*64);
  const u16* Kh = Kb + (size_t)head * (4096*64);
  const u16* Vh = Vt + (size_t)head * (64*4096);

  s8v qf[4];
#pragma unroll
  for (int dc = 0; dc < 4; ++dc)
    qf[dc] = *(const s8v*)(Qh + (size_t)(q0 + lq)*64 + dc*16 + lh*8);

  // staging: thread t owns 16B chunks {t, t+256} of both K and V tiles
  const int c0 = t, c1 = t + 256;
  const int kr0 = c0 >> 3, kc0 = c0 & 7;
  const int kr1 = c1 >> 3, kc1 = c1 & 7;
  const int kt0 = z * 1024;
  const u16* gK0 = Kh + (size_t)(kt0 + kr0)*64 + kc0*8;
  const u16* gK1 = Kh + (size_t)(kt0 + kr1)*64 + kc1*8;
  const u16* gV0 = Vh + (size_t)kr0*4096 + kt0 + kc0*8;
  const u16* gV1 = Vh + (size_t)kr1*4096 + kt0 + kc1*8;
  const int lo0 = kr0*128 + ((kc0*16) ^ ((kr0 & 7) << 4));
  const int lo1 = kr1*128 + ((kc1*16) ^ ((kr1 & 7) << 4));

  // stage tile 0 into buffer 0
  {
    s8v a = *(const s8v*)gK0, b = *(const s8v*)gK1;
    s8v c = *(const s8v*)gV0, d = *(const s8v*)gV1;
    *(s8v*)((char*)Kl[0] + lo0) = a; *(s8v*)((char*)Kl[0] + lo1) = b;
    *(s8v*)((char*)Vl[0] + lo0) = c; *(s8v*)((char*)Vl[0] + lo1) = d;
  }
  __syncthreads();

  // constant LDS read offsets (tile-independent)
  int roK[2][4];
#pragma unroll
  for (int c = 0; c < 2; ++c) {
    int row = c*32 + lq;
#pragma unroll
    for (int dc = 0; dc < 4; ++dc)
      roK[c][dc] = row*128 + ((dc*32 + lh*16) ^ ((row & 7) << 4));
  }
  int roV[2][2][2];
#pragma unroll
  for (int dm = 0; dm < 2; ++dm) {
    int row = dm*32 + lq;
#pragma unroll
    for (int c = 0; c < 2; ++c)
#pragma unroll
      for (int kc = 0; kc < 2; ++kc)
        roV[c][kc][dm] = row*128 + ((c*64 + kc*32 + lh*16) ^ ((row & 7) << 4));
  }

  f16v accO[2];
#pragma unroll
  for (int dm = 0; dm < 2; ++dm)
#pragma unroll
    for (int i = 0; i < 16; ++i) accO[dm][i] = 0.f;
  float mrow = -INFINITY, lrow = 0.f;
  const float CE = 0.18033688011112042f;  // log2(e)/8

  s8v rK0, rK1, rV0, rV1;
  for (int tt = 0; tt < 16; ++tt) {
    const int cur = tt & 1;
    char* Kc = (char*)Kl[cur];
    char* Vc = (char*)Vl[cur];
    char* Kn = (char*)Kl[cur ^ 1];
    char* Vn = (char*)Vl[cur ^ 1];
    if (tt < 15) {           // T14 issue-early: next tile's global loads
      gK0 += 64*64; gK1 += 64*64; gV0 += 64; gV1 += 64;
      rK0 = *(const s8v*)gK0; rK1 = *(const s8v*)gK1;
      rV0 = *(const s8v*)gV0; rV1 = *(const s8v*)gV1;
    }
    // QK^T from LDS
    s8v kf[2][4];
#pragma unroll
    for (int c = 0; c < 2; ++c)
#pragma unroll
      for (int dc = 0; dc < 4; ++dc)
        kf[c][dc] = *(const s8v*)(Kc + roK[c][dc]);
    f16v st[2];
#pragma unroll
    for (int c = 0; c < 2; ++c)
#pragma unroll
      for (int i = 0; i < 16; ++i) st[c][i] = 0.f;
#pragma unroll
    for (int dc = 0; dc < 4; ++dc) {
      st[0] = __builtin_amdgcn_mfma_f32_32x32x16_bf16(kf[0][dc], qf[dc], st[0], 0, 0, 0);
      st[1] = __builtin_amdgcn_mfma_f32_32x32x16_bf16(kf[1][dc], qf[dc], st[1], 0, 0, 0);
    }
    // softmax
    float mx = st[0][0];
#pragma unroll
    for (int i = 1; i < 16; ++i) mx = fmaxf(mx, st[0][i]);
#pragma unroll
    for (int i = 0; i < 16; ++i) mx = fmaxf(mx, st[1][i]);
    mx = fmaxf(mx, __shfl_xor(mx, 32));
    float mn = fmaxf(mrow, mx);
    float sc = exp2f((mrow - mn) * CE);
    mrow = mn;
    float ps = 0.f;
#pragma unroll
    for (int c = 0; c < 2; ++c)
#pragma unroll
      for (int i = 0; i < 16; ++i) {
        float p = exp2f((st[c][i] - mn) * CE);
        st[c][i] = p;
        ps += p;
      }
    ps += __shfl_xor(ps, 32);
    lrow = lrow * sc + ps;
#pragma unroll
    for (int dm = 0; dm < 2; ++dm)
#pragma unroll
      for (int i = 0; i < 16; ++i) accO[dm][i] *= sc;

    // PV from LDS (V pre-permuted in global)
#pragma unroll
    for (int c = 0; c < 2; ++c) {
#pragma unroll
      for (int kc = 0; kc < 2; ++kc) {
        s8v vf0 = *(const s8v*)(Vc + roV[c][kc][0]);
        s8v vf1 = *(const s8v*)(Vc + roV[c][kc][1]);
        union { s8v v; unsigned int w[4]; } pb;
#pragma unroll
        for (int wd = 0; wd < 4; ++wd) {
          pb.w[wd] = (unsigned int)f2bf(st[c][kc*8 + wd*2])
                   | ((unsigned int)f2bf(st[c][kc*8 + wd*2 + 1]) << 16);
        }
        accO[0] = __builtin_amdgcn_mfma_f32_32x32x16_bf16(vf0, pb.v, accO[0], 0, 0, 0);
        accO[1] = __builtin_amdgcn_mfma_f32_32x32x16_bf16(vf1, pb.v, accO[1], 0, 0, 0);
      }
    }
    if (tt < 15) {           // T14 write-late: into the idle buffer (no pre-barrier needed)
      *(s8v*)(Kn + lo0) = rK0; *(s8v*)(Kn + lo1) = rK1;
      *(s8v*)(Vn + lo0) = rV0; *(s8v*)(Vn + lo1) = rV1;
    }
    __syncthreads();         // writes to next buf visible; everyone done reading cur
  }

  // write partial (m, l, O) for this z-split
  int q = q0 + lq;
  int pidx = (z*4 + head)*4096 + q;
  if (lh == 0) { mball[pidx] = mrow; lball[pidx] = lrow; }
  size_t obase = ((size_t)(z*4 + head)*4096 + q)*64;
#pragma unroll
  for (int dm = 0; dm < 2; ++dm)
#pragma unroll
    for (int g = 0; g < 4; ++g) {
      f4v v;
#pragma unroll
      for (int rr = 0; rr < 4; ++rr) v[rr] = accO[dm][g*4 + rr];
      *(f4v*)&op[obase + dm*32 + lh*4 + g*8] = v;
    }
}

// merge the 4 z-partials -> bf16 attn output
__global__ __launch_bounds__(256) void k_attn_mrg4(
    const float* __restrict__ op, const float* __restrict__ mball,
    const float* __restrict__ lball, u16* __restrict__ attno_b)
{
  const int bq = blockIdx.x;       // 0..127
  const int head = blockIdx.y;
  const int t = threadIdx.x;
  const int q = bq*32 + (t >> 3);
  const int d0 = (t & 7) * 8;
  const float CE = 0.18033688011112042f;
  float m[4], M = -INFINITY;
#pragma unroll
  for (int z = 0; z < 4; ++z) {
    m[z] = mball[(z*4 + head)*4096 + q];
    M = fmaxf(M, m[z]);
  }
  float w[4], L = 0.f;
#pragma unroll
  for (int z = 0; z < 4; ++z) {
    w[z] = exp2f((m[z] - M) * CE);
    L += w[z] * lball[(z*4 + head)*4096 + q];
  }
  float inv = 1.f / L;
  float o[8] = {0,0,0,0,0,0,0,0};
#pragma unroll
  for (int z = 0; z < 4; ++z) {
    size_t base = ((size_t)(z*4 + head)*4096 + q)*64 + d0;
    f4v a = *(const f4v*)&op[base];
    f4v b = *(const f4v*)&op[base + 4];
#pragma unroll
    for (int i = 0; i < 4; ++i) { o[i] += w[z]*a[i]; o[4+i] += w[z]*b[i]; }
  }
  u16 o8[8];
#pragma unroll
  for (int i = 0; i < 8; ++i) o8[i] = f2b(o[i] * inv);
  *(uint4*)(attno_b + (size_t)q*256 + head*64 + d0) = *(uint4*)o8;
}

// ===================== host launcher =====================
extern "C" void kernel_launch(void* const* d_in, const int* in_sizes, int n_in,
                              void* d_out, int out_size, void* d_ws, size_t ws_size,
                              hipStream_t stream)
{
  const float* x       = (const float*)d_in[0];
  const int*   ei      = (const int*)d_in[1];
  const float* gat1_w  = (const float*)d_in[2];
  const float* gat1_as = (const float*)d_in[3];
  const float* gat1_ad = (const float*)d_in[4];
  const float* gat1_b  = (const float*)d_in[5];
  const float* inp_w   = (const float*)d_in[6];
  const float* inp_b   = (const float*)d_in[7];
  const float* outp_w  = (const float*)d_in[8];
  const float* outp_b  = (const float*)d_in[9];
  const float* lin1_w  = (const float*)d_in[10];
  const float* lin1_b  = (const float*)d_in[11];
  const float* lin2_w  = (const float*)d_in[12];
  const float* lin2_b  = (const float*)d_in[13];
  const float* ln1_g   = (const float*)d_in[14];
  const float* ln1_bb  = (const float*)d_in[15];
  const float* ln2_g   = (const float*)d_in[16];
  const float* ln2_bb  = (const float*)d_in[17];
  const float* gat2_w  = (const float*)d_in[18];
  const float* gat2_as = (const float*)d_in[19];
  const float* gat2_ad = (const float*)d_in[20];
  const float* gat2_b  = (const float*)d_in[21];
  float* out = (float*)d_out;
  (void)in_sizes; (void)n_in; (void)out_size; (void)ws_size;

  char* ws = (char*)d_ws;
  size_t off = 0;
  auto nxt = [&](size_t bytes) { size_t r = off; off += (bytes + 255) & ~(size_t)255; return r; };
  int* deg      = (int*)(ws + nxt((size_t)NN*4));
  int* cursor   = (int*)(ws + nxt((size_t)NN*4));
  int* rowptr   = (int*)(ws + nxt((size_t)(NN+1)*4));
  int* csr_src  = (int*)(ws + nxt((size_t)EE*4));
  float* al1s   = (float*)(ws + nxt((size_t)NN*4*4));
  float* al1d   = (float*)(ws + nxt((size_t)NN*4*4));
  float* hgat1  = (float*)(ws + nxt((size_t)NN*256*4));
  float* tmp256 = (float*)(ws + nxt((size_t)NN*256*4));
  float* hln1   = (float*)(ws + nxt((size_t)NN*256*4));
  float* hln2   = (float*)(ws + nxt((size_t)NN*256*4));
  float* Po     = (float*)(ws + nxt((size_t)4*NN*256*4));   // 16MB: attn partials (4 z), then lin2 split-K
  float* al2s   = (float*)(ws + nxt((size_t)NN*4));
  float* al2d   = (float*)(ws + nxt((size_t)NN*4));
  float* mball  = (float*)(ws + nxt((size_t)16*NN*4));      // 256KB
  float* lball  = (float*)(ws + nxt((size_t)16*NN*4));      // 256KB
  u16* x_b      = (u16*)(ws + nxt((size_t)NN*128*2));
  u16* feat1_b  = (u16*)(ws + nxt((size_t)NN*256*2));
  u16* feat2_b  = (u16*)(ws + nxt((size_t)NN*128*2));
  u16* hgat1_b  = (u16*)(ws + nxt((size_t)NN*256*2));
  u16* attno_b  = (u16*)(ws + nxt((size_t)NN*256*2));
  u16* hln1_b   = (u16*)(ws + nxt((size_t)NN*256*2));
  u16* hln2_b   = (u16*)(ws + nxt((size_t)NN*256*2));
  u16* ff1_b    = (u16*)(ws + nxt((size_t)NN*2048*2));
  u16* Qb       = (u16*)(ws + nxt((size_t)4*4096*64*2));
  u16* Kb       = (u16*)(ws + nxt((size_t)4*4096*64*2));
  u16* Vt       = (u16*)(ws + nxt((size_t)4*4096*64*2));
  u16* inp_w_b  = (u16*)(ws + nxt((size_t)768*256*2));
  u16* outp_w_b = (u16*)(ws + nxt((size_t)256*256*2));
  u16* lin1_w_b = (u16*)(ws + nxt((size_t)2048*256*2));
  u16* lin2_w_b = (u16*)(ws + nxt((size_t)256*2048*2));
  u16* gat1_w_b = (u16*)(ws + nxt((size_t)256*128*2));
  u16* gat2_w_b = (u16*)(ws + nxt((size_t)128*256*2));

  hipMemsetAsync(deg, 0, (size_t)NN*4, stream);
  hipMemsetAsync(cursor, 0, (size_t)NN*4, stream);
  k_count<<<(EE+255)/256, 256, 0, stream>>>(ei, deg);
  k_scan<<<1, 1024, 0, stream>>>(deg, rowptr);
  k_scatter<<<(EE+255)/256, 256, 0, stream>>>(ei, rowptr, cursor, csr_src);

  // all fp32->bf16 conversions in one launch (cumulative float4 ends)
  k_f2b_all<<<1856, 256, 0, stream>>>(
      inp_w,  inp_w_b,  49152,
      outp_w, outp_w_b, 65536,
      lin1_w, lin1_w_b, 196608,
      lin2_w, lin2_w_b, 327680,
      gat1_w, gat1_w_b, 335872,
      gat2_w, gat2_w_b, 344064,
      x,      x_b,      475136);

  // GAT layer 1: proj (MFMA) + logits + aggregate (+ELU)
  k_gemm_mfma<2><<<dim3(4, 64), 256, 0, stream>>>(x_b, gat1_w_b, nullptr, nullptr, feat1_b, nullptr, nullptr, nullptr, NN, 256, 128);
  k_alogits<4,64><<<NN, 256, 0, stream>>>(feat1_b, gat1_as, gat1_ad, al1s, al1d);
  k_gat_agg<4,64,true,true><<<NN, 256, 0, stream>>>(feat1_b, al1s, al1d, gat1_b, rowptr, csr_src, hgat1, hgat1_b);

  // Transformer encoder layer
  k_gemm_mfma<3><<<dim3(12, 64), 256, 0, stream>>>(hgat1_b, inp_w_b, inp_b, nullptr, nullptr, Qb, Kb, Vt, NN, 768, 256);
  k_attn3<<<dim3(32, 4, 4), 256, 0, stream>>>(Qb, Kb, Vt, Po, mball, lball);
  k_attn_mrg4<<<dim3(128, 4), 256, 0, stream>>>(Po, mball, lball, attno_b);
  k_gemm_mfma<0><<<dim3(4, 64), 256, 0, stream>>>(attno_b, outp_w_b, outp_b, tmp256, nullptr, nullptr, nullptr, nullptr, NN, 256, 256);
  k_ln<true><<<NN, 256, 0, stream>>>(tmp256, hgat1, ln1_g, ln1_bb, hln1, hln1_b);
  k_gemm2<1><<<dim3(32, 32), 256, 0, stream>>>(hln1_b, lin1_w_b, lin1_b, nullptr, ff1_b, NN, 2048, 256, 256);
  k_gemm2<4><<<dim3(4, 32, 4), 256, 0, stream>>>(ff1_b, lin2_w_b, nullptr, Po, nullptr, NN, 256, 2048, 512);
  k_ln_sk<true><<<NN, 256, 0, stream>>>(Po, lin2_b, hln1, ln2_g, ln2_bb, hln2, hln2_b);

  // GAT layer 2 -> final output
  k_gemm_mfma<2><<<dim3(2, 64), 256, 0, stream>>>(hln2_b, gat2_w_b, nullptr, nullptr, feat2_b, nullptr, nullptr, nullptr, NN, 128, 256);
  k_alogits<1,128><<<NN, 128, 0, stream>>>(feat2_b, gat2_as, gat2_ad, al2s, al2d);
  k_gat_agg<1,128,false,false><<<NN, 128, 0, stream>>>(feat2_b, al2s, al2d, gat2_b, rowptr, csr_src, out, nullptr);
}

// Round 11
// 260.625 us; speedup vs baseline: 3.7365x; 1.0208x over previous
//
#include <hip/hip_runtime.h>
#include <hip/hip_bf16.h>
#include <math.h>

#define NN 4096
#define NE 131072
#define EE (NE + NN)

typedef unsigned short u16;
typedef short s8v __attribute__((ext_vector_type(8)));
typedef float f4v __attribute__((ext_vector_type(4)));
typedef float f16v __attribute__((ext_vector_type(16)));

__device__ inline u16 f2b(float f) {
  __hip_bfloat16 h = __float2bfloat16(f);
  return __builtin_bit_cast(u16, h);
}
__device__ inline float b2f(u16 v) {
  unsigned int u = ((unsigned int)v) << 16;
  return __builtin_bit_cast(float, u);
}
__device__ inline unsigned int cvt_pk_bf16(float lo, float hi) {
  unsigned int r;
  asm("v_cvt_pk_bf16_f32 %0, %1, %2" : "=v"(r) : "v"(lo), "v"(hi));
  return r;
}

// ===================== CSR build =====================
__global__ void k_count(const int* __restrict__ ei, int* __restrict__ deg) {
  int e = blockIdx.x * 256 + threadIdx.x;
  if (e >= EE) return;
  int dst = (e < NE) ? ei[NE + e] : (e - NE);
  atomicAdd(&deg[dst], 1);
}

__global__ __launch_bounds__(1024) void k_scan(const int* __restrict__ deg, int* __restrict__ rowptr) {
  __shared__ int lds[1024];
  int t = threadIdx.x;
  int v0 = deg[t*4+0], v1 = deg[t*4+1], v2 = deg[t*4+2], v3 = deg[t*4+3];
  int s1 = v0+v1, s2 = s1+v2, s3 = s2+v3;
  lds[t] = s3;
  __syncthreads();
  for (int off = 1; off < 1024; off <<= 1) {
    int add = (t >= off) ? lds[t-off] : 0;
    __syncthreads();
    lds[t] += add;
    __syncthreads();
  }
  int base = lds[t] - s3;
  rowptr[t*4+1] = base + v0;
  rowptr[t*4+2] = base + s1;
  rowptr[t*4+3] = base + s2;
  rowptr[t*4+4] = base + s3;
  if (t == 0) rowptr[0] = 0;
}

__global__ void k_scatter(const int* __restrict__ ei, const int* __restrict__ rowptr,
                          int* __restrict__ cursor, int* __restrict__ csr_src) {
  int e = blockIdx.x * 256 + threadIdx.x;
  if (e >= EE) return;
  int src, dst;
  if (e < NE) { src = ei[e]; dst = ei[NE + e]; }
  else { src = e - NE; dst = src; }
  int pos = rowptr[dst] + atomicAdd(&cursor[dst], 1);
  csr_src[pos] = src;
}

// ===================== batched fp32 -> bf16 conversion =====================
__global__ __launch_bounds__(256) void k_f2b_all(
    const float* a0, u16* b0, int e0, const float* a1, u16* b1, int e1,
    const float* a2, u16* b2, int e2, const float* a3, u16* b3, int e3,
    const float* a4, u16* b4, int e4, const float* a5, u16* b5, int e5,
    const float* a6, u16* b6, int e6)
{
  int i = blockIdx.x * 256 + threadIdx.x;
  const float* s; u16* d; int base;
  if      (i < e0) { s=a0; d=b0; base=0;  }
  else if (i < e1) { s=a1; d=b1; base=e0; }
  else if (i < e2) { s=a2; d=b2; base=e1; }
  else if (i < e3) { s=a3; d=b3; base=e2; }
  else if (i < e4) { s=a4; d=b4; base=e3; }
  else if (i < e5) { s=a5; d=b5; base=e4; }
  else if (i < e6) { s=a6; d=b6; base=e5; }
  else return;
  int j = i - base;
  float4 v = ((const float4*)s)[j];
  u16 r[4] = {f2b(v.x), f2b(v.y), f2b(v.z), f2b(v.w)};
  *(uint2*)(d + (size_t)j*4) = *(uint2*)r;
}

// ===================== a-logits via wave shuffles =====================
template<int HEADS, int C>
__global__ __launch_bounds__(256) void k_alogits(
    const u16* __restrict__ featb, const float* __restrict__ asrc,
    const float* __restrict__ adst, float* __restrict__ als, float* __restrict__ ald)
{
  constexpr int F = HEADS * C;
  int n = blockIdx.x, t = threadIdx.x;
  float f = b2f(featb[(size_t)n*F + t]);
  float ps = f * asrc[t];
  float pd = f * adst[t];
  #pragma unroll
  for (int off = 32; off; off >>= 1) {
    ps += __shfl_xor(ps, off);
    pd += __shfl_xor(pd, off);
  }
  if constexpr (C == 64) {
    if ((t & 63) == 0) {
      int hh = t >> 6;
      als[(size_t)n*HEADS + hh] = ps;
      ald[(size_t)n*HEADS + hh] = pd;
    }
  } else {
    __shared__ float sh[2][2];
    if ((t & 63) == 0) { sh[t>>6][0] = ps; sh[t>>6][1] = pd; }
    __syncthreads();
    if (t == 0) {
      als[n] = sh[0][0] + sh[1][0];
      ald[n] = sh[0][1] + sh[1][1];
    }
  }
}

// ===================== GAT aggregation v2: chunked alpha in LDS =====================
template<int HEADS, int C, bool DO_ELU, bool WB>
__global__ __launch_bounds__(256) void k_gat_agg(
    const u16* __restrict__ featb, const float* __restrict__ als,
    const float* __restrict__ ald, const float* __restrict__ bias,
    const int* __restrict__ rowptr, const int* __restrict__ csr_src,
    float* __restrict__ out, u16* __restrict__ outb)
{
  constexpr int F = HEADS * C;
  int n = blockIdx.x, t = threadIdx.x;
  __shared__ float m_sh[HEADS], s_sh[HEADS];
  __shared__ float alpha_sh[HEADS][64];
  __shared__ int src_sh[64];
  int start = rowptr[n];
  int deg = rowptr[n+1] - start;
  int lane = t & 63, wv = t >> 6;
  for (int hh = wv; hh < HEADS; hh += F/64) {
    float adl = ald[(size_t)n*HEADS + hh];
    float mx = -INFINITY;
    for (int i = lane; i < deg; i += 64) {
      int s = csr_src[start + i];
      float lg = als[(size_t)s*HEADS + hh] + adl;
      lg = (lg > 0.f) ? lg : 0.2f * lg;
      mx = fmaxf(mx, lg);
    }
    #pragma unroll
    for (int off = 32; off; off >>= 1) mx = fmaxf(mx, __shfl_xor(mx, off));
    float sm = 0.f;
    for (int i = lane; i < deg; i += 64) {
      int s = csr_src[start + i];
      float lg = als[(size_t)s*HEADS + hh] + adl;
      lg = (lg > 0.f) ? lg : 0.2f * lg;
      sm += expf(lg - mx);
    }
    #pragma unroll
    for (int off = 32; off; off >>= 1) sm += __shfl_xor(sm, off);
    if (lane == 0) { m_sh[hh] = mx; s_sh[hh] = sm; }
  }
  __syncthreads();
  int hh = t / C;
  int hh2 = t >> 6;
  int ia = t & 63;
  float acc0 = 0.f, acc1 = 0.f, acc2 = 0.f, acc3 = 0.f;
  for (int c0 = 0; c0 < deg; c0 += 64) {
    int cn = min(64, deg - c0);
    if (hh2 < HEADS && ia < cn) {
      int s = csr_src[start + c0 + ia];
      if (hh2 == 0) src_sh[ia] = s;
      float lg = als[(size_t)s*HEADS + hh2] + ald[(size_t)n*HEADS + hh2];
      lg = (lg > 0.f) ? lg : 0.2f * lg;
      alpha_sh[hh2][ia] = expf(lg - m_sh[hh2]);
    }
    __syncthreads();
    int i = 0;
    for (; i + 3 < cn; i += 4) {
      int s0 = src_sh[i], s1 = src_sh[i+1], s2 = src_sh[i+2], s3 = src_sh[i+3];
      acc0 += alpha_sh[hh][i]   * b2f(featb[(size_t)s0*F + t]);
      acc1 += alpha_sh[hh][i+1] * b2f(featb[(size_t)s1*F + t]);
      acc2 += alpha_sh[hh][i+2] * b2f(featb[(size_t)s2*F + t]);
      acc3 += alpha_sh[hh][i+3] * b2f(featb[(size_t)s3*F + t]);
    }
    for (; i < cn; ++i)
      acc0 += alpha_sh[hh][i] * b2f(featb[(size_t)src_sh[i]*F + t]);
    __syncthreads();
  }
  float o = ((acc0 + acc1) + (acc2 + acc3)) / (s_sh[hh] + 1e-16f) + bias[t];
  if (DO_ELU) o = (o > 0.f) ? o : (expf(o) - 1.f);
  out[(size_t)n*F + t] = o;
  if (WB) outb[(size_t)n*F + t] = f2b(o);
}

// ===================== bf16 MFMA GEMM 64x64: MODE 0 f32, 2 bf16, 3 qkv scatter =====================
// MODE 3: Q columns pre-scaled by log2(e)/8 so attention softmax uses exp2 directly.
template<int MODE>
__global__ __launch_bounds__(256) void k_gemm_mfma(
    const u16* __restrict__ A, const u16* __restrict__ B,
    const float* __restrict__ bias, float* __restrict__ Cf, u16* __restrict__ Cb,
    u16* __restrict__ Qb, u16* __restrict__ Kb, u16* __restrict__ Vt,
    int M, int N, int K)
{
  __shared__ u16 Al[64*64];
  __shared__ u16 Bl[64*64];
  char* Ab = (char*)Al;
  char* Bb = (char*)Bl;
  const int t = threadIdx.x;
  const int lane = t & 63;
  const int lr = lane & 15, lk = lane >> 4;
  const int wid = t >> 6;
  const int wm = wid & 1, wn = wid >> 1;
  const int m0 = blockIdx.y * 64, n0 = blockIdx.x * 64;

  f4v acc[2][2];
  #pragma unroll
  for (int mi = 0; mi < 2; ++mi)
    #pragma unroll
    for (int ni = 0; ni < 2; ++ni)
      acc[mi][ni] = f4v{0.f, 0.f, 0.f, 0.f};

  for (int k0 = 0; k0 < K; k0 += 64) {
    #pragma unroll
    for (int i = 0; i < 2; ++i) {
      int idx = t + i*256;
      int row = idx >> 3, ch = idx & 7;
      s8v av = *(const s8v*)(A + (size_t)(m0 + row)*K + k0 + ch*8);
      *(s8v*)(Ab + row*128 + ((ch*16) ^ ((row & 7) << 4))) = av;
      s8v bv = *(const s8v*)(B + (size_t)(n0 + row)*K + k0 + ch*8);
      *(s8v*)(Bb + row*128 + ((ch*16) ^ ((row & 7) << 4))) = bv;
    }
    __syncthreads();
    #pragma unroll
    for (int ks = 0; ks < 2; ++ks) {
      s8v af[2], bfr[2];
      #pragma unroll
      for (int mi = 0; mi < 2; ++mi) {
        int row = wm*32 + mi*16 + lr;
        int ch = ks*4 + lk;
        af[mi] = *(const s8v*)(Ab + row*128 + ((ch*16) ^ ((row & 7) << 4)));
      }
      #pragma unroll
      for (int ni = 0; ni < 2; ++ni) {
        int row = wn*32 + ni*16 + lr;
        int ch = ks*4 + lk;
        bfr[ni] = *(const s8v*)(Bb + row*128 + ((ch*16) ^ ((row & 7) << 4)));
      }
      #pragma unroll
      for (int mi = 0; mi < 2; ++mi)
        #pragma unroll
        for (int ni = 0; ni < 2; ++ni)
          acc[mi][ni] = __builtin_amdgcn_mfma_f32_16x16x32_bf16(af[mi], bfr[ni], acc[mi][ni], 0, 0, 0);
    }
    __syncthreads();
  }
  #pragma unroll
  for (int ni = 0; ni < 2; ++ni) {
    int col = n0 + wn*32 + ni*16 + lr;
    float bc = bias ? bias[col] : 0.f;
    #pragma unroll
    for (int mi = 0; mi < 2; ++mi) {
      int row0 = m0 + wm*32 + mi*16 + lk*4;
      float v[4];
      #pragma unroll
      for (int r = 0; r < 4; ++r) v[r] = acc[mi][ni][r] + bc;
      if (MODE == 0) {
        #pragma unroll
        for (int r = 0; r < 4; ++r) Cf[(size_t)(row0 + r)*N + col] = v[r];
      } else if (MODE == 2) {
        #pragma unroll
        for (int r = 0; r < 4; ++r) Cb[(size_t)(row0 + r)*N + col] = f2b(v[r]);
      } else { // MODE 3: qkv scatter
        if (col < 512) {
          if (col < 256) {
            #pragma unroll
            for (int r = 0; r < 4; ++r) v[r] *= 0.18033688011112042f;  // log2(e)/8
          }
          int head = (col >> 6) & 3;
          int d = col & 63;
          u16* dst = ((col < 256) ? Qb : Kb) + (size_t)head*262144 + d;
          #pragma unroll
          for (int r = 0; r < 4; ++r) dst[(size_t)(row0 + r)*64] = f2b(v[r]);
        } else {
          int cc = col - 512;
          int head = cc >> 6;
          int d = cc & 63;
          int quad = row0 & 12;
          int qs = (quad == 4) ? 8 : ((quad == 8) ? 4 : quad);
          size_t nphys = (size_t)((row0 & ~15) | qs);
          u16 o4[4];
          #pragma unroll
          for (int r = 0; r < 4; ++r) o4[r] = f2b(v[r]);
          *(uint2*)(Vt + (size_t)head*262144 + (size_t)d*4096 + nphys) = *(uint2*)o4;
        }
      }
    }
  }
}

// ===================== bf16 MFMA GEMM 128x64 tile: MODE 1 relu+bf16, MODE 4 split-K f32 partials =====================
template<int MODE>
__global__ __launch_bounds__(256) void k_gemm2(
    const u16* __restrict__ A, const u16* __restrict__ B,
    const float* __restrict__ bias, float* __restrict__ Cf, u16* __restrict__ Cb,
    int M, int N, int K, int ksl)
{
  __shared__ u16 Al[128*64];
  __shared__ u16 Bl[64*64];
  char* Ab = (char*)Al;
  char* Bb = (char*)Bl;
  const int t = threadIdx.x;
  const int lane = t & 63;
  const int lr = lane & 15, lk = lane >> 4;
  const int wv = t >> 6;
  const int m0 = blockIdx.y * 128, n0 = blockIdx.x * 64;
  const int z = blockIdx.z;
  const int kbeg = z * ksl, kend = kbeg + ksl;

  f4v acc[2][4];
  #pragma unroll
  for (int mi = 0; mi < 2; ++mi)
    #pragma unroll
    for (int ni = 0; ni < 4; ++ni)
      acc[mi][ni] = f4v{0.f, 0.f, 0.f, 0.f};

  for (int k0 = kbeg; k0 < kend; k0 += 64) {
    #pragma unroll
    for (int i = 0; i < 4; ++i) {
      int idx = t + i*256;
      int row = idx >> 3, ch = idx & 7;
      s8v av = *(const s8v*)(A + (size_t)(m0 + row)*K + k0 + ch*8);
      *(s8v*)(Ab + row*128 + ((ch*16) ^ ((row & 7) << 4))) = av;
    }
    #pragma unroll
    for (int i = 0; i < 2; ++i) {
      int idx = t + i*256;
      int row = idx >> 3, ch = idx & 7;
      s8v bv = *(const s8v*)(B + (size_t)(n0 + row)*K + k0 + ch*8);
      *(s8v*)(Bb + row*128 + ((ch*16) ^ ((row & 7) << 4))) = bv;
    }
    __syncthreads();
    #pragma unroll
    for (int ks = 0; ks < 2; ++ks) {
      s8v af[2], bfr[4];
      #pragma unroll
      for (int mi = 0; mi < 2; ++mi) {
        int row = wv*32 + mi*16 + lr;
        int ch = ks*4 + lk;
        af[mi] = *(const s8v*)(Ab + row*128 + ((ch*16) ^ ((row & 7) << 4)));
      }
      #pragma unroll
      for (int ni = 0; ni < 4; ++ni) {
        int row = ni*16 + lr;
        int ch = ks*4 + lk;
        bfr[ni] = *(const s8v*)(Bb + row*128 + ((ch*16) ^ ((row & 7) << 4)));
      }
      #pragma unroll
      for (int mi = 0; mi < 2; ++mi)
        #pragma unroll
        for (int ni = 0; ni < 4; ++ni)
          acc[mi][ni] = __builtin_amdgcn_mfma_f32_16x16x32_bf16(af[mi], bfr[ni], acc[mi][ni], 0, 0, 0);
    }
    __syncthreads();
  }
  #pragma unroll
  for (int ni = 0; ni < 4; ++ni) {
    int col = n0 + ni*16 + lr;
    float bc = (MODE == 4) ? 0.f : bias[col];
    #pragma unroll
    for (int mi = 0; mi < 2; ++mi) {
      int row0 = m0 + wv*32 + mi*16 + lk*4;
      #pragma unroll
      for (int r = 0; r < 4; ++r) {
        float v = acc[mi][ni][r] + bc;
        if (MODE == 1) {
          v = fmaxf(v, 0.f);
          Cb[(size_t)(row0 + r)*N + col] = f2b(v);
        } else {
          (Cf + (size_t)z*M*N)[(size_t)(row0 + r)*N + col] = v;
        }
      }
    }
  }
}

// ===================== LayerNorm(a + res) =====================
template<bool WB>
__global__ __launch_bounds__(256) void k_ln(
    const float* __restrict__ a, const float* __restrict__ res,
    const float* __restrict__ g, const float* __restrict__ bb,
    float* __restrict__ out, u16* __restrict__ outb)
{
  int n = blockIdx.x, t = threadIdx.x;
  __shared__ float part[4];
  float v = a[(size_t)n*256 + t] + res[(size_t)n*256 + t];
  float s = v;
  #pragma unroll
  for (int off = 32; off; off >>= 1) s += __shfl_xor(s, off);
  if ((t & 63) == 0) part[t >> 6] = s;
  __syncthreads();
  float mean = (part[0] + part[1] + part[2] + part[3]) * (1.f/256.f);
  __syncthreads();
  float d = v - mean;
  float s2 = d * d;
  #pragma unroll
  for (int off = 32; off; off >>= 1) s2 += __shfl_xor(s2, off);
  if ((t & 63) == 0) part[t >> 6] = s2;
  __syncthreads();
  float var = (part[0] + part[1] + part[2] + part[3]) * (1.f/256.f);
  float rstd = rsqrtf(var + 1e-5f);
  float o = d * rstd * g[t] + bb[t];
  out[(size_t)n*256 + t] = o;
  if (WB) outb[(size_t)n*256 + t] = f2b(o);
}

// ===================== LayerNorm over 4 split-K partials + bias + res =====================
template<bool WB>
__global__ __launch_bounds__(256) void k_ln_sk(
    const float* __restrict__ Po, const float* __restrict__ bias,
    const float* __restrict__ res, const float* __restrict__ g,
    const float* __restrict__ bb, float* __restrict__ out, u16* __restrict__ outb)
{
  int n = blockIdx.x, t = threadIdx.x;
  __shared__ float part[4];
  const size_t MN = (size_t)NN * 256;
  size_t idx = (size_t)n*256 + t;
  float v = Po[idx] + Po[MN + idx] + Po[2*MN + idx] + Po[3*MN + idx]
          + bias[t] + res[idx];
  float s = v;
  #pragma unroll
  for (int off = 32; off; off >>= 1) s += __shfl_xor(s, off);
  if ((t & 63) == 0) part[t >> 6] = s;
  __syncthreads();
  float mean = (part[0] + part[1] + part[2] + part[3]) * (1.f/256.f);
  __syncthreads();
  float d = v - mean;
  float s2 = d * d;
  #pragma unroll
  for (int off = 32; off; off >>= 1) s2 += __shfl_xor(s2, off);
  if ((t & 63) == 0) part[t >> 6] = s2;
  __syncthreads();
  float var = (part[0] + part[1] + part[2] + part[3]) * (1.f/256.f);
  float rstd = rsqrtf(var + 1e-5f);
  float o = d * rstd * g[t] + bb[t];
  out[idx] = o;
  if (WB) outb[idx] = f2b(o);
}

// ===================== bf16 MFMA flash attention v7: dbuf LDS + cvt_pk + MFMA row-sum =====================
// grid (32 strips, 4 heads, 4 z); 4-wave blocks; block covers 128 queries,
// keys [z*1024, +1024) in 16 tiles of 64. K/V double-buffered in LDS (32KB).
// Q pre-scaled by log2(e)/8 (exp2 direct); P packed via v_cvt_pk_bf16_f32;
// softmax denominator accumulated on the MFMA pipe via ones-fragment.
__global__ __launch_bounds__(256) void k_attn3(
    const u16* __restrict__ Qb, const u16* __restrict__ Kb,
    const u16* __restrict__ Vt, float* __restrict__ op,
    float* __restrict__ mball, float* __restrict__ lball)
{
  const int strip = blockIdx.x;
  const int head  = blockIdx.y;
  const int z     = blockIdx.z;
  const int t = threadIdx.x;
  const int wv = t >> 6;
  const int l = t & 63;
  const int lq = l & 31;
  const int lh = l >> 5;
  const int q0 = strip*128 + wv*32;

  __shared__ u16 Kl[2][64*64];
  __shared__ u16 Vl[2][64*64];

  const u16* Qh = Qb + (size_t)head * (4096*64);
  const u16* Kh = Kb + (size_t)head * (4096*64);
  const u16* Vh = Vt + (size_t)head * (64*4096);

  s8v qf[4];
#pragma unroll
  for (int dc = 0; dc < 4; ++dc)
    qf[dc] = *(const s8v*)(Qh + (size_t)(q0 + lq)*64 + dc*16 + lh*8);

  const short one_bf = (short)0x3F80;
  const s8v pones = {one_bf, one_bf, one_bf, one_bf, one_bf, one_bf, one_bf, one_bf};

  // staging: thread t owns 16B chunks {t, t+256} of both K and V tiles
  const int c0 = t, c1 = t + 256;
  const int kr0 = c0 >> 3, kc0 = c0 & 7;
  const int kr1 = c1 >> 3, kc1 = c1 & 7;
  const int kt0 = z * 1024;
  const u16* gK0 = Kh + (size_t)(kt0 + kr0)*64 + kc0*8;
  const u16* gK1 = Kh + (size_t)(kt0 + kr1)*64 + kc1*8;
  const u16* gV0 = Vh + (size_t)kr0*4096 + kt0 + kc0*8;
  const u16* gV1 = Vh + (size_t)kr1*4096 + kt0 + kc1*8;
  const int lo0 = kr0*128 + ((kc0*16) ^ ((kr0 & 7) << 4));
  const int lo1 = kr1*128 + ((kc1*16) ^ ((kr1 & 7) << 4));

  // stage tile 0 into buffer 0
  {
    s8v a = *(const s8v*)gK0, b = *(const s8v*)gK1;
    s8v c = *(const s8v*)gV0, d = *(const s8v*)gV1;
    *(s8v*)((char*)Kl[0] + lo0) = a; *(s8v*)((char*)Kl[0] + lo1) = b;
    *(s8v*)((char*)Vl[0] + lo0) = c; *(s8v*)((char*)Vl[0] + lo1) = d;
  }
  __syncthreads();

  // constant LDS read offsets (tile-independent)
  int roK[2][4];
#pragma unroll
  for (int c = 0; c < 2; ++c) {
    int row = c*32 + lq;
#pragma unroll
    for (int dc = 0; dc < 4; ++dc)
      roK[c][dc] = row*128 + ((dc*32 + lh*16) ^ ((row & 7) << 4));
  }
  int roV[2][2][2];
#pragma unroll
  for (int dm = 0; dm < 2; ++dm) {
    int row = dm*32 + lq;
#pragma unroll
    for (int c = 0; c < 2; ++c)
#pragma unroll
      for (int kc = 0; kc < 2; ++kc)
        roV[c][kc][dm] = row*128 + ((c*64 + kc*32 + lh*16) ^ ((row & 7) << 4));
  }

  f16v accO[2], accS;
#pragma unroll
  for (int dm = 0; dm < 2; ++dm)
#pragma unroll
    for (int i = 0; i < 16; ++i) accO[dm][i] = 0.f;
#pragma unroll
  for (int i = 0; i < 16; ++i) accS[i] = 0.f;
  float mrow = -INFINITY;

  s8v rK0, rK1, rV0, rV1;
  for (int tt = 0; tt < 16; ++tt) {
    const int cur = tt & 1;
    char* Kc = (char*)Kl[cur];
    char* Vc = (char*)Vl[cur];
    char* Kn = (char*)Kl[cur ^ 1];
    char* Vn = (char*)Vl[cur ^ 1];
    if (tt < 15) {           // T14 issue-early: next tile's global loads
      gK0 += 64*64; gK1 += 64*64; gV0 += 64; gV1 += 64;
      rK0 = *(const s8v*)gK0; rK1 = *(const s8v*)gK1;
      rV0 = *(const s8v*)gV0; rV1 = *(const s8v*)gV1;
    }
    // QK^T from LDS (scores already in exp2 units; Q pre-scaled)
    s8v kf[2][4];
#pragma unroll
    for (int c = 0; c < 2; ++c)
#pragma unroll
      for (int dc = 0; dc < 4; ++dc)
        kf[c][dc] = *(const s8v*)(Kc + roK[c][dc]);
    f16v st[2];
#pragma unroll
    for (int c = 0; c < 2; ++c)
#pragma unroll
      for (int i = 0; i < 16; ++i) st[c][i] = 0.f;
#pragma unroll
    for (int dc = 0; dc < 4; ++dc) {
      st[0] = __builtin_amdgcn_mfma_f32_32x32x16_bf16(kf[0][dc], qf[dc], st[0], 0, 0, 0);
      st[1] = __builtin_amdgcn_mfma_f32_32x32x16_bf16(kf[1][dc], qf[dc], st[1], 0, 0, 0);
    }
    // softmax: max tree + exp2; sum is accumulated on the MFMA pipe (accS)
    float mx = st[0][0];
#pragma unroll
    for (int i = 1; i < 16; ++i) mx = fmaxf(mx, st[0][i]);
#pragma unroll
    for (int i = 0; i < 16; ++i) mx = fmaxf(mx, st[1][i]);
    mx = fmaxf(mx, __shfl_xor(mx, 32));
    float mn = fmaxf(mrow, mx);
    float sc = exp2f(mrow - mn);
    mrow = mn;
#pragma unroll
    for (int c = 0; c < 2; ++c)
#pragma unroll
      for (int i = 0; i < 16; ++i)
        st[c][i] = exp2f(st[c][i] - mn);
#pragma unroll
    for (int dm = 0; dm < 2; ++dm)
#pragma unroll
      for (int i = 0; i < 16; ++i) accO[dm][i] *= sc;
    accS[0] *= sc;

    // PV from LDS (V pre-permuted in global); P packed via cvt_pk
#pragma unroll
    for (int c = 0; c < 2; ++c) {
#pragma unroll
      for (int kc = 0; kc < 2; ++kc) {
        s8v vf0 = *(const s8v*)(Vc + roV[c][kc][0]);
        s8v vf1 = *(const s8v*)(Vc + roV[c][kc][1]);
        union { s8v v; unsigned int w[4]; } pb;
#pragma unroll
        for (int wd = 0; wd < 4; ++wd)
          pb.w[wd] = cvt_pk_bf16(st[c][kc*8 + wd*2], st[c][kc*8 + wd*2 + 1]);
        accO[0] = __builtin_amdgcn_mfma_f32_32x32x16_bf16(vf0, pb.v, accO[0], 0, 0, 0);
        accO[1] = __builtin_amdgcn_mfma_f32_32x32x16_bf16(vf1, pb.v, accO[1], 0, 0, 0);
        accS    = __builtin_amdgcn_mfma_f32_32x32x16_bf16(pones, pb.v, accS, 0, 0, 0);
      }
    }
    if (tt < 15) {           // T14 write-late: into the idle buffer
      *(s8v*)(Kn + lo0) = rK0; *(s8v*)(Kn + lo1) = rK1;
      *(s8v*)(Vn + lo0) = rV0; *(s8v*)(Vn + lo1) = rV1;
    }
    __syncthreads();         // writes to next buf visible; everyone done reading cur
  }
  float lrow = accS[0];

  // write partial (m, l, O) for this z-split
  int q = q0 + lq;
  int pidx = (z*4 + head)*4096 + q;
  if (lh == 0) { mball[pidx] = mrow; lball[pidx] = lrow; }
  size_t obase = ((size_t)(z*4 + head)*4096 + q)*64;
#pragma unroll
  for (int dm = 0; dm < 2; ++dm)
#pragma unroll
    for (int g = 0; g < 4; ++g) {
      f4v v;
#pragma unroll
      for (int rr = 0; rr < 4; ++rr) v[rr] = accO[dm][g*4 + rr];
      *(f4v*)&op[obase + dm*32 + lh*4 + g*8] = v;
    }
}

// merge the 4 z-partials -> bf16 attn output (m in exp2 units)
__global__ __launch_bounds__(256) void k_attn_mrg4(
    const float* __restrict__ op, const float* __restrict__ mball,
    const float* __restrict__ lball, u16* __restrict__ attno_b)
{
  const int bq = blockIdx.x;       // 0..127
  const int head = blockIdx.y;
  const int t = threadIdx.x;
  const int q = bq*32 + (t >> 3);
  const int d0 = (t & 7) * 8;
  float m[4], M = -INFINITY;
#pragma unroll
  for (int z = 0; z < 4; ++z) {
    m[z] = mball[(z*4 + head)*4096 + q];
    M = fmaxf(M, m[z]);
  }
  float w[4], L = 0.f;
#pragma unroll
  for (int z = 0; z < 4; ++z) {
    w[z] = exp2f(m[z] - M);
    L += w[z] * lball[(z*4 + head)*4096 + q];
  }
  float inv = 1.f / L;
  float o[8] = {0,0,0,0,0,0,0,0};
#pragma unroll
  for (int z = 0; z < 4; ++z) {
    size_t base = ((size_t)(z*4 + head)*4096 + q)*64 + d0;
    f4v a = *(const f4v*)&op[base];
    f4v b = *(const f4v*)&op[base + 4];
#pragma unroll
    for (int i = 0; i < 4; ++i) { o[i] += w[z]*a[i]; o[4+i] += w[z]*b[i]; }
  }
  u16 o8[8];
#pragma unroll
  for (int i = 0; i < 8; ++i) o8[i] = f2b(o[i] * inv);
  *(uint4*)(attno_b + (size_t)q*256 + head*64 + d0) = *(uint4*)o8;
}

// ===================== host launcher =====================
extern "C" void kernel_launch(void* const* d_in, const int* in_sizes, int n_in,
                              void* d_out, int out_size, void* d_ws, size_t ws_size,
                              hipStream_t stream)
{
  const float* x       = (const float*)d_in[0];
  const int*   ei      = (const int*)d_in[1];
  const float* gat1_w  = (const float*)d_in[2];
  const float* gat1_as = (const float*)d_in[3];
  const float* gat1_ad = (const float*)d_in[4];
  const float* gat1_b  = (const float*)d_in[5];
  const float* inp_w   = (const float*)d_in[6];
  const float* inp_b   = (const float*)d_in[7];
  const float* outp_w  = (const float*)d_in[8];
  const float* outp_b  = (const float*)d_in[9];
  const float* lin1_w  = (const float*)d_in[10];
  const float* lin1_b  = (const float*)d_in[11];
  const float* lin2_w  = (const float*)d_in[12];
  const float* lin2_b  = (const float*)d_in[13];
  const float* ln1_g   = (const float*)d_in[14];
  const float* ln1_bb  = (const float*)d_in[15];
  const float* ln2_g   = (const float*)d_in[16];
  const float* ln2_bb  = (const float*)d_in[17];
  const float* gat2_w  = (const float*)d_in[18];
  const float* gat2_as = (const float*)d_in[19];
  const float* gat2_ad = (const float*)d_in[20];
  const float* gat2_b  = (const float*)d_in[21];
  float* out = (float*)d_out;
  (void)in_sizes; (void)n_in; (void)out_size; (void)ws_size;

  char* ws = (char*)d_ws;
  size_t off = 0;
  auto nxt = [&](size_t bytes) { size_t r = off; off += (bytes + 255) & ~(size_t)255; return r; };
  int* deg      = (int*)(ws + nxt((size_t)NN*4));
  int* cursor   = (int*)(ws + nxt((size_t)NN*4));
  int* rowptr   = (int*)(ws + nxt((size_t)(NN+1)*4));
  int* csr_src  = (int*)(ws + nxt((size_t)EE*4));
  float* al1s   = (float*)(ws + nxt((size_t)NN*4*4));
  float* al1d   = (float*)(ws + nxt((size_t)NN*4*4));
  float* hgat1  = (float*)(ws + nxt((size_t)NN*256*4));
  float* tmp256 = (float*)(ws + nxt((size_t)NN*256*4));
  float* hln1   = (float*)(ws + nxt((size_t)NN*256*4));
  float* hln2   = (float*)(ws + nxt((size_t)NN*256*4));
  float* Po     = (float*)(ws + nxt((size_t)4*NN*256*4));   // 16MB: attn partials (4 z), then lin2 split-K
  float* al2s   = (float*)(ws + nxt((size_t)NN*4));
  float* al2d   = (float*)(ws + nxt((size_t)NN*4));
  float* mball  = (float*)(ws + nxt((size_t)16*NN*4));      // 256KB
  float* lball  = (float*)(ws + nxt((size_t)16*NN*4));      // 256KB
  u16* x_b      = (u16*)(ws + nxt((size_t)NN*128*2));
  u16* feat1_b  = (u16*)(ws + nxt((size_t)NN*256*2));
  u16* feat2_b  = (u16*)(ws + nxt((size_t)NN*128*2));
  u16* hgat1_b  = (u16*)(ws + nxt((size_t)NN*256*2));
  u16* attno_b  = (u16*)(ws + nxt((size_t)NN*256*2));
  u16* hln1_b   = (u16*)(ws + nxt((size_t)NN*256*2));
  u16* hln2_b   = (u16*)(ws + nxt((size_t)NN*256*2));
  u16* ff1_b    = (u16*)(ws + nxt((size_t)NN*2048*2));
  u16* Qb       = (u16*)(ws + nxt((size_t)4*4096*64*2));
  u16* Kb       = (u16*)(ws + nxt((size_t)4*4096*64*2));
  u16* Vt       = (u16*)(ws + nxt((size_t)4*4096*64*2));
  u16* inp_w_b  = (u16*)(ws + nxt((size_t)768*256*2));
  u16* outp_w_b = (u16*)(ws + nxt((size_t)256*256*2));
  u16* lin1_w_b = (u16*)(ws + nxt((size_t)2048*256*2));
  u16* lin2_w_b = (u16*)(ws + nxt((size_t)256*2048*2));
  u16* gat1_w_b = (u16*)(ws + nxt((size_t)256*128*2));
  u16* gat2_w_b = (u16*)(ws + nxt((size_t)128*256*2));

  hipMemsetAsync(deg, 0, (size_t)NN*4, stream);
  hipMemsetAsync(cursor, 0, (size_t)NN*4, stream);
  k_count<<<(EE+255)/256, 256, 0, stream>>>(ei, deg);
  k_scan<<<1, 1024, 0, stream>>>(deg, rowptr);
  k_scatter<<<(EE+255)/256, 256, 0, stream>>>(ei, rowptr, cursor, csr_src);

  // all fp32->bf16 conversions in one launch (cumulative float4 ends)
  k_f2b_all<<<1856, 256, 0, stream>>>(
      inp_w,  inp_w_b,  49152,
      outp_w, outp_w_b, 65536,
      lin1_w, lin1_w_b, 196608,
      lin2_w, lin2_w_b, 327680,
      gat1_w, gat1_w_b, 335872,
      gat2_w, gat2_w_b, 344064,
      x,      x_b,      475136);

  // GAT layer 1: proj (MFMA) + logits + aggregate (+ELU)
  k_gemm_mfma<2><<<dim3(4, 64), 256, 0, stream>>>(x_b, gat1_w_b, nullptr, nullptr, feat1_b, nullptr, nullptr, nullptr, NN, 256, 128);
  k_alogits<4,64><<<NN, 256, 0, stream>>>(feat1_b, gat1_as, gat1_ad, al1s, al1d);
  k_gat_agg<4,64,true,true><<<NN, 256, 0, stream>>>(feat1_b, al1s, al1d, gat1_b, rowptr, csr_src, hgat1, hgat1_b);

  // Transformer encoder layer
  k_gemm_mfma<3><<<dim3(12, 64), 256, 0, stream>>>(hgat1_b, inp_w_b, inp_b, nullptr, nullptr, Qb, Kb, Vt, NN, 768, 256);
  k_attn3<<<dim3(32, 4, 4), 256, 0, stream>>>(Qb, Kb, Vt, Po, mball, lball);
  k_attn_mrg4<<<dim3(128, 4), 256, 0, stream>>>(Po, mball, lball, attno_b);
  k_gemm_mfma<0><<<dim3(4, 64), 256, 0, stream>>>(attno_b, outp_w_b, outp_b, tmp256, nullptr, nullptr, nullptr, nullptr, NN, 256, 256);
  k_ln<true><<<NN, 256, 0, stream>>>(tmp256, hgat1, ln1_g, ln1_bb, hln1, hln1_b);
  k_gemm2<1><<<dim3(32, 32), 256, 0, stream>>>(hln1_b, lin1_w_b, lin1_b, nullptr, ff1_b, NN, 2048, 256, 256);
  k_gemm2<4><<<dim3(4, 32, 4), 256, 0, stream>>>(ff1_b, lin2_w_b, nullptr, Po, nullptr, NN, 256, 2048, 512);
  k_ln_sk<true><<<NN, 256, 0, stream>>>(Po, lin2_b, hln1, ln2_g, ln2_bb, hln2, hln2_b);

  // GAT layer 2 -> final output
  k_gemm_mfma<2><<<dim3(2, 64), 256, 0, stream>>>(hln2_b, gat2_w_b, nullptr, nullptr, feat2_b, nullptr, nullptr, nullptr, NN, 128, 256);
  k_alogits<1,128><<<NN, 128, 0, stream>>>(feat2_b, gat2_as, gat2_ad, al2s, al2d);
  k_gat_agg<1,128,false,false><<<NN, 128, 0, stream>>>(feat2_b, al2s, al2d, gat2_b, rowptr, csr_src, out, nullptr);
}